// Round 6
// baseline (1443.888 us; speedup 1.0000x reference)
//
#include <hip/hip_runtime.h>
#include <hip/hip_bf16.h>

typedef __attribute__((ext_vector_type(8))) short sv8_t;   // 8 bf16 (4 VGPR)
typedef __attribute__((ext_vector_type(4))) float fv4_t;   // MFMA accumulator
typedef __attribute__((ext_vector_type(4))) float f4ld_t;  // global float4 load

#define BB 8
#define TT 8
#define HH 56
#define WW2 56
#define NTOK 98
#define BNW 2048
#define PSPAT 25088
#define TOK_TOTAL 200704
#define ACT_ELEMS 25690112
#define VT_WSTRIDE 14336   // 128 * 112

#define SWZB(row, cb) ((cb) ^ ((((unsigned)(row)) & 7u) << 4))

__device__ __forceinline__ unsigned short f2bf(float f) {
    union { float f; unsigned u; } x; x.f = f;
    unsigned r = x.u + 0x7fffu + ((x.u >> 16) & 1u);
    return (unsigned short)(r >> 16);
}
__device__ __forceinline__ unsigned packbf(float lo, float hi) {
    return (unsigned)f2bf(lo) | ((unsigned)f2bf(hi) << 16);
}
__device__ __forceinline__ sv8_t lds_ld8(const unsigned short* p, int byteoff) {
    return *(const sv8_t*)((const char*)p + byteoff);
}
__device__ __forceinline__ void lds_st8(unsigned short* p, int byteoff, sv8_t v) {
    *(sv8_t*)((char*)p + byteoff) = v;
}
__device__ __forceinline__ void lds_st1(unsigned short* p, int byteoff, unsigned short v) {
    *(unsigned short*)((char*)p + byteoff) = v;
}
// GELU, tanh form via hardware exp (~10 VALU ops vs erff's ~30)
__device__ __forceinline__ float gelu_f(float v) {
    float u = v * (0.7978845608028654f + 0.035677408136300125f * v * v);
    float e = __expf(2.f * u);
    float th = 1.f - 2.f / (e + 1.f);
    return 0.5f * v * (1.f + th);
}

// ---------------- transpose in: (B,C,P) -> (B,P,C) f32 ----------------
__global__ __launch_bounds__(256) void k_transpose_in(const float* __restrict__ in,
                                                      float* __restrict__ xbuf) {
    __shared__ float tile[32][33];
    int p0 = blockIdx.x * 32, c0 = blockIdx.y * 32, b = blockIdx.z;
    int pi = threadIdx.x, ci = threadIdx.y;
    const float* src = in + ((size_t)b * 128 + c0) * PSPAT + p0;
    for (int r = 0; r < 32; r += 8)
        tile[ci + r][pi] = src[(size_t)(ci + r) * PSPAT + pi];
    __syncthreads();
    float* dst = xbuf + ((size_t)b * PSPAT + p0) * 128 + c0;
    for (int r = 0; r < 32; r += 8)
        dst[(size_t)(ci + r) * 128 + pi] = tile[pi][ci + r];
}

// ---------------- transpose out: (B,P,C) -> (B,C,P) ----------------
__global__ __launch_bounds__(256) void k_transpose_out(const float* __restrict__ xbuf,
                                                       float* __restrict__ out) {
    __shared__ float tile[32][33];
    int p0 = blockIdx.x * 32, c0 = blockIdx.y * 32, b = blockIdx.z;
    int pi = threadIdx.x, ci = threadIdx.y;
    const float* src = xbuf + ((size_t)b * PSPAT + p0) * 128 + c0;
    for (int r = 0; r < 32; r += 8)
        tile[ci + r][pi] = src[(size_t)(ci + r) * 128 + pi];
    __syncthreads();
    float* dst = out + ((size_t)b * 128 + c0) * PSPAT + p0;
    for (int r = 0; r < 32; r += 8)
        dst[(size_t)(ci + r) * PSPAT + pi] = tile[pi][ci + r];
}

// ---------------- weight prep: in f32 [K][N] -> out bf16 [N][K] ----------------
__global__ __launch_bounds__(256) void k_prep_w(const float* __restrict__ in,
                                                unsigned short* __restrict__ out,
                                                int K, int N) {
    __shared__ float tile[32][33];
    int n0 = blockIdx.x * 32, k0 = blockIdx.y * 32;
    int x = threadIdx.x, y = threadIdx.y;
    for (int r = 0; r < 32; r += 8)
        tile[y + r][x] = in[(size_t)(k0 + y + r) * N + n0 + x];
    __syncthreads();
    for (int r = 0; r < 32; r += 8)
        out[(size_t)(n0 + y + r) * K + k0 + x] = f2bf(tile[x][y + r]);
}

// ---------------- bias prep: biasb[layer][head][112][112] ----------------
__global__ void k_prep_bias(const float* __restrict__ rpb, float* __restrict__ biasb) {
    int col = threadIdx.x;   // 0..111
    int row = blockIdx.x;    // 0..111
    int head = blockIdx.y;   // 0..3
    int layer = blockIdx.z;
    int tn = min(row, 97), tm = min(col, 97);
    int itn = tn / 49, rn = tn - itn * 49, ihn = rn / 7, iwn = rn - ihn * 7;
    int itm = tm / 49, rm = tm - itm * 49, ihm = rm / 7, iwm = rm - ihm * 7;
    int dt = itn - itm + 1, dh = ihn - ihm + 6, dw = iwn - iwm + 6;
    float v = rpb[((size_t)layer * 507 + dt * 169 + dh * 13 + dw) * 4 + head];
    biasb[(((size_t)layer * 4 + head) * 112 + row) * 112 + col] = v;
}

// ---------------- fused LN1 + gather + qkv GEMM ----------------
// Q,K (pre-scaled Q) -> qkbuf [tok][256]; V (+bias) -> vT [win][128][112]
__global__ __launch_bounds__(256) void k_qkv(const float* __restrict__ xbuf,
                                             const float* __restrict__ g,
                                             const float* __restrict__ be,
                                             const unsigned short* __restrict__ wT,  // [384][128]
                                             const float* __restrict__ bias,         // [384]
                                             unsigned short* __restrict__ qkbuf,
                                             unsigned short* __restrict__ vT,
                                             int shifted) {
    __shared__ unsigned short xt[64 * 128];
    int tid = threadIdx.x;
    int row0 = blockIdx.x * 64;
    {
        int r = tid >> 2, q = tid & 3;
        int wt = row0 + r;
        int win = wt / 98, n = wt - win * 98;
        int b_ = win >> 8, wrem = win & 255;
        int tw = wrem >> 6, hw = (wrem >> 3) & 7, ww = wrem & 7;
        int it = n / 49, r2 = n - it * 49, ih = r2 / 7, iw = r2 - ih * 7;
        int t = tw * 2 + it, h = hw * 7 + ih, w = ww * 7 + iw;
        if (shifted) {
            t += 1; if (t >= TT) t -= TT;
            h += 3; if (h >= HH) h -= HH;
            w += 3; if (w >= WW2) w -= WW2;
        }
        const float* src = xbuf + ((size_t)b_ * PSPAT + t * (HH * WW2) + h * WW2 + w) * 128 + q * 32;
        float v[32];
        float s = 0.f, sq = 0.f;
        for (int i = 0; i < 8; i++) {
            f4ld_t f = *(const f4ld_t*)(src + i * 4);
            v[i * 4 + 0] = f.x; v[i * 4 + 1] = f.y; v[i * 4 + 2] = f.z; v[i * 4 + 3] = f.w;
            s += f.x + f.y + f.z + f.w;
            sq += f.x * f.x + f.y * f.y + f.z * f.z + f.w * f.w;
        }
        s += __shfl_xor(s, 1); sq += __shfl_xor(sq, 1);
        s += __shfl_xor(s, 2); sq += __shfl_xor(sq, 2);
        float mu = s * (1.f / 128.f);
        float var = sq * (1.f / 128.f) - mu * mu;
        float rs = rsqrtf(var + 1e-5f);
        for (int c0 = 0; c0 < 32; c0 += 8) {
            sv8_t o;
            #pragma unroll
            for (int i = 0; i < 8; i++) {
                int c = q * 32 + c0 + i;
                o[i] = (short)f2bf((v[c0 + i] - mu) * rs * g[c] + be[c]);
            }
            lds_st8(xt, r * 256 + SWZB(r, (q * 32 + c0) * 2), o);
        }
    }
    __syncthreads();
    int wv = tid >> 6, lane = tid & 63, l15 = lane & 15, lhi = lane >> 4;
    int nb = wv * 96;
    fv4_t acc[4][6];
    for (int m = 0; m < 4; m++) for (int j = 0; j < 6; j++) acc[m][j] = (fv4_t){0.f, 0.f, 0.f, 0.f};
    for (int kk = 0; kk < 4; kk++) {
        sv8_t a[4];
        #pragma unroll
        for (int m = 0; m < 4; m++) {
            int ar = 16 * m + l15;
            a[m] = lds_ld8(xt, ar * 256 + SWZB(ar, (kk * 32 + 8 * lhi) * 2));
        }
        #pragma unroll
        for (int j = 0; j < 6; j++) {
            sv8_t b = *(const sv8_t*)(wT + (size_t)(nb + 16 * j + l15) * 128 + kk * 32 + 8 * lhi);
            #pragma unroll
            for (int m = 0; m < 4; m++)
                acc[m][j] = __builtin_amdgcn_mfma_f32_16x16x32_bf16(a[m], b, acc[m][j], 0, 0, 0);
        }
    }
    const float scq = 0.17677669529663687f;
    for (int j = 0; j < 6; j++) {
        int col = nb + 16 * j + l15;
        float bb = bias[col];
        if (nb + 16 * j < 256) {            // Q or K -> qkbuf (wave-uniform branch)
            float sc_ = (nb + 16 * j < 128) ? scq : 1.f;
            #pragma unroll
            for (int m = 0; m < 4; m++)
                #pragma unroll
                for (int r = 0; r < 4; r++) {
                    int row = row0 + 16 * m + lhi * 4 + r;
                    qkbuf[(size_t)row * 256 + col] = f2bf((acc[m][j][r] + bb) * sc_);
                }
        } else {                             // V -> vT[win][d][tok]
            int d = col - 256;
            #pragma unroll
            for (int m = 0; m < 4; m++)
                #pragma unroll
                for (int r = 0; r < 4; r++) {
                    int row = row0 + 16 * m + lhi * 4 + r;
                    int win = row / 98, tok = row - win * 98;
                    vT[(size_t)win * VT_WSTRIDE + d * 112 + tok] = f2bf(acc[m][j][r] + bb);
                }
        }
    }
}

// ---------------- attention core + proj, one block per window ----------------
__global__ __launch_bounds__(256) void k_attn_proj(const unsigned short* __restrict__ qk,
                                                   const unsigned short* __restrict__ vT,
                                                   const float* __restrict__ biasb,  // [4][112][112]
                                                   const unsigned short* __restrict__ pwT, // [128][128]
                                                   const float* __restrict__ pb,
                                                   float* __restrict__ xbuf,
                                                   int shifted) {
    __shared__ unsigned short pt[4 * 16 * 128];
    __shared__ unsigned short ot[112 * 128];
    __shared__ int lablut[112];
    int win = blockIdx.x;
    int tid = threadIdx.x;
    int wv = tid >> 6, lane = tid & 63;
    int head = wv;
    int l15 = lane & 15, lhi = lane >> 4;
    int wrem = win & 255;
    int tw = wrem >> 6, hw = (wrem >> 3) & 7, ww = wrem & 7;

    for (int m = tid; m < 112; m += 256) {
        int t0 = min(m, 97);
        int it = t0 / 49, r2 = t0 - it * 49, ih = r2 / 7, iw = r2 - ih * 7;
        int lab = 0;
        if (shifted) {
            int t = tw * 2 + it, h = hw * 7 + ih, w = ww * 7 + iw;
            int ct = (t < TT - 2) ? 0 : ((t < TT - 1) ? 1 : 2);
            int ch = (h < HH - 7) ? 0 : ((h < HH - 3) ? 1 : 2);
            int cw = (w < WW2 - 7) ? 0 : ((w < WW2 - 3) ? 1 : 2);
            lab = ct * 9 + ch * 3 + cw;
        }
        lablut[m] = lab;
    }
    {   // zero P pad cols 112..127 (per wave tile)
        unsigned short* myp = pt + wv * 16 * 128;
        for (int idx = lane; idx < 256; idx += 64) {
            int r = idx >> 4, c = 112 + (idx & 15);
            lds_st1(myp, r * 256 + SWZB(r, c * 2), 0);
        }
    }
    __syncthreads();

    size_t rowbase = (size_t)win * 98;
    sv8_t kf[7];
    #pragma unroll
    for (int j = 0; j < 7; j++) {
        int tok = min(16 * j + l15, 97);
        kf[j] = *(const sv8_t*)(qk + (rowbase + tok) * 256 + 128 + head * 32 + 8 * lhi);
    }
    // V fragments: contiguous loads from vT[win][d][tok]
    const unsigned short* vbase = vT + (size_t)win * VT_WSTRIDE + (head * 32) * 112;
    sv8_t vf[4][2];
    #pragma unroll
    for (int kk = 0; kk < 4; kk++)
        #pragma unroll
        for (int j = 0; j < 2; j++)
            vf[kk][j] = *(const sv8_t*)(vbase + (16 * j + l15) * 112 + kk * 32 + 8 * lhi);

    unsigned short* myp = pt + wv * 16 * 128;
    const float* bslice = biasb + (size_t)head * 112 * 112;

    for (int ms = 0; ms < 7; ms++) {
        int qtok = min(16 * ms + l15, 97);
        sv8_t qa = *(const sv8_t*)(qk + (rowbase + qtok) * 256 + head * 32 + 8 * lhi);
        fv4_t sc[7];
        __builtin_amdgcn_s_setprio(1);
        #pragma unroll
        for (int j = 0; j < 7; j++) {
            fv4_t z = {0.f, 0.f, 0.f, 0.f};
            sc[j] = __builtin_amdgcn_mfma_f32_16x16x32_bf16(qa, kf[j], z, 0, 0, 0);
        }
        __builtin_amdgcn_s_setprio(0);
        float mx[4] = {-1e30f, -1e30f, -1e30f, -1e30f};
        int rowt[4];
        #pragma unroll
        for (int r = 0; r < 4; r++) rowt[r] = 16 * ms + lhi * 4 + r;
        #pragma unroll
        for (int j = 0; j < 7; j++) {
            int col = 16 * j + l15;
            int labc = lablut[col];
            bool colpad = (col >= 98);
            #pragma unroll
            for (int r = 0; r < 4; r++) {
                float s = sc[j][r] + bslice[rowt[r] * 112 + col];
                if (shifted && labc != lablut[rowt[r]]) s -= 100.f;
                if (colpad) s = -1e30f;
                sc[j][r] = s;
                mx[r] = fmaxf(mx[r], s);
            }
        }
        #pragma unroll
        for (int o = 1; o < 16; o <<= 1)
            #pragma unroll
            for (int r = 0; r < 4; r++) mx[r] = fmaxf(mx[r], __shfl_xor(mx[r], o));
        float sm[4] = {0.f, 0.f, 0.f, 0.f};
        #pragma unroll
        for (int j = 0; j < 7; j++)
            #pragma unroll
            for (int r = 0; r < 4; r++) {
                float p = __expf(sc[j][r] - mx[r]);
                sc[j][r] = p;
                sm[r] += p;
            }
        #pragma unroll
        for (int o = 1; o < 16; o <<= 1)
            #pragma unroll
            for (int r = 0; r < 4; r++) sm[r] += __shfl_xor(sm[r], o);
        #pragma unroll
        for (int j = 0; j < 7; j++)
            #pragma unroll
            for (int r = 0; r < 4; r++) {
                int pr = lhi * 4 + r, pc = 16 * j + l15;
                lds_st1(myp, pr * 256 + SWZB(pr, pc * 2), f2bf(sc[j][r]));
            }
        fv4_t oacc[2] = {{0.f, 0.f, 0.f, 0.f}, {0.f, 0.f, 0.f, 0.f}};
        __builtin_amdgcn_s_setprio(1);
        for (int kk = 0; kk < 4; kk++) {
            sv8_t pa = lds_ld8(myp, l15 * 256 + SWZB(l15, (kk * 32 + 8 * lhi) * 2));
            #pragma unroll
            for (int j = 0; j < 2; j++)
                oacc[j] = __builtin_amdgcn_mfma_f32_16x16x32_bf16(pa, vf[kk][j], oacc[j], 0, 0, 0);
        }
        __builtin_amdgcn_s_setprio(0);
        #pragma unroll
        for (int r = 0; r < 4; r++) {
            int orow = rowt[r];
            float inv = 1.f / sm[r];
            #pragma unroll
            for (int j = 0; j < 2; j++) {
                int ocol = head * 32 + 16 * j + l15;
                float v = (orow < 98) ? oacc[j][r] * inv : 0.f;
                lds_st1(ot, orow * 256 + SWZB(orow, ocol * 2), f2bf(v));
            }
        }
    }
    __syncthreads();

    // proj: wave wv handles output cols wv*32..+31 over 112 rows, K=128
    {
        int nb = wv * 32;
        fv4_t acc[7][2];
        for (int m = 0; m < 7; m++) for (int j = 0; j < 2; j++) acc[m][j] = (fv4_t){0.f, 0.f, 0.f, 0.f};
        for (int kk = 0; kk < 4; kk++) {
            sv8_t b[2];
            #pragma unroll
            for (int j = 0; j < 2; j++)
                b[j] = *(const sv8_t*)(pwT + (size_t)(nb + 16 * j + l15) * 128 + kk * 32 + 8 * lhi);
            __builtin_amdgcn_s_setprio(1);
            #pragma unroll
            for (int m = 0; m < 7; m++) {
                int ar = 16 * m + l15;
                sv8_t a = lds_ld8(ot, ar * 256 + SWZB(ar, (kk * 32 + 8 * lhi) * 2));
                #pragma unroll
                for (int j = 0; j < 2; j++)
                    acc[m][j] = __builtin_amdgcn_mfma_f32_16x16x32_bf16(a, b[j], acc[m][j], 0, 0, 0);
            }
            __builtin_amdgcn_s_setprio(0);
        }
        int b_ = win >> 8;
        for (int m = 0; m < 7; m++)
            #pragma unroll
            for (int r = 0; r < 4; r++) {
                int row = 16 * m + lhi * 4 + r;
                if (row < 98) {
                    int it = row / 49, r2 = row - it * 49, ih = r2 / 7, iw = r2 - ih * 7;
                    int t = tw * 2 + it, h = hw * 7 + ih, w = ww * 7 + iw;
                    if (shifted) {
                        t += 1; if (t >= TT) t -= TT;
                        h += 3; if (h >= HH) h -= HH;
                        w += 3; if (w >= WW2) w -= WW2;
                    }
                    float* xp = xbuf + ((size_t)b_ * PSPAT + t * (HH * WW2) + h * WW2 + w) * 128 + nb;
                    #pragma unroll
                    for (int j = 0; j < 2; j++) {
                        int c = 16 * j + l15;
                        xp[c] += acc[m][j][r] + pb[nb + c];
                    }
                }
            }
    }
}

// ---------------- fused LN2 + fc1 + GELU + fc2 + residual ----------------
// Barrier-free, wave-private, 2-wave blocks (finer scheduling granularity).
// Each wave owns 32 tokens; weight fragments batch-loaded; each feeds 2 MFMAs.
__global__ __launch_bounds__(128, 3) void k_mlp(const float* __restrict__ xin,
                                                const float* __restrict__ g,
                                                const float* __restrict__ be,
                                                const unsigned short* __restrict__ w1T,  // [512][128]
                                                const float* __restrict__ b1p,
                                                const unsigned short* __restrict__ w2T,  // [128][512]
                                                const float* __restrict__ b2p,
                                                float* __restrict__ xbuf) {
    __shared__ unsigned short buf[2][32 * 128];   // 8 KB per wave: xt then ut
    int tid = threadIdx.x;
    int wv = tid >> 6, lane = tid & 63, l15 = lane & 15, lhi = lane >> 4;
    unsigned short* bw = buf[wv];
    int tok0 = blockIdx.x * 64 + wv * 32;

    // ---- LN: lane handles rows tok0+16tf+l15, cols 32*lhi..+31; stats over 4 lanes
    #pragma unroll
    for (int tf = 0; tf < 2; tf++) {
        int lrow = 16 * tf + l15;
        const float* src = xin + (size_t)(tok0 + lrow) * 128 + lhi * 32;
        float v[32];
        float s = 0.f, sq = 0.f;
        #pragma unroll
        for (int i = 0; i < 8; i++) {
            f4ld_t f = *(const f4ld_t*)(src + i * 4);
            v[i * 4 + 0] = f.x; v[i * 4 + 1] = f.y; v[i * 4 + 2] = f.z; v[i * 4 + 3] = f.w;
            s += f.x + f.y + f.z + f.w;
            sq += f.x * f.x + f.y * f.y + f.z * f.z + f.w * f.w;
        }
        s += __shfl_xor(s, 16); sq += __shfl_xor(sq, 16);
        s += __shfl_xor(s, 32); sq += __shfl_xor(sq, 32);
        float mu = s * (1.f / 128.f);
        float var = sq * (1.f / 128.f) - mu * mu;
        float rs = rsqrtf(var + 1e-5f);
        #pragma unroll
        for (int j = 0; j < 4; j++) {     // 8 cols -> one b128
            int c0 = lhi * 32 + 8 * j;
            f4ld_t g0 = *(const f4ld_t*)(g + c0);
            f4ld_t g1 = *(const f4ld_t*)(g + c0 + 4);
            f4ld_t b0 = *(const f4ld_t*)(be + c0);
            f4ld_t b1 = *(const f4ld_t*)(be + c0 + 4);
            float y0 = (v[8 * j + 0] - mu) * rs * g0.x + b0.x;
            float y1 = (v[8 * j + 1] - mu) * rs * g0.y + b0.y;
            float y2 = (v[8 * j + 2] - mu) * rs * g0.z + b0.z;
            float y3 = (v[8 * j + 3] - mu) * rs * g0.w + b0.w;
            float y4 = (v[8 * j + 4] - mu) * rs * g1.x + b1.x;
            float y5 = (v[8 * j + 5] - mu) * rs * g1.y + b1.y;
            float y6 = (v[8 * j + 6] - mu) * rs * g1.z + b1.z;
            float y7 = (v[8 * j + 7] - mu) * rs * g1.w + b1.w;
            union { unsigned u[4]; sv8_t s8; } pk;
            pk.u[0] = packbf(y0, y1); pk.u[1] = packbf(y2, y3);
            pk.u[2] = packbf(y4, y5); pk.u[3] = packbf(y6, y7);
            lds_st8(bw, lrow * 256 + SWZB(lrow, 64 * lhi + 16 * j), pk.s8);
        }
    }
    // fc1 B-fragments (lane = token l15 within frag tf): x[tok][kk*32 + 8*lhi .. +7]
    sv8_t xf[2][4];
    #pragma unroll
    for (int tf = 0; tf < 2; tf++)
        #pragma unroll
        for (int kk = 0; kk < 4; kk++) {
            int lrow = 16 * tf + l15;
            xf[tf][kk] = lds_ld8(bw, lrow * 256 + SWZB(lrow, 64 * kk + 16 * lhi));
        }

    fv4_t acc2[8][2];
    #pragma unroll
    for (int cg = 0; cg < 8; cg++)
        #pragma unroll
        for (int tf = 0; tf < 2; tf++) acc2[cg][tf] = (fv4_t){0.f, 0.f, 0.f, 0.f};

    for (int q = 0; q < 4; q++) {        // 128 U-cols per quarter
        // ---- fc1: U^T quarter = mfma(w1 rows as A, x as B); batch 4 loads per f
        #pragma unroll
        for (int f = 0; f < 8; f++) {
            sv8_t wf[4];
            #pragma unroll
            for (int kk = 0; kk < 4; kk++)
                wf[kk] = *(const sv8_t*)(w1T + (size_t)(q * 128 + 16 * f + l15) * 128 + kk * 32 + 8 * lhi);
            fv4_t a1[2] = {{0.f, 0.f, 0.f, 0.f}, {0.f, 0.f, 0.f, 0.f}};
            __builtin_amdgcn_s_setprio(1);
            #pragma unroll
            for (int kk = 0; kk < 4; kk++) {
                a1[0] = __builtin_amdgcn_mfma_f32_16x16x32_bf16(wf[kk], xf[0][kk], a1[0], 0, 0, 0);
                a1[1] = __builtin_amdgcn_mfma_f32_16x16x32_bf16(wf[kk], xf[1][kk], a1[1], 0, 0, 0);
            }
            __builtin_amdgcn_s_setprio(0);
            // GELU + bias + pack -> U tile (ucols q*128+16f+4lhi+r, token row)
            f4ld_t b4 = *(const f4ld_t*)(b1p + q * 128 + 16 * f + 4 * lhi);
            #pragma unroll
            for (int tf = 0; tf < 2; tf++) {
                float g0 = gelu_f(a1[tf][0] + b4.x);
                float g1 = gelu_f(a1[tf][1] + b4.y);
                float g2 = gelu_f(a1[tf][2] + b4.z);
                float g3 = gelu_f(a1[tf][3] + b4.w);
                union { unsigned u[2]; uint2 u2; } pk;
                pk.u[0] = packbf(g0, g1); pk.u[1] = packbf(g2, g3);
                int lrow = 16 * tf + l15;
                *(uint2*)((char*)bw + lrow * 256 + SWZB(lrow, 32 * f + 8 * lhi)) = pk.u2;
            }
        }
        // ---- fc2 quarter: Out^T += mfma(w2 rows as A, U as B); batch 4 weight loads
        #pragma unroll
        for (int kq = 0; kq < 4; kq++) {
            sv8_t uf[2];
            #pragma unroll
            for (int tf = 0; tf < 2; tf++) {
                int lrow = 16 * tf + l15;
                uf[tf] = lds_ld8(bw, lrow * 256 + SWZB(lrow, 64 * kq + 16 * lhi));
            }
            #pragma unroll
            for (int cb = 0; cb < 2; cb++) {
                sv8_t w2f[4];
                #pragma unroll
                for (int c = 0; c < 4; c++)
                    w2f[c] = *(const sv8_t*)(w2T + (size_t)(16 * (4 * cb + c) + l15) * 512 + q * 128 + kq * 32 + 8 * lhi);
                __builtin_amdgcn_s_setprio(1);
                #pragma unroll
                for (int c = 0; c < 4; c++) {
                    int cg = 4 * cb + c;
                    acc2[cg][0] = __builtin_amdgcn_mfma_f32_16x16x32_bf16(w2f[c], uf[0], acc2[cg][0], 0, 0, 0);
                    acc2[cg][1] = __builtin_amdgcn_mfma_f32_16x16x32_bf16(w2f[c], uf[1], acc2[cg][1], 0, 0, 0);
                }
                __builtin_amdgcn_s_setprio(0);
            }
        }
    }
    // ---- epilogue: out[tok][16cg+4lhi+r] += acc2 + b2  (float4 RMW)
    #pragma unroll
    for (int tf = 0; tf < 2; tf++) {
        int row = tok0 + 16 * tf + l15;
        #pragma unroll
        for (int cg = 0; cg < 8; cg++) {
            int c0 = 16 * cg + 4 * lhi;
            f4ld_t b4 = *(const f4ld_t*)(b2p + c0);
            float* xp = xbuf + (size_t)row * 128 + c0;
            f4ld_t o = *(f4ld_t*)xp;
            o.x += acc2[cg][tf][0] + b4.x;
            o.y += acc2[cg][tf][1] + b4.y;
            o.z += acc2[cg][tf][2] + b4.z;
            o.w += acc2[cg][tf][3] + b4.w;
            *(f4ld_t*)xp = o;
        }
    }
}

extern "C" void kernel_launch(void* const* d_in, const int* in_sizes, int n_in,
                              void* d_out, int out_size, void* d_ws, size_t ws_size,
                              hipStream_t stream) {
    const float* x_in   = (const float*)d_in[0];
    const float* ln1_g  = (const float*)d_in[1];
    const float* ln1_b  = (const float*)d_in[2];
    const float* qkv_w  = (const float*)d_in[3];
    const float* qkv_b  = (const float*)d_in[4];
    const float* rpb    = (const float*)d_in[5];
    const float* proj_w = (const float*)d_in[6];
    const float* proj_b = (const float*)d_in[7];
    const float* ln2_g  = (const float*)d_in[8];
    const float* ln2_b  = (const float*)d_in[9];
    const float* fc1_w  = (const float*)d_in[10];
    const float* fc1_b  = (const float*)d_in[11];
    const float* fc2_w  = (const float*)d_in[12];
    const float* fc2_b  = (const float*)d_in[13];
    float* out = (float*)d_out;

    char* ws = (char*)d_ws;
    float* xbuf = (float*)ws;                                        // 102,760,448 B
    unsigned short* qkbuf = (unsigned short*)(ws + 102760448);       // 102,760,448 B
    unsigned short* vTbuf = (unsigned short*)(ws + 205520896);       //  58,720,256 B (+256 pad)
    unsigned short* wbase = (unsigned short*)(ws + 264241408);       //     786,432 B
    float* biasb = (float*)(ws + 264241408 + 786432);                //     401,408 B

    k_transpose_in<<<dim3(PSPAT / 32, 4, BB), dim3(32, 8), 0, stream>>>(x_in, xbuf);

    for (int l = 0; l < 2; l++) {
        unsigned short* wqT = wbase + (size_t)l * 196608;
        unsigned short* wpT = wqT + 49152;
        unsigned short* w1T = wpT + 16384;
        unsigned short* w2T = w1T + 65536;
        k_prep_w<<<dim3(12, 4), dim3(32, 8), 0, stream>>>(qkv_w + (size_t)l * 49152, wqT, 128, 384);
        k_prep_w<<<dim3(4, 4),  dim3(32, 8), 0, stream>>>(proj_w + (size_t)l * 16384, wpT, 128, 128);
        k_prep_w<<<dim3(16, 4), dim3(32, 8), 0, stream>>>(fc1_w + (size_t)l * 65536, w1T, 128, 512);
        k_prep_w<<<dim3(4, 16), dim3(32, 8), 0, stream>>>(fc2_w + (size_t)l * 65536, w2T, 512, 128);
    }
    k_prep_bias<<<dim3(112, 4, 2), 112, 0, stream>>>(rpb, biasb);

    for (int layer = 0; layer < 2; layer++) {
        unsigned short* wqT = wbase + (size_t)layer * 196608;
        unsigned short* wpT = wqT + 49152;
        unsigned short* w1T = wpT + 16384;
        unsigned short* w2T = w1T + 65536;
        int shifted = layer & 1;

        k_qkv<<<TOK_TOTAL / 64, 256, 0, stream>>>(xbuf, ln1_g + layer * 128, ln1_b + layer * 128,
                                                  wqT, qkv_b + layer * 384, qkbuf, vTbuf, shifted);
        k_attn_proj<<<BNW, 256, 0, stream>>>(qkbuf, vTbuf, biasb + (size_t)layer * 4 * 112 * 112,
                                             wpT, proj_b + layer * 128, xbuf, shifted);
        k_mlp<<<TOK_TOTAL / 64, 128, 0, stream>>>(xbuf, ln2_g + layer * 128, ln2_b + layer * 128,
                                                  w1T, fc1_b + layer * 512, w2T, fc2_b + layer * 128, xbuf);
    }

    k_transpose_out<<<dim3(PSPAT / 32, 4, BB), dim3(32, 8), 0, stream>>>(xbuf, out);
}

// Round 7
// 1143.731 us; speedup vs baseline: 1.2624x; 1.2624x over previous
//
#include <hip/hip_runtime.h>
#include <hip/hip_bf16.h>

typedef __attribute__((ext_vector_type(8))) short sv8_t;   // 8 bf16 (4 VGPR)
typedef __attribute__((ext_vector_type(4))) float fv4_t;   // MFMA accumulator
typedef __attribute__((ext_vector_type(4))) float f4ld_t;  // global float4 load

#define BB 8
#define TT 8
#define HH 56
#define WW2 56
#define NTOK 98
#define BNW 2048
#define PSPAT 25088
#define TOK_TOTAL 200704
#define ACT_ELEMS 25690112
#define VT_WSTRIDE 14336   // 128 * 112

#define SWZB(row, cb) ((cb) ^ ((((unsigned)(row)) & 7u) << 4))

__device__ __forceinline__ unsigned short f2bf(float f) {
    union { float f; unsigned u; } x; x.f = f;
    unsigned r = x.u + 0x7fffu + ((x.u >> 16) & 1u);
    return (unsigned short)(r >> 16);
}
__device__ __forceinline__ unsigned packbf(float lo, float hi) {
    return (unsigned)f2bf(lo) | ((unsigned)f2bf(hi) << 16);
}
__device__ __forceinline__ sv8_t lds_ld8(const unsigned short* p, int byteoff) {
    return *(const sv8_t*)((const char*)p + byteoff);
}
__device__ __forceinline__ void lds_st8(unsigned short* p, int byteoff, sv8_t v) {
    *(sv8_t*)((char*)p + byteoff) = v;
}
__device__ __forceinline__ void lds_st1(unsigned short* p, int byteoff, unsigned short v) {
    *(unsigned short*)((char*)p + byteoff) = v;
}
// GELU, tanh form via hardware exp (~10 VALU ops vs erff's ~30)
__device__ __forceinline__ float gelu_f(float v) {
    float u = v * (0.7978845608028654f + 0.035677408136300125f * v * v);
    float e = __expf(2.f * u);
    float th = 1.f - 2.f / (e + 1.f);
    return 0.5f * v * (1.f + th);
}

// ---------------- transpose in: (B,C,P) -> (B,P,C) f32 ----------------
__global__ __launch_bounds__(256) void k_transpose_in(const float* __restrict__ in,
                                                      float* __restrict__ xbuf) {
    __shared__ float tile[32][33];
    int p0 = blockIdx.x * 32, c0 = blockIdx.y * 32, b = blockIdx.z;
    int pi = threadIdx.x, ci = threadIdx.y;
    const float* src = in + ((size_t)b * 128 + c0) * PSPAT + p0;
    for (int r = 0; r < 32; r += 8)
        tile[ci + r][pi] = src[(size_t)(ci + r) * PSPAT + pi];
    __syncthreads();
    float* dst = xbuf + ((size_t)b * PSPAT + p0) * 128 + c0;
    for (int r = 0; r < 32; r += 8)
        dst[(size_t)(ci + r) * 128 + pi] = tile[pi][ci + r];
}

// ---------------- transpose out: (B,P,C) -> (B,C,P) ----------------
__global__ __launch_bounds__(256) void k_transpose_out(const float* __restrict__ xbuf,
                                                       float* __restrict__ out) {
    __shared__ float tile[32][33];
    int p0 = blockIdx.x * 32, c0 = blockIdx.y * 32, b = blockIdx.z;
    int pi = threadIdx.x, ci = threadIdx.y;
    const float* src = xbuf + ((size_t)b * PSPAT + p0) * 128 + c0;
    for (int r = 0; r < 32; r += 8)
        tile[ci + r][pi] = src[(size_t)(ci + r) * 128 + pi];
    __syncthreads();
    float* dst = out + ((size_t)b * 128 + c0) * PSPAT + p0;
    for (int r = 0; r < 32; r += 8)
        dst[(size_t)(ci + r) * PSPAT + pi] = tile[pi][ci + r];
}

// ---------------- weight prep: in f32 [K][N] -> out bf16 [N][K] ----------------
__global__ __launch_bounds__(256) void k_prep_w(const float* __restrict__ in,
                                                unsigned short* __restrict__ out,
                                                int K, int N) {
    __shared__ float tile[32][33];
    int n0 = blockIdx.x * 32, k0 = blockIdx.y * 32;
    int x = threadIdx.x, y = threadIdx.y;
    for (int r = 0; r < 32; r += 8)
        tile[y + r][x] = in[(size_t)(k0 + y + r) * N + n0 + x];
    __syncthreads();
    for (int r = 0; r < 32; r += 8)
        out[(size_t)(n0 + y + r) * K + k0 + x] = f2bf(tile[x][y + r]);
}

// ---------------- bias prep: biasbT[layer][head][col(112)][row(112)] ----------------
// Transposed so the attn kernel can load 4 consecutive ROWS (q-index) per col
// as one float4 (the C-fragment's reg dimension is the row).
__global__ void k_prep_bias(const float* __restrict__ rpb, float* __restrict__ biasbT) {
    int row = threadIdx.x;   // 0..111 (q index)
    int col = blockIdx.x;    // 0..111 (k index)
    int head = blockIdx.y;   // 0..3
    int layer = blockIdx.z;
    int tn = min(row, 97), tm = min(col, 97);
    int itn = tn / 49, rn = tn - itn * 49, ihn = rn / 7, iwn = rn - ihn * 7;
    int itm = tm / 49, rm = tm - itm * 49, ihm = rm / 7, iwm = rm - ihm * 7;
    int dt = itn - itm + 1, dh = ihn - ihm + 6, dw = iwn - iwm + 6;
    float v = rpb[((size_t)layer * 507 + dt * 169 + dh * 13 + dw) * 4 + head];
    biasbT[(((size_t)layer * 4 + head) * 112 + col) * 112 + row] = v;
}

// ---------------- fused LN1 + gather + qkv GEMM ----------------
// Waves 0/1: Q,K (normal orientation) -> qkbuf [tok][256], Q pre-scaled.
// Waves 2/3: V with SWAPPED operands -> C[d][tok]: lanes write consecutive
// toks of vT[win][d][tok] (32B runs instead of 2B scatter).
__global__ __launch_bounds__(256) void k_qkv(const float* __restrict__ xbuf,
                                             const float* __restrict__ g,
                                             const float* __restrict__ be,
                                             const unsigned short* __restrict__ wT,  // [384][128]
                                             const float* __restrict__ bias,         // [384]
                                             unsigned short* __restrict__ qkbuf,
                                             unsigned short* __restrict__ vT,
                                             int shifted) {
    __shared__ unsigned short xt[64 * 128];
    int tid = threadIdx.x;
    int row0 = blockIdx.x * 64;
    {
        int r = tid >> 2, q = tid & 3;
        int wt = row0 + r;
        int win = wt / 98, n = wt - win * 98;
        int b_ = win >> 8, wrem = win & 255;
        int tw = wrem >> 6, hw = (wrem >> 3) & 7, ww = wrem & 7;
        int it = n / 49, r2 = n - it * 49, ih = r2 / 7, iw = r2 - ih * 7;
        int t = tw * 2 + it, h = hw * 7 + ih, w = ww * 7 + iw;
        if (shifted) {
            t += 1; if (t >= TT) t -= TT;
            h += 3; if (h >= HH) h -= HH;
            w += 3; if (w >= WW2) w -= WW2;
        }
        const float* src = xbuf + ((size_t)b_ * PSPAT + t * (HH * WW2) + h * WW2 + w) * 128 + q * 32;
        float v[32];
        float s = 0.f, sq = 0.f;
        for (int i = 0; i < 8; i++) {
            f4ld_t f = *(const f4ld_t*)(src + i * 4);
            v[i * 4 + 0] = f.x; v[i * 4 + 1] = f.y; v[i * 4 + 2] = f.z; v[i * 4 + 3] = f.w;
            s += f.x + f.y + f.z + f.w;
            sq += f.x * f.x + f.y * f.y + f.z * f.z + f.w * f.w;
        }
        s += __shfl_xor(s, 1); sq += __shfl_xor(sq, 1);
        s += __shfl_xor(s, 2); sq += __shfl_xor(sq, 2);
        float mu = s * (1.f / 128.f);
        float var = sq * (1.f / 128.f) - mu * mu;
        float rs = rsqrtf(var + 1e-5f);
        for (int c0 = 0; c0 < 32; c0 += 8) {
            sv8_t o;
            #pragma unroll
            for (int i = 0; i < 8; i++) {
                int c = q * 32 + c0 + i;
                o[i] = (short)f2bf((v[c0 + i] - mu) * rs * g[c] + be[c]);
            }
            lds_st8(xt, r * 256 + SWZB(r, (q * 32 + c0) * 2), o);
        }
    }
    __syncthreads();
    int wv = tid >> 6, lane = tid & 63, l15 = lane & 15, lhi = lane >> 4;

    if (wv < 2) {
        // ---- Q (wv0) or K (wv1), normal orientation: 8 n-frags over 64 rows
        int nb = wv * 128;
        fv4_t acc[4][8];
        for (int m = 0; m < 4; m++) for (int j = 0; j < 8; j++) acc[m][j] = (fv4_t){0.f, 0.f, 0.f, 0.f};
        for (int kk = 0; kk < 4; kk++) {
            sv8_t a[4];
            #pragma unroll
            for (int m = 0; m < 4; m++) {
                int ar = 16 * m + l15;
                a[m] = lds_ld8(xt, ar * 256 + SWZB(ar, (kk * 32 + 8 * lhi) * 2));
            }
            #pragma unroll
            for (int j = 0; j < 8; j++) {
                sv8_t b = *(const sv8_t*)(wT + (size_t)(nb + 16 * j + l15) * 128 + kk * 32 + 8 * lhi);
                #pragma unroll
                for (int m = 0; m < 4; m++)
                    acc[m][j] = __builtin_amdgcn_mfma_f32_16x16x32_bf16(a[m], b, acc[m][j], 0, 0, 0);
            }
        }
        float sc_ = (wv == 0) ? 0.17677669529663687f : 1.f;
        for (int j = 0; j < 8; j++) {
            int col = nb + 16 * j + l15;
            float bb = bias[col];
            #pragma unroll
            for (int m = 0; m < 4; m++)
                #pragma unroll
                for (int r = 0; r < 4; r++) {
                    int row = row0 + 16 * m + lhi * 4 + r;
                    qkbuf[(size_t)row * 256 + col] = f2bf((acc[m][j][r] + bb) * sc_);
                }
        }
    } else {
        // ---- V, swapped: C[d][tok]; wave handles d16 frags (wv-2)*4 .. +3
        int d16base = (wv - 2) * 4;
        fv4_t acc[4][4];   // [m][f]
        for (int m = 0; m < 4; m++) for (int f = 0; f < 4; f++) acc[m][f] = (fv4_t){0.f, 0.f, 0.f, 0.f};
        for (int kk = 0; kk < 4; kk++) {
            sv8_t x4[4];
            #pragma unroll
            for (int m = 0; m < 4; m++) {
                int ar = 16 * m + l15;
                x4[m] = lds_ld8(xt, ar * 256 + SWZB(ar, (kk * 32 + 8 * lhi) * 2));
            }
            #pragma unroll
            for (int f = 0; f < 4; f++) {
                sv8_t wf = *(const sv8_t*)(wT + (size_t)(256 + (d16base + f) * 16 + l15) * 128 + kk * 32 + 8 * lhi);
                #pragma unroll
                for (int m = 0; m < 4; m++)
                    acc[m][f] = __builtin_amdgcn_mfma_f32_16x16x32_bf16(wf, x4[m], acc[m][f], 0, 0, 0);
            }
        }
        #pragma unroll
        for (int f = 0; f < 4; f++) {
            f4ld_t b4 = *(const f4ld_t*)(bias + 256 + (d16base + f) * 16 + 4 * lhi);
            #pragma unroll
            for (int r = 0; r < 4; r++) {
                int d = (d16base + f) * 16 + 4 * lhi + r;
                #pragma unroll
                for (int m = 0; m < 4; m++) {
                    int row = row0 + 16 * m + l15;
                    int win = row / 98, tok = row - win * 98;
                    vT[(size_t)win * VT_WSTRIDE + d * 112 + tok] = f2bf(acc[m][f][r] + b4[r]);
                }
            }
        }
    }
}

// ---------------- attention core + proj, one block per window ----------------
__global__ __launch_bounds__(256) void k_attn_proj(const unsigned short* __restrict__ qk,
                                                   const unsigned short* __restrict__ vT,
                                                   const float* __restrict__ biasbT, // [4][112 col][112 row]
                                                   const unsigned short* __restrict__ pwT, // [128][128]
                                                   const float* __restrict__ pb,
                                                   float* __restrict__ xbuf,
                                                   int shifted) {
    __shared__ unsigned short pt[4 * 16 * 128];
    __shared__ unsigned short ot[112 * 128];
    __shared__ int lablut[112];
    int win = blockIdx.x;
    int tid = threadIdx.x;
    int wv = tid >> 6, lane = tid & 63;
    int head = wv;
    int l15 = lane & 15, lhi = lane >> 4;
    int wrem = win & 255;
    int tw = wrem >> 6, hw = (wrem >> 3) & 7, ww = wrem & 7;

    for (int m = tid; m < 112; m += 256) {
        int t0 = min(m, 97);
        int it = t0 / 49, r2 = t0 - it * 49, ih = r2 / 7, iw = r2 - ih * 7;
        int lab = 0;
        if (shifted) {
            int t = tw * 2 + it, h = hw * 7 + ih, w = ww * 7 + iw;
            int ct = (t < TT - 2) ? 0 : ((t < TT - 1) ? 1 : 2);
            int ch = (h < HH - 7) ? 0 : ((h < HH - 3) ? 1 : 2);
            int cw = (w < WW2 - 7) ? 0 : ((w < WW2 - 3) ? 1 : 2);
            lab = ct * 9 + ch * 3 + cw;
        }
        lablut[m] = lab;
    }
    {   // zero P pad cols 112..127 (per wave tile)
        unsigned short* myp = pt + wv * 16 * 128;
        for (int idx = lane; idx < 256; idx += 64) {
            int r = idx >> 4, c = 112 + (idx & 15);
            lds_st1(myp, r * 256 + SWZB(r, c * 2), 0);
        }
    }
    __syncthreads();

    size_t rowbase = (size_t)win * 98;
    sv8_t kf[7];
    #pragma unroll
    for (int j = 0; j < 7; j++) {
        int tok = min(16 * j + l15, 97);
        kf[j] = *(const sv8_t*)(qk + (rowbase + tok) * 256 + 128 + head * 32 + 8 * lhi);
    }
    // V fragments: contiguous loads from vT[win][d][tok]
    const unsigned short* vbase = vT + (size_t)win * VT_WSTRIDE + (head * 32) * 112;
    sv8_t vf[4][2];
    #pragma unroll
    for (int kk = 0; kk < 4; kk++)
        #pragma unroll
        for (int j = 0; j < 2; j++)
            vf[kk][j] = *(const sv8_t*)(vbase + (16 * j + l15) * 112 + kk * 32 + 8 * lhi);

    unsigned short* myp = pt + wv * 16 * 128;
    const float* bsliceT = biasbT + (size_t)head * 112 * 112;

    for (int ms = 0; ms < 7; ms++) {
        int qtok = min(16 * ms + l15, 97);
        sv8_t qa = *(const sv8_t*)(qk + (rowbase + qtok) * 256 + head * 32 + 8 * lhi);
        // prefetch bias: one float4 per j (rows 16ms+4lhi..+3 of col 16j+l15)
        f4ld_t bv[7];
        #pragma unroll
        for (int j = 0; j < 7; j++)
            bv[j] = *(const f4ld_t*)(bsliceT + (16 * j + l15) * 112 + 16 * ms + 4 * lhi);
        fv4_t sc[7];
        __builtin_amdgcn_s_setprio(1);
        #pragma unroll
        for (int j = 0; j < 7; j++) {
            fv4_t z = {0.f, 0.f, 0.f, 0.f};
            sc[j] = __builtin_amdgcn_mfma_f32_16x16x32_bf16(qa, kf[j], z, 0, 0, 0);
        }
        __builtin_amdgcn_s_setprio(0);
        float mx[4] = {-1e30f, -1e30f, -1e30f, -1e30f};
        int rowt[4];
        #pragma unroll
        for (int r = 0; r < 4; r++) rowt[r] = 16 * ms + lhi * 4 + r;
        #pragma unroll
        for (int j = 0; j < 7; j++) {
            int col = 16 * j + l15;
            int labc = lablut[col];
            bool colpad = (col >= 98);
            #pragma unroll
            for (int r = 0; r < 4; r++) {
                float s = sc[j][r] + bv[j][r];
                if (shifted && labc != lablut[rowt[r]]) s -= 100.f;
                if (colpad) s = -1e30f;
                sc[j][r] = s;
                mx[r] = fmaxf(mx[r], s);
            }
        }
        #pragma unroll
        for (int o = 1; o < 16; o <<= 1)
            #pragma unroll
            for (int r = 0; r < 4; r++) mx[r] = fmaxf(mx[r], __shfl_xor(mx[r], o));
        float sm[4] = {0.f, 0.f, 0.f, 0.f};
        #pragma unroll
        for (int j = 0; j < 7; j++)
            #pragma unroll
            for (int r = 0; r < 4; r++) {
                float p = __expf(sc[j][r] - mx[r]);
                sc[j][r] = p;
                sm[r] += p;
            }
        #pragma unroll
        for (int o = 1; o < 16; o <<= 1)
            #pragma unroll
            for (int r = 0; r < 4; r++) sm[r] += __shfl_xor(sm[r], o);
        #pragma unroll
        for (int j = 0; j < 7; j++)
            #pragma unroll
            for (int r = 0; r < 4; r++) {
                int pr = lhi * 4 + r, pc = 16 * j + l15;
                lds_st1(myp, pr * 256 + SWZB(pr, pc * 2), f2bf(sc[j][r]));
            }
        fv4_t oacc[2] = {{0.f, 0.f, 0.f, 0.f}, {0.f, 0.f, 0.f, 0.f}};
        __builtin_amdgcn_s_setprio(1);
        for (int kk = 0; kk < 4; kk++) {
            sv8_t pa = lds_ld8(myp, l15 * 256 + SWZB(l15, (kk * 32 + 8 * lhi) * 2));
            #pragma unroll
            for (int j = 0; j < 2; j++)
                oacc[j] = __builtin_amdgcn_mfma_f32_16x16x32_bf16(pa, vf[kk][j], oacc[j], 0, 0, 0);
        }
        __builtin_amdgcn_s_setprio(0);
        #pragma unroll
        for (int r = 0; r < 4; r++) {
            int orow = rowt[r];
            float inv = 1.f / sm[r];
            #pragma unroll
            for (int j = 0; j < 2; j++) {
                int ocol = head * 32 + 16 * j + l15;
                float v = (orow < 98) ? oacc[j][r] * inv : 0.f;
                lds_st1(ot, orow * 256 + SWZB(orow, ocol * 2), f2bf(v));
            }
        }
    }
    __syncthreads();

    // proj: wave wv handles output cols wv*32..+31 over 112 rows, K=128
    {
        int nb = wv * 32;
        fv4_t acc[7][2];
        for (int m = 0; m < 7; m++) for (int j = 0; j < 2; j++) acc[m][j] = (fv4_t){0.f, 0.f, 0.f, 0.f};
        for (int kk = 0; kk < 4; kk++) {
            sv8_t b[2];
            #pragma unroll
            for (int j = 0; j < 2; j++)
                b[j] = *(const sv8_t*)(pwT + (size_t)(nb + 16 * j + l15) * 128 + kk * 32 + 8 * lhi);
            __builtin_amdgcn_s_setprio(1);
            #pragma unroll
            for (int m = 0; m < 7; m++) {
                int ar = 16 * m + l15;
                sv8_t a = lds_ld8(ot, ar * 256 + SWZB(ar, (kk * 32 + 8 * lhi) * 2));
                #pragma unroll
                for (int j = 0; j < 2; j++)
                    acc[m][j] = __builtin_amdgcn_mfma_f32_16x16x32_bf16(a, b[j], acc[m][j], 0, 0, 0);
            }
            __builtin_amdgcn_s_setprio(0);
        }
        int b_ = win >> 8;
        for (int m = 0; m < 7; m++)
            #pragma unroll
            for (int r = 0; r < 4; r++) {
                int row = 16 * m + lhi * 4 + r;
                if (row < 98) {
                    int it = row / 49, r2 = row - it * 49, ih = r2 / 7, iw = r2 - ih * 7;
                    int t = tw * 2 + it, h = hw * 7 + ih, w = ww * 7 + iw;
                    if (shifted) {
                        t += 1; if (t >= TT) t -= TT;
                        h += 3; if (h >= HH) h -= HH;
                        w += 3; if (w >= WW2) w -= WW2;
                    }
                    float* xp = xbuf + ((size_t)b_ * PSPAT + t * (HH * WW2) + h * WW2 + w) * 128 + nb;
                    #pragma unroll
                    for (int j = 0; j < 2; j++) {
                        int c = 16 * j + l15;
                        xp[c] += acc[m][j][r] + pb[nb + c];
                    }
                }
            }
    }
}

// ---------------- fused LN2 + fc1 + GELU + fc2 + residual ----------------
// Barrier-free, wave-private, 2-wave blocks (finer scheduling granularity).
// Each wave owns 32 tokens; weight fragments batch-loaded; each feeds 2 MFMAs.
__global__ __launch_bounds__(128, 3) void k_mlp(const float* __restrict__ xin,
                                                const float* __restrict__ g,
                                                const float* __restrict__ be,
                                                const unsigned short* __restrict__ w1T,  // [512][128]
                                                const float* __restrict__ b1p,
                                                const unsigned short* __restrict__ w2T,  // [128][512]
                                                const float* __restrict__ b2p,
                                                float* __restrict__ xbuf) {
    __shared__ unsigned short buf[2][32 * 128];   // 8 KB per wave: xt then ut
    int tid = threadIdx.x;
    int wv = tid >> 6, lane = tid & 63, l15 = lane & 15, lhi = lane >> 4;
    unsigned short* bw = buf[wv];
    int tok0 = blockIdx.x * 64 + wv * 32;

    // ---- LN: lane handles rows tok0+16tf+l15, cols 32*lhi..+31; stats over 4 lanes
    #pragma unroll
    for (int tf = 0; tf < 2; tf++) {
        int lrow = 16 * tf + l15;
        const float* src = xin + (size_t)(tok0 + lrow) * 128 + lhi * 32;
        float v[32];
        float s = 0.f, sq = 0.f;
        #pragma unroll
        for (int i = 0; i < 8; i++) {
            f4ld_t f = *(const f4ld_t*)(src + i * 4);
            v[i * 4 + 0] = f.x; v[i * 4 + 1] = f.y; v[i * 4 + 2] = f.z; v[i * 4 + 3] = f.w;
            s += f.x + f.y + f.z + f.w;
            sq += f.x * f.x + f.y * f.y + f.z * f.z + f.w * f.w;
        }
        s += __shfl_xor(s, 16); sq += __shfl_xor(sq, 16);
        s += __shfl_xor(s, 32); sq += __shfl_xor(sq, 32);
        float mu = s * (1.f / 128.f);
        float var = sq * (1.f / 128.f) - mu * mu;
        float rs = rsqrtf(var + 1e-5f);
        #pragma unroll
        for (int j = 0; j < 4; j++) {     // 8 cols -> one b128
            int c0 = lhi * 32 + 8 * j;
            f4ld_t g0 = *(const f4ld_t*)(g + c0);
            f4ld_t g1 = *(const f4ld_t*)(g + c0 + 4);
            f4ld_t b0 = *(const f4ld_t*)(be + c0);
            f4ld_t b1 = *(const f4ld_t*)(be + c0 + 4);
            float y0 = (v[8 * j + 0] - mu) * rs * g0.x + b0.x;
            float y1 = (v[8 * j + 1] - mu) * rs * g0.y + b0.y;
            float y2 = (v[8 * j + 2] - mu) * rs * g0.z + b0.z;
            float y3 = (v[8 * j + 3] - mu) * rs * g0.w + b0.w;
            float y4 = (v[8 * j + 4] - mu) * rs * g1.x + b1.x;
            float y5 = (v[8 * j + 5] - mu) * rs * g1.y + b1.y;
            float y6 = (v[8 * j + 6] - mu) * rs * g1.z + b1.z;
            float y7 = (v[8 * j + 7] - mu) * rs * g1.w + b1.w;
            union { unsigned u[4]; sv8_t s8; } pk;
            pk.u[0] = packbf(y0, y1); pk.u[1] = packbf(y2, y3);
            pk.u[2] = packbf(y4, y5); pk.u[3] = packbf(y6, y7);
            lds_st8(bw, lrow * 256 + SWZB(lrow, 64 * lhi + 16 * j), pk.s8);
        }
    }
    // fc1 B-fragments (lane = token l15 within frag tf): x[tok][kk*32 + 8*lhi .. +7]
    sv8_t xf[2][4];
    #pragma unroll
    for (int tf = 0; tf < 2; tf++)
        #pragma unroll
        for (int kk = 0; kk < 4; kk++) {
            int lrow = 16 * tf + l15;
            xf[tf][kk] = lds_ld8(bw, lrow * 256 + SWZB(lrow, 64 * kk + 16 * lhi));
        }

    fv4_t acc2[8][2];
    #pragma unroll
    for (int cg = 0; cg < 8; cg++)
        #pragma unroll
        for (int tf = 0; tf < 2; tf++) acc2[cg][tf] = (fv4_t){0.f, 0.f, 0.f, 0.f};

    for (int q = 0; q < 4; q++) {        // 128 U-cols per quarter
        // ---- fc1: U^T quarter = mfma(w1 rows as A, x as B); batch 4 loads per f
        #pragma unroll
        for (int f = 0; f < 8; f++) {
            sv8_t wf[4];
            #pragma unroll
            for (int kk = 0; kk < 4; kk++)
                wf[kk] = *(const sv8_t*)(w1T + (size_t)(q * 128 + 16 * f + l15) * 128 + kk * 32 + 8 * lhi);
            fv4_t a1[2] = {{0.f, 0.f, 0.f, 0.f}, {0.f, 0.f, 0.f, 0.f}};
            __builtin_amdgcn_s_setprio(1);
            #pragma unroll
            for (int kk = 0; kk < 4; kk++) {
                a1[0] = __builtin_amdgcn_mfma_f32_16x16x32_bf16(wf[kk], xf[0][kk], a1[0], 0, 0, 0);
                a1[1] = __builtin_amdgcn_mfma_f32_16x16x32_bf16(wf[kk], xf[1][kk], a1[1], 0, 0, 0);
            }
            __builtin_amdgcn_s_setprio(0);
            // GELU + bias + pack -> U tile (ucols q*128+16f+4lhi+r, token row)
            f4ld_t b4 = *(const f4ld_t*)(b1p + q * 128 + 16 * f + 4 * lhi);
            #pragma unroll
            for (int tf = 0; tf < 2; tf++) {
                float g0 = gelu_f(a1[tf][0] + b4.x);
                float g1 = gelu_f(a1[tf][1] + b4.y);
                float g2 = gelu_f(a1[tf][2] + b4.z);
                float g3 = gelu_f(a1[tf][3] + b4.w);
                union { unsigned u[2]; uint2 u2; } pk;
                pk.u[0] = packbf(g0, g1); pk.u[1] = packbf(g2, g3);
                int lrow = 16 * tf + l15;
                *(uint2*)((char*)bw + lrow * 256 + SWZB(lrow, 32 * f + 8 * lhi)) = pk.u2;
            }
        }
        // ---- fc2 quarter: Out^T += mfma(w2 rows as A, U as B); batch 4 weight loads
        #pragma unroll
        for (int kq = 0; kq < 4; kq++) {
            sv8_t uf[2];
            #pragma unroll
            for (int tf = 0; tf < 2; tf++) {
                int lrow = 16 * tf + l15;
                uf[tf] = lds_ld8(bw, lrow * 256 + SWZB(lrow, 64 * kq + 16 * lhi));
            }
            #pragma unroll
            for (int cb = 0; cb < 2; cb++) {
                sv8_t w2f[4];
                #pragma unroll
                for (int c = 0; c < 4; c++)
                    w2f[c] = *(const sv8_t*)(w2T + (size_t)(16 * (4 * cb + c) + l15) * 512 + q * 128 + kq * 32 + 8 * lhi);
                __builtin_amdgcn_s_setprio(1);
                #pragma unroll
                for (int c = 0; c < 4; c++) {
                    int cg = 4 * cb + c;
                    acc2[cg][0] = __builtin_amdgcn_mfma_f32_16x16x32_bf16(w2f[c], uf[0], acc2[cg][0], 0, 0, 0);
                    acc2[cg][1] = __builtin_amdgcn_mfma_f32_16x16x32_bf16(w2f[c], uf[1], acc2[cg][1], 0, 0, 0);
                }
                __builtin_amdgcn_s_setprio(0);
            }
        }
    }
    // ---- epilogue: out[tok][16cg+4lhi+r] += acc2 + b2  (float4 RMW)
    #pragma unroll
    for (int tf = 0; tf < 2; tf++) {
        int row = tok0 + 16 * tf + l15;
        #pragma unroll
        for (int cg = 0; cg < 8; cg++) {
            int c0 = 16 * cg + 4 * lhi;
            f4ld_t b4 = *(const f4ld_t*)(b2p + c0);
            float* xp = xbuf + (size_t)row * 128 + c0;
            f4ld_t o = *(f4ld_t*)xp;
            o.x += acc2[cg][tf][0] + b4.x;
            o.y += acc2[cg][tf][1] + b4.y;
            o.z += acc2[cg][tf][2] + b4.z;
            o.w += acc2[cg][tf][3] + b4.w;
            *(f4ld_t*)xp = o;
        }
    }
}

extern "C" void kernel_launch(void* const* d_in, const int* in_sizes, int n_in,
                              void* d_out, int out_size, void* d_ws, size_t ws_size,
                              hipStream_t stream) {
    const float* x_in   = (const float*)d_in[0];
    const float* ln1_g  = (const float*)d_in[1];
    const float* ln1_b  = (const float*)d_in[2];
    const float* qkv_w  = (const float*)d_in[3];
    const float* qkv_b  = (const float*)d_in[4];
    const float* rpb    = (const float*)d_in[5];
    const float* proj_w = (const float*)d_in[6];
    const float* proj_b = (const float*)d_in[7];
    const float* ln2_g  = (const float*)d_in[8];
    const float* ln2_b  = (const float*)d_in[9];
    const float* fc1_w  = (const float*)d_in[10];
    const float* fc1_b  = (const float*)d_in[11];
    const float* fc2_w  = (const float*)d_in[12];
    const float* fc2_b  = (const float*)d_in[13];
    float* out = (float*)d_out;

    char* ws = (char*)d_ws;
    float* xbuf = (float*)ws;                                        // 102,760,448 B
    unsigned short* qkbuf = (unsigned short*)(ws + 102760448);       // 102,760,448 B
    unsigned short* vTbuf = (unsigned short*)(ws + 205520896);       //  58,720,256 B
    unsigned short* wbase = (unsigned short*)(ws + 264241408);       //     786,432 B
    float* biasbT = (float*)(ws + 264241408 + 786432);               //     401,408 B

    k_transpose_in<<<dim3(PSPAT / 32, 4, BB), dim3(32, 8), 0, stream>>>(x_in, xbuf);

    for (int l = 0; l < 2; l++) {
        unsigned short* wqT = wbase + (size_t)l * 196608;
        unsigned short* wpT = wqT + 49152;
        unsigned short* w1T = wpT + 16384;
        unsigned short* w2T = w1T + 65536;
        k_prep_w<<<dim3(12, 4), dim3(32, 8), 0, stream>>>(qkv_w + (size_t)l * 49152, wqT, 128, 384);
        k_prep_w<<<dim3(4, 4),  dim3(32, 8), 0, stream>>>(proj_w + (size_t)l * 16384, wpT, 128, 128);
        k_prep_w<<<dim3(16, 4), dim3(32, 8), 0, stream>>>(fc1_w + (size_t)l * 65536, w1T, 128, 512);
        k_prep_w<<<dim3(4, 16), dim3(32, 8), 0, stream>>>(fc2_w + (size_t)l * 65536, w2T, 512, 128);
    }
    k_prep_bias<<<dim3(112, 4, 2), 112, 0, stream>>>(rpb, biasbT);

    for (int layer = 0; layer < 2; layer++) {
        unsigned short* wqT = wbase + (size_t)layer * 196608;
        unsigned short* wpT = wqT + 49152;
        unsigned short* w1T = wpT + 16384;
        unsigned short* w2T = w1T + 65536;
        int shifted = layer & 1;

        k_qkv<<<TOK_TOTAL / 64, 256, 0, stream>>>(xbuf, ln1_g + layer * 128, ln1_b + layer * 128,
                                                  wqT, qkv_b + layer * 384, qkbuf, vTbuf, shifted);
        k_attn_proj<<<BNW, 256, 0, stream>>>(qkbuf, vTbuf, biasbT + (size_t)layer * 4 * 112 * 112,
                                             wpT, proj_b + layer * 128, xbuf, shifted);
        k_mlp<<<TOK_TOTAL / 64, 128, 0, stream>>>(xbuf, ln2_g + layer * 128, ln2_b + layer * 128,
                                                  w1T, fc1_b + layer * 512, w2T, fc2_b + layer * 128, xbuf);
    }

    k_transpose_out<<<dim3(PSPAT / 32, 4, BB), dim3(32, 8), 0, stream>>>(xbuf, out);
}

// Round 8
// 980.802 us; speedup vs baseline: 1.4722x; 1.1661x over previous
//
#include <hip/hip_runtime.h>
#include <hip/hip_bf16.h>

typedef __attribute__((ext_vector_type(8))) short sv8_t;   // 8 bf16 (4 VGPR)
typedef __attribute__((ext_vector_type(4))) float fv4_t;   // MFMA accumulator
typedef __attribute__((ext_vector_type(4))) float f4ld_t;  // global float4 load

#define BB 8
#define TT 8
#define HH 56
#define WW2 56
#define NTOK 98
#define BNW 2048
#define PSPAT 25088
#define TOK_TOTAL 200704
#define ACT_ELEMS 25690112
#define VT_WSTRIDE 14336   // 128 * 112

#define SWZB(row, cb) ((cb) ^ ((((unsigned)(row)) & 7u) << 4))

__device__ __forceinline__ unsigned short f2bf(float f) {
    union { float f; unsigned u; } x; x.f = f;
    unsigned r = x.u + 0x7fffu + ((x.u >> 16) & 1u);
    return (unsigned short)(r >> 16);
}
__device__ __forceinline__ unsigned packbf(float lo, float hi) {
    return (unsigned)f2bf(lo) | ((unsigned)f2bf(hi) << 16);
}
__device__ __forceinline__ sv8_t lds_ld8(const unsigned short* p, int byteoff) {
    return *(const sv8_t*)((const char*)p + byteoff);
}
__device__ __forceinline__ void lds_st8(unsigned short* p, int byteoff, sv8_t v) {
    *(sv8_t*)((char*)p + byteoff) = v;
}
__device__ __forceinline__ void lds_st1(unsigned short* p, int byteoff, unsigned short v) {
    *(unsigned short*)((char*)p + byteoff) = v;
}
// GELU, tanh form via hardware exp (~10 VALU ops vs erff's ~30)
__device__ __forceinline__ float gelu_f(float v) {
    float u = v * (0.7978845608028654f + 0.035677408136300125f * v * v);
    float e = __expf(2.f * u);
    float th = 1.f - 2.f / (e + 1.f);
    return 0.5f * v * (1.f + th);
}

// ---------------- transpose in: (B,C,P) -> (B,P,C) f32 ----------------
__global__ __launch_bounds__(256) void k_transpose_in(const float* __restrict__ in,
                                                      float* __restrict__ xbuf) {
    __shared__ float tile[32][33];
    int p0 = blockIdx.x * 32, c0 = blockIdx.y * 32, b = blockIdx.z;
    int pi = threadIdx.x, ci = threadIdx.y;
    const float* src = in + ((size_t)b * 128 + c0) * PSPAT + p0;
    for (int r = 0; r < 32; r += 8)
        tile[ci + r][pi] = src[(size_t)(ci + r) * PSPAT + pi];
    __syncthreads();
    float* dst = xbuf + ((size_t)b * PSPAT + p0) * 128 + c0;
    for (int r = 0; r < 32; r += 8)
        dst[(size_t)(ci + r) * 128 + pi] = tile[pi][ci + r];
}

// ---------------- transpose out: (B,P,C) -> (B,C,P) ----------------
__global__ __launch_bounds__(256) void k_transpose_out(const float* __restrict__ xbuf,
                                                       float* __restrict__ out) {
    __shared__ float tile[32][33];
    int p0 = blockIdx.x * 32, c0 = blockIdx.y * 32, b = blockIdx.z;
    int pi = threadIdx.x, ci = threadIdx.y;
    const float* src = xbuf + ((size_t)b * PSPAT + p0) * 128 + c0;
    for (int r = 0; r < 32; r += 8)
        tile[ci + r][pi] = src[(size_t)(ci + r) * 128 + pi];
    __syncthreads();
    float* dst = out + ((size_t)b * 128 + c0) * PSPAT + p0;
    for (int r = 0; r < 32; r += 8)
        dst[(size_t)(ci + r) * PSPAT + pi] = tile[pi][ci + r];
}

// ---------------- weight prep: in f32 [K][N] -> out bf16 [N][K] ----------------
__global__ __launch_bounds__(256) void k_prep_w(const float* __restrict__ in,
                                                unsigned short* __restrict__ out,
                                                int K, int N) {
    __shared__ float tile[32][33];
    int n0 = blockIdx.x * 32, k0 = blockIdx.y * 32;
    int x = threadIdx.x, y = threadIdx.y;
    for (int r = 0; r < 32; r += 8)
        tile[y + r][x] = in[(size_t)(k0 + y + r) * N + n0 + x];
    __syncthreads();
    for (int r = 0; r < 32; r += 8)
        out[(size_t)(n0 + y + r) * K + k0 + x] = f2bf(tile[x][y + r]);
}

// ---------------- bias prep: biasbT[layer][head][col(112)][row(112)] ----------------
__global__ void k_prep_bias(const float* __restrict__ rpb, float* __restrict__ biasbT) {
    int row = threadIdx.x;   // 0..111 (q index)
    int col = blockIdx.x;    // 0..111 (k index)
    int head = blockIdx.y;   // 0..3
    int layer = blockIdx.z;
    int tn = min(row, 97), tm = min(col, 97);
    int itn = tn / 49, rn = tn - itn * 49, ihn = rn / 7, iwn = rn - ihn * 7;
    int itm = tm / 49, rm = tm - itm * 49, ihm = rm / 7, iwm = rm - ihm * 7;
    int dt = itn - itm + 1, dh = ihn - ihm + 6, dw = iwn - iwm + 6;
    float v = rpb[((size_t)layer * 507 + dt * 169 + dh * 13 + dw) * 4 + head];
    biasbT[(((size_t)layer * 4 + head) * 112 + col) * 112 + row] = v;
}

// ---------------- fused LN1 + gather + qkv GEMM ----------------
__global__ __launch_bounds__(256) void k_qkv(const float* __restrict__ xbuf,
                                             const float* __restrict__ g,
                                             const float* __restrict__ be,
                                             const unsigned short* __restrict__ wT,  // [384][128]
                                             const float* __restrict__ bias,         // [384]
                                             unsigned short* __restrict__ qkbuf,
                                             unsigned short* __restrict__ vT,
                                             int shifted) {
    __shared__ unsigned short xt[64 * 128];
    int tid = threadIdx.x;
    int row0 = blockIdx.x * 64;
    {
        int r = tid >> 2, q = tid & 3;
        int wt = row0 + r;
        int win = wt / 98, n = wt - win * 98;
        int b_ = win >> 8, wrem = win & 255;
        int tw = wrem >> 6, hw = (wrem >> 3) & 7, ww = wrem & 7;
        int it = n / 49, r2 = n - it * 49, ih = r2 / 7, iw = r2 - ih * 7;
        int t = tw * 2 + it, h = hw * 7 + ih, w = ww * 7 + iw;
        if (shifted) {
            t += 1; if (t >= TT) t -= TT;
            h += 3; if (h >= HH) h -= HH;
            w += 3; if (w >= WW2) w -= WW2;
        }
        const float* src = xbuf + ((size_t)b_ * PSPAT + t * (HH * WW2) + h * WW2 + w) * 128 + q * 32;
        float v[32];
        float s = 0.f, sq = 0.f;
        for (int i = 0; i < 8; i++) {
            f4ld_t f = *(const f4ld_t*)(src + i * 4);
            v[i * 4 + 0] = f.x; v[i * 4 + 1] = f.y; v[i * 4 + 2] = f.z; v[i * 4 + 3] = f.w;
            s += f.x + f.y + f.z + f.w;
            sq += f.x * f.x + f.y * f.y + f.z * f.z + f.w * f.w;
        }
        s += __shfl_xor(s, 1); sq += __shfl_xor(sq, 1);
        s += __shfl_xor(s, 2); sq += __shfl_xor(sq, 2);
        float mu = s * (1.f / 128.f);
        float var = sq * (1.f / 128.f) - mu * mu;
        float rs = rsqrtf(var + 1e-5f);
        for (int c0 = 0; c0 < 32; c0 += 8) {
            sv8_t o;
            #pragma unroll
            for (int i = 0; i < 8; i++) {
                int c = q * 32 + c0 + i;
                o[i] = (short)f2bf((v[c0 + i] - mu) * rs * g[c] + be[c]);
            }
            lds_st8(xt, r * 256 + SWZB(r, (q * 32 + c0) * 2), o);
        }
    }
    __syncthreads();
    int wv = tid >> 6, lane = tid & 63, l15 = lane & 15, lhi = lane >> 4;

    if (wv < 2) {
        int nb = wv * 128;
        fv4_t acc[4][8];
        for (int m = 0; m < 4; m++) for (int j = 0; j < 8; j++) acc[m][j] = (fv4_t){0.f, 0.f, 0.f, 0.f};
        for (int kk = 0; kk < 4; kk++) {
            sv8_t a[4];
            #pragma unroll
            for (int m = 0; m < 4; m++) {
                int ar = 16 * m + l15;
                a[m] = lds_ld8(xt, ar * 256 + SWZB(ar, (kk * 32 + 8 * lhi) * 2));
            }
            #pragma unroll
            for (int j = 0; j < 8; j++) {
                sv8_t b = *(const sv8_t*)(wT + (size_t)(nb + 16 * j + l15) * 128 + kk * 32 + 8 * lhi);
                #pragma unroll
                for (int m = 0; m < 4; m++)
                    acc[m][j] = __builtin_amdgcn_mfma_f32_16x16x32_bf16(a[m], b, acc[m][j], 0, 0, 0);
            }
        }
        float sc_ = (wv == 0) ? 0.17677669529663687f : 1.f;
        for (int j = 0; j < 8; j++) {
            int col = nb + 16 * j + l15;
            float bb = bias[col];
            #pragma unroll
            for (int m = 0; m < 4; m++)
                #pragma unroll
                for (int r = 0; r < 4; r++) {
                    int row = row0 + 16 * m + lhi * 4 + r;
                    qkbuf[(size_t)row * 256 + col] = f2bf((acc[m][j][r] + bb) * sc_);
                }
        }
    } else {
        int d16base = (wv - 2) * 4;
        fv4_t acc[4][4];   // [m][f]
        for (int m = 0; m < 4; m++) for (int f = 0; f < 4; f++) acc[m][f] = (fv4_t){0.f, 0.f, 0.f, 0.f};
        for (int kk = 0; kk < 4; kk++) {
            sv8_t x4[4];
            #pragma unroll
            for (int m = 0; m < 4; m++) {
                int ar = 16 * m + l15;
                x4[m] = lds_ld8(xt, ar * 256 + SWZB(ar, (kk * 32 + 8 * lhi) * 2));
            }
            #pragma unroll
            for (int f = 0; f < 4; f++) {
                sv8_t wf = *(const sv8_t*)(wT + (size_t)(256 + (d16base + f) * 16 + l15) * 128 + kk * 32 + 8 * lhi);
                #pragma unroll
                for (int m = 0; m < 4; m++)
                    acc[m][f] = __builtin_amdgcn_mfma_f32_16x16x32_bf16(wf, x4[m], acc[m][f], 0, 0, 0);
            }
        }
        #pragma unroll
        for (int f = 0; f < 4; f++) {
            f4ld_t b4 = *(const f4ld_t*)(bias + 256 + (d16base + f) * 16 + 4 * lhi);
            #pragma unroll
            for (int r = 0; r < 4; r++) {
                int d = (d16base + f) * 16 + 4 * lhi + r;
                #pragma unroll
                for (int m = 0; m < 4; m++) {
                    int row = row0 + 16 * m + l15;
                    int win = row / 98, tok = row - win * 98;
                    vT[(size_t)win * VT_WSTRIDE + d * 112 + tok] = f2bf(acc[m][f][r] + b4[r]);
                }
            }
        }
    }
}

// ---------------- attention core + proj, one block per window ----------------
__global__ __launch_bounds__(256) void k_attn_proj(const unsigned short* __restrict__ qk,
                                                   const unsigned short* __restrict__ vT,
                                                   const float* __restrict__ biasbT, // [4][112 col][112 row]
                                                   const unsigned short* __restrict__ pwT, // [128][128]
                                                   const float* __restrict__ pb,
                                                   float* __restrict__ xbuf,
                                                   int shifted) {
    __shared__ unsigned short pt[4 * 16 * 128];
    __shared__ unsigned short ot[112 * 128];
    __shared__ int lablut[112];
    int win = blockIdx.x;
    int tid = threadIdx.x;
    int wv = tid >> 6, lane = tid & 63;
    int head = wv;
    int l15 = lane & 15, lhi = lane >> 4;
    int wrem = win & 255;
    int tw = wrem >> 6, hw = (wrem >> 3) & 7, ww = wrem & 7;

    for (int m = tid; m < 112; m += 256) {
        int t0 = min(m, 97);
        int it = t0 / 49, r2 = t0 - it * 49, ih = r2 / 7, iw = r2 - ih * 7;
        int lab = 0;
        if (shifted) {
            int t = tw * 2 + it, h = hw * 7 + ih, w = ww * 7 + iw;
            int ct = (t < TT - 2) ? 0 : ((t < TT - 1) ? 1 : 2);
            int ch = (h < HH - 7) ? 0 : ((h < HH - 3) ? 1 : 2);
            int cw = (w < WW2 - 7) ? 0 : ((w < WW2 - 3) ? 1 : 2);
            lab = ct * 9 + ch * 3 + cw;
        }
        lablut[m] = lab;
    }
    {
        unsigned short* myp = pt + wv * 16 * 128;
        for (int idx = lane; idx < 256; idx += 64) {
            int r = idx >> 4, c = 112 + (idx & 15);
            lds_st1(myp, r * 256 + SWZB(r, c * 2), 0);
        }
    }
    __syncthreads();

    size_t rowbase = (size_t)win * 98;
    sv8_t kf[7];
    #pragma unroll
    for (int j = 0; j < 7; j++) {
        int tok = min(16 * j + l15, 97);
        kf[j] = *(const sv8_t*)(qk + (rowbase + tok) * 256 + 128 + head * 32 + 8 * lhi);
    }
    const unsigned short* vbase = vT + (size_t)win * VT_WSTRIDE + (head * 32) * 112;
    sv8_t vf[4][2];
    #pragma unroll
    for (int kk = 0; kk < 4; kk++)
        #pragma unroll
        for (int j = 0; j < 2; j++)
            vf[kk][j] = *(const sv8_t*)(vbase + (16 * j + l15) * 112 + kk * 32 + 8 * lhi);

    unsigned short* myp = pt + wv * 16 * 128;
    const float* bsliceT = biasbT + (size_t)head * 112 * 112;

    for (int ms = 0; ms < 7; ms++) {
        int qtok = min(16 * ms + l15, 97);
        sv8_t qa = *(const sv8_t*)(qk + (rowbase + qtok) * 256 + head * 32 + 8 * lhi);
        f4ld_t bv[7];
        #pragma unroll
        for (int j = 0; j < 7; j++)
            bv[j] = *(const f4ld_t*)(bsliceT + (16 * j + l15) * 112 + 16 * ms + 4 * lhi);
        fv4_t sc[7];
        __builtin_amdgcn_s_setprio(1);
        #pragma unroll
        for (int j = 0; j < 7; j++) {
            fv4_t z = {0.f, 0.f, 0.f, 0.f};
            sc[j] = __builtin_amdgcn_mfma_f32_16x16x32_bf16(qa, kf[j], z, 0, 0, 0);
        }
        __builtin_amdgcn_s_setprio(0);
        float mx[4] = {-1e30f, -1e30f, -1e30f, -1e30f};
        int rowt[4];
        #pragma unroll
        for (int r = 0; r < 4; r++) rowt[r] = 16 * ms + lhi * 4 + r;
        #pragma unroll
        for (int j = 0; j < 7; j++) {
            int col = 16 * j + l15;
            int labc = lablut[col];
            bool colpad = (col >= 98);
            #pragma unroll
            for (int r = 0; r < 4; r++) {
                float s = sc[j][r] + bv[j][r];
                if (shifted && labc != lablut[rowt[r]]) s -= 100.f;
                if (colpad) s = -1e30f;
                sc[j][r] = s;
                mx[r] = fmaxf(mx[r], s);
            }
        }
        #pragma unroll
        for (int o = 1; o < 16; o <<= 1)
            #pragma unroll
            for (int r = 0; r < 4; r++) mx[r] = fmaxf(mx[r], __shfl_xor(mx[r], o));
        float sm[4] = {0.f, 0.f, 0.f, 0.f};
        #pragma unroll
        for (int j = 0; j < 7; j++)
            #pragma unroll
            for (int r = 0; r < 4; r++) {
                float p = __expf(sc[j][r] - mx[r]);
                sc[j][r] = p;
                sm[r] += p;
            }
        #pragma unroll
        for (int o = 1; o < 16; o <<= 1)
            #pragma unroll
            for (int r = 0; r < 4; r++) sm[r] += __shfl_xor(sm[r], o);
        #pragma unroll
        for (int j = 0; j < 7; j++)
            #pragma unroll
            for (int r = 0; r < 4; r++) {
                int pr = lhi * 4 + r, pc = 16 * j + l15;
                lds_st1(myp, pr * 256 + SWZB(pr, pc * 2), f2bf(sc[j][r]));
            }
        fv4_t oacc[2] = {{0.f, 0.f, 0.f, 0.f}, {0.f, 0.f, 0.f, 0.f}};
        __builtin_amdgcn_s_setprio(1);
        for (int kk = 0; kk < 4; kk++) {
            sv8_t pa = lds_ld8(myp, l15 * 256 + SWZB(l15, (kk * 32 + 8 * lhi) * 2));
            #pragma unroll
            for (int j = 0; j < 2; j++)
                oacc[j] = __builtin_amdgcn_mfma_f32_16x16x32_bf16(pa, vf[kk][j], oacc[j], 0, 0, 0);
        }
        __builtin_amdgcn_s_setprio(0);
        #pragma unroll
        for (int r = 0; r < 4; r++) {
            int orow = rowt[r];
            float inv = 1.f / sm[r];
            #pragma unroll
            for (int j = 0; j < 2; j++) {
                int ocol = head * 32 + 16 * j + l15;
                float v = (orow < 98) ? oacc[j][r] * inv : 0.f;
                lds_st1(ot, orow * 256 + SWZB(orow, ocol * 2), f2bf(v));
            }
        }
    }
    __syncthreads();

    {
        int nb = wv * 32;
        fv4_t acc[7][2];
        for (int m = 0; m < 7; m++) for (int j = 0; j < 2; j++) acc[m][j] = (fv4_t){0.f, 0.f, 0.f, 0.f};
        for (int kk = 0; kk < 4; kk++) {
            sv8_t b[2];
            #pragma unroll
            for (int j = 0; j < 2; j++)
                b[j] = *(const sv8_t*)(pwT + (size_t)(nb + 16 * j + l15) * 128 + kk * 32 + 8 * lhi);
            __builtin_amdgcn_s_setprio(1);
            #pragma unroll
            for (int m = 0; m < 7; m++) {
                int ar = 16 * m + l15;
                sv8_t a = lds_ld8(ot, ar * 256 + SWZB(ar, (kk * 32 + 8 * lhi) * 2));
                #pragma unroll
                for (int j = 0; j < 2; j++)
                    acc[m][j] = __builtin_amdgcn_mfma_f32_16x16x32_bf16(a, b[j], acc[m][j], 0, 0, 0);
            }
            __builtin_amdgcn_s_setprio(0);
        }
        int b_ = win >> 8;
        for (int m = 0; m < 7; m++)
            #pragma unroll
            for (int r = 0; r < 4; r++) {
                int row = 16 * m + lhi * 4 + r;
                if (row < 98) {
                    int it = row / 49, r2 = row - it * 49, ih = r2 / 7, iw = r2 - ih * 7;
                    int t = tw * 2 + it, h = hw * 7 + ih, w = ww * 7 + iw;
                    if (shifted) {
                        t += 1; if (t >= TT) t -= TT;
                        h += 3; if (h >= HH) h -= HH;
                        w += 3; if (w >= WW2) w -= WW2;
                    }
                    float* xp = xbuf + ((size_t)b_ * PSPAT + t * (HH * WW2) + h * WW2 + w) * 128 + nb;
                    #pragma unroll
                    for (int j = 0; j < 2; j++) {
                        int c = 16 * j + l15;
                        xp[c] += acc[m][j][r] + pb[nb + c];
                    }
                }
            }
    }
}

// ---------------- fused LN2 + fc1 + GELU + fc2 + residual ----------------
// Block-cooperative: 4 waves / 128 tokens. Weight quarters staged into a shared
// 32 KB LDS region (reg-staged, XOR-swizzled ds_write; conflict-free swizzled
// ds_read_b128). Each wave keeps its verified 32-token swapped-operand MFMA
// structure; w2q global loads are issued before fc1 so their latency hides
// under fc1 compute (T14). LDS 64 KB -> 2 blocks/CU.
__global__ __launch_bounds__(256, 2) void k_mlp(const float* __restrict__ xin,
                                                const float* __restrict__ g,
                                                const float* __restrict__ be,
                                                const unsigned short* __restrict__ w1T,  // [512][128]
                                                const float* __restrict__ b1p,
                                                const unsigned short* __restrict__ w2T,  // [128][512]
                                                const float* __restrict__ b2p,
                                                float* __restrict__ xbuf) {
    __shared__ unsigned short A[4][32 * 128];   // 32 KB: per-wave xt then U slice
    __shared__ unsigned short Bst[128 * 128];   // 32 KB: staged weight quarter
    int tid = threadIdx.x;
    int wv = tid >> 6, lane = tid & 63, l15 = lane & 15, lhi = lane >> 4;
    unsigned short* bw = A[wv];
    int tok0 = blockIdx.x * 128 + wv * 32;

    // ---- LN (wave-private xt in A[wv])
    #pragma unroll
    for (int tf = 0; tf < 2; tf++) {
        int lrow = 16 * tf + l15;
        const float* src = xin + (size_t)(tok0 + lrow) * 128 + lhi * 32;
        float v[32];
        float s = 0.f, sq = 0.f;
        #pragma unroll
        for (int i = 0; i < 8; i++) {
            f4ld_t f = *(const f4ld_t*)(src + i * 4);
            v[i * 4 + 0] = f.x; v[i * 4 + 1] = f.y; v[i * 4 + 2] = f.z; v[i * 4 + 3] = f.w;
            s += f.x + f.y + f.z + f.w;
            sq += f.x * f.x + f.y * f.y + f.z * f.z + f.w * f.w;
        }
        s += __shfl_xor(s, 16); sq += __shfl_xor(sq, 16);
        s += __shfl_xor(s, 32); sq += __shfl_xor(sq, 32);
        float mu = s * (1.f / 128.f);
        float var = sq * (1.f / 128.f) - mu * mu;
        float rs = rsqrtf(var + 1e-5f);
        #pragma unroll
        for (int j = 0; j < 4; j++) {
            int c0 = lhi * 32 + 8 * j;
            f4ld_t g0 = *(const f4ld_t*)(g + c0);
            f4ld_t g1 = *(const f4ld_t*)(g + c0 + 4);
            f4ld_t b0 = *(const f4ld_t*)(be + c0);
            f4ld_t b1 = *(const f4ld_t*)(be + c0 + 4);
            float y0 = (v[8 * j + 0] - mu) * rs * g0.x + b0.x;
            float y1 = (v[8 * j + 1] - mu) * rs * g0.y + b0.y;
            float y2 = (v[8 * j + 2] - mu) * rs * g0.z + b0.z;
            float y3 = (v[8 * j + 3] - mu) * rs * g0.w + b0.w;
            float y4 = (v[8 * j + 4] - mu) * rs * g1.x + b1.x;
            float y5 = (v[8 * j + 5] - mu) * rs * g1.y + b1.y;
            float y6 = (v[8 * j + 6] - mu) * rs * g1.z + b1.z;
            float y7 = (v[8 * j + 7] - mu) * rs * g1.w + b1.w;
            union { unsigned u[4]; sv8_t s8; } pk;
            pk.u[0] = packbf(y0, y1); pk.u[1] = packbf(y2, y3);
            pk.u[2] = packbf(y4, y5); pk.u[3] = packbf(y6, y7);
            lds_st8(bw, lrow * 256 + SWZB(lrow, 64 * lhi + 16 * j), pk.s8);
        }
    }
    // x fragments to registers (frees A[wv] for U reuse)
    sv8_t xf[2][4];
    #pragma unroll
    for (int tf = 0; tf < 2; tf++)
        #pragma unroll
        for (int kk = 0; kk < 4; kk++) {
            int lrow = 16 * tf + l15;
            xf[tf][kk] = lds_ld8(bw, lrow * 256 + SWZB(lrow, 64 * kk + 16 * lhi));
        }

    fv4_t acc2[8][2];
    #pragma unroll
    for (int cg = 0; cg < 8; cg++)
        #pragma unroll
        for (int tf = 0; tf < 2; tf++) acc2[cg][tf] = (fv4_t){0.f, 0.f, 0.f, 0.f};

    for (int q = 0; q < 4; q++) {
        // ---- load w1 quarter to regs (batched), stage into Bst (swizzled)
        sv8_t w1r[8];
        #pragma unroll
        for (int i = 0; i < 8; i++) {
            int s = i * 256 + tid, row = s >> 4, colb = (s & 15) * 16;
            w1r[i] = *(const sv8_t*)(w1T + (size_t)(q * 128 + row) * 128 + (colb >> 1));
        }
        if (q > 0) __syncthreads();        // prev fc2 done reading Bst
        #pragma unroll
        for (int i = 0; i < 8; i++) {
            int s = i * 256 + tid, row = s >> 4, colb = (s & 15) * 16;
            lds_st8(Bst, row * 256 + SWZB(row, colb), w1r[i]);
        }
        __syncthreads();
        // ---- issue w2 quarter loads NOW; latency hides under fc1 (T14)
        sv8_t w2r[8];
        #pragma unroll
        for (int i = 0; i < 8; i++) {
            int s = i * 256 + tid, row = s >> 4, colb = (s & 15) * 16;
            w2r[i] = *(const sv8_t*)(w2T + (size_t)row * 512 + q * 128 + (colb >> 1));
        }
        // ---- fc1: U^T quarter = mfma(w1 frag from LDS, x frag)
        #pragma unroll
        for (int f = 0; f < 8; f++) {
            sv8_t wf[4];
            #pragma unroll
            for (int kk = 0; kk < 4; kk++) {
                int wrow = 16 * f + l15;
                wf[kk] = lds_ld8(Bst, wrow * 256 + SWZB(wrow, kk * 64 + 16 * lhi));
            }
            fv4_t a1[2] = {{0.f, 0.f, 0.f, 0.f}, {0.f, 0.f, 0.f, 0.f}};
            __builtin_amdgcn_s_setprio(1);
            #pragma unroll
            for (int kk = 0; kk < 4; kk++) {
                a1[0] = __builtin_amdgcn_mfma_f32_16x16x32_bf16(wf[kk], xf[0][kk], a1[0], 0, 0, 0);
                a1[1] = __builtin_amdgcn_mfma_f32_16x16x32_bf16(wf[kk], xf[1][kk], a1[1], 0, 0, 0);
            }
            __builtin_amdgcn_s_setprio(0);
            f4ld_t b4 = *(const f4ld_t*)(b1p + q * 128 + 16 * f + 4 * lhi);
            #pragma unroll
            for (int tf = 0; tf < 2; tf++) {
                float g0 = gelu_f(a1[tf][0] + b4.x);
                float g1 = gelu_f(a1[tf][1] + b4.y);
                float g2 = gelu_f(a1[tf][2] + b4.z);
                float g3 = gelu_f(a1[tf][3] + b4.w);
                union { unsigned u[2]; uint2 u2; } pk;
                pk.u[0] = packbf(g0, g1); pk.u[1] = packbf(g2, g3);
                int lrow = 16 * tf + l15;
                *(uint2*)((char*)bw + lrow * 256 + SWZB(lrow, 32 * f + 8 * lhi)) = pk.u2;
            }
        }
        __syncthreads();                   // all fc1 reads of Bst done
        #pragma unroll
        for (int i = 0; i < 8; i++) {
            int s = i * 256 + tid, row = s >> 4, colb = (s & 15) * 16;
            lds_st8(Bst, row * 256 + SWZB(row, colb), w2r[i]);
        }
        __syncthreads();
        // ---- fc2 quarter: Out^T += mfma(w2 frag from LDS, U frag)
        #pragma unroll
        for (int kq = 0; kq < 4; kq++) {
            sv8_t uf[2];
            #pragma unroll
            for (int tf = 0; tf < 2; tf++) {
                int lrow = 16 * tf + l15;
                uf[tf] = lds_ld8(bw, lrow * 256 + SWZB(lrow, 64 * kq + 16 * lhi));
            }
            #pragma unroll
            for (int cb = 0; cb < 2; cb++) {
                sv8_t w2f[4];
                #pragma unroll
                for (int c = 0; c < 4; c++) {
                    int wrow = 16 * (4 * cb + c) + l15;
                    w2f[c] = lds_ld8(Bst, wrow * 256 + SWZB(wrow, kq * 64 + 16 * lhi));
                }
                __builtin_amdgcn_s_setprio(1);
                #pragma unroll
                for (int c = 0; c < 4; c++) {
                    int cg = 4 * cb + c;
                    acc2[cg][0] = __builtin_amdgcn_mfma_f32_16x16x32_bf16(w2f[c], uf[0], acc2[cg][0], 0, 0, 0);
                    acc2[cg][1] = __builtin_amdgcn_mfma_f32_16x16x32_bf16(w2f[c], uf[1], acc2[cg][1], 0, 0, 0);
                }
                __builtin_amdgcn_s_setprio(0);
            }
        }
    }
    // ---- epilogue: out[tok][16cg+4lhi+r] += acc2 + b2  (float4 RMW)
    #pragma unroll
    for (int tf = 0; tf < 2; tf++) {
        int row = tok0 + 16 * tf + l15;
        #pragma unroll
        for (int cg = 0; cg < 8; cg++) {
            int c0 = 16 * cg + 4 * lhi;
            f4ld_t b4 = *(const f4ld_t*)(b2p + c0);
            float* xp = xbuf + (size_t)row * 128 + c0;
            f4ld_t o = *(f4ld_t*)xp;
            o.x += acc2[cg][tf][0] + b4.x;
            o.y += acc2[cg][tf][1] + b4.y;
            o.z += acc2[cg][tf][2] + b4.z;
            o.w += acc2[cg][tf][3] + b4.w;
            *(f4ld_t*)xp = o;
        }
    }
}

extern "C" void kernel_launch(void* const* d_in, const int* in_sizes, int n_in,
                              void* d_out, int out_size, void* d_ws, size_t ws_size,
                              hipStream_t stream) {
    const float* x_in   = (const float*)d_in[0];
    const float* ln1_g  = (const float*)d_in[1];
    const float* ln1_b  = (const float*)d_in[2];
    const float* qkv_w  = (const float*)d_in[3];
    const float* qkv_b  = (const float*)d_in[4];
    const float* rpb    = (const float*)d_in[5];
    const float* proj_w = (const float*)d_in[6];
    const float* proj_b = (const float*)d_in[7];
    const float* ln2_g  = (const float*)d_in[8];
    const float* ln2_b  = (const float*)d_in[9];
    const float* fc1_w  = (const float*)d_in[10];
    const float* fc1_b  = (const float*)d_in[11];
    const float* fc2_w  = (const float*)d_in[12];
    const float* fc2_b  = (const float*)d_in[13];
    float* out = (float*)d_out;

    char* ws = (char*)d_ws;
    float* xbuf = (float*)ws;                                        // 102,760,448 B
    unsigned short* qkbuf = (unsigned short*)(ws + 102760448);       // 102,760,448 B
    unsigned short* vTbuf = (unsigned short*)(ws + 205520896);       //  58,720,256 B
    unsigned short* wbase = (unsigned short*)(ws + 264241408);       //     786,432 B
    float* biasbT = (float*)(ws + 264241408 + 786432);               //     401,408 B

    k_transpose_in<<<dim3(PSPAT / 32, 4, BB), dim3(32, 8), 0, stream>>>(x_in, xbuf);

    for (int l = 0; l < 2; l++) {
        unsigned short* wqT = wbase + (size_t)l * 196608;
        unsigned short* wpT = wqT + 49152;
        unsigned short* w1T = wpT + 16384;
        unsigned short* w2T = w1T + 65536;
        k_prep_w<<<dim3(12, 4), dim3(32, 8), 0, stream>>>(qkv_w + (size_t)l * 49152, wqT, 128, 384);
        k_prep_w<<<dim3(4, 4),  dim3(32, 8), 0, stream>>>(proj_w + (size_t)l * 16384, wpT, 128, 128);
        k_prep_w<<<dim3(16, 4), dim3(32, 8), 0, stream>>>(fc1_w + (size_t)l * 65536, w1T, 128, 512);
        k_prep_w<<<dim3(4, 16), dim3(32, 8), 0, stream>>>(fc2_w + (size_t)l * 65536, w2T, 512, 128);
    }
    k_prep_bias<<<dim3(112, 4, 2), 112, 0, stream>>>(rpb, biasbT);

    for (int layer = 0; layer < 2; layer++) {
        unsigned short* wqT = wbase + (size_t)layer * 196608;
        unsigned short* wpT = wqT + 49152;
        unsigned short* w1T = wpT + 16384;
        unsigned short* w2T = w1T + 65536;
        int shifted = layer & 1;

        k_qkv<<<TOK_TOTAL / 64, 256, 0, stream>>>(xbuf, ln1_g + layer * 128, ln1_b + layer * 128,
                                                  wqT, qkv_b + layer * 384, qkbuf, vTbuf, shifted);
        k_attn_proj<<<BNW, 256, 0, stream>>>(qkbuf, vTbuf, biasbT + (size_t)layer * 4 * 112 * 112,
                                             wpT, proj_b + layer * 128, xbuf, shifted);
        k_mlp<<<TOK_TOTAL / 128, 256, 0, stream>>>(xbuf, ln2_g + layer * 128, ln2_b + layer * 128,
                                                   w1T, fc1_b + layer * 512, w2T, fc2_b + layer * 128, xbuf);
    }

    k_transpose_out<<<dim3(PSPAT / 32, 4, BB), dim3(32, 8), 0, stream>>>(xbuf, out);
}

// Round 9
// 976.759 us; speedup vs baseline: 1.4782x; 1.0041x over previous
//
#include <hip/hip_runtime.h>
#include <hip/hip_bf16.h>

typedef __attribute__((ext_vector_type(8))) short sv8_t;   // 8 bf16 (4 VGPR)
typedef __attribute__((ext_vector_type(4))) float fv4_t;   // MFMA accumulator
typedef __attribute__((ext_vector_type(4))) float f4ld_t;  // global float4 load

#define BB 8
#define TT 8
#define HH 56
#define WW2 56
#define NTOK 98
#define BNW 2048
#define PSPAT 25088
#define TOK_TOTAL 200704
#define ACT_ELEMS 25690112
#define VT_WSTRIDE 14336   // 128 * 112

#define SWZB(row, cb) ((cb) ^ ((((unsigned)(row)) & 7u) << 4))

__device__ __forceinline__ unsigned short f2bf(float f) {
    union { float f; unsigned u; } x; x.f = f;
    unsigned r = x.u + 0x7fffu + ((x.u >> 16) & 1u);
    return (unsigned short)(r >> 16);
}
// packed pair via v_cvt_pk_bf16_f32 (RNE, bit-identical to f2bf pair, 1 inst)
__device__ __forceinline__ unsigned packbf(float lo, float hi) {
    __hip_bfloat162 h = __float22bfloat162_rn(make_float2(lo, hi));
    union { __hip_bfloat162 h; unsigned u; } cv; cv.h = h; return cv.u;
}
__device__ __forceinline__ sv8_t lds_ld8(const unsigned short* p, int byteoff) {
    return *(const sv8_t*)((const char*)p + byteoff);
}
__device__ __forceinline__ void lds_st8(unsigned short* p, int byteoff, sv8_t v) {
    *(sv8_t*)((char*)p + byteoff) = v;
}
__device__ __forceinline__ void lds_st1(unsigned short* p, int byteoff, unsigned short v) {
    *(unsigned short*)((char*)p + byteoff) = v;
}
// GELU, tanh form via hardware exp (~10 VALU ops vs erff's ~30)
__device__ __forceinline__ float gelu_f(float v) {
    float u = v * (0.7978845608028654f + 0.035677408136300125f * v * v);
    float e = __expf(2.f * u);
    float th = 1.f - 2.f / (e + 1.f);
    return 0.5f * v * (1.f + th);
}

// ---------------- transpose in: (B,C,P) -> (B,P,C) f32 ----------------
__global__ __launch_bounds__(256) void k_transpose_in(const float* __restrict__ in,
                                                      float* __restrict__ xbuf) {
    __shared__ float tile[32][33];
    int p0 = blockIdx.x * 32, c0 = blockIdx.y * 32, b = blockIdx.z;
    int pi = threadIdx.x, ci = threadIdx.y;
    const float* src = in + ((size_t)b * 128 + c0) * PSPAT + p0;
    for (int r = 0; r < 32; r += 8)
        tile[ci + r][pi] = src[(size_t)(ci + r) * PSPAT + pi];
    __syncthreads();
    float* dst = xbuf + ((size_t)b * PSPAT + p0) * 128 + c0;
    for (int r = 0; r < 32; r += 8)
        dst[(size_t)(ci + r) * 128 + pi] = tile[pi][ci + r];
}

// ---------------- transpose out: (B,P,C) -> (B,C,P) ----------------
__global__ __launch_bounds__(256) void k_transpose_out(const float* __restrict__ xbuf,
                                                       float* __restrict__ out) {
    __shared__ float tile[32][33];
    int p0 = blockIdx.x * 32, c0 = blockIdx.y * 32, b = blockIdx.z;
    int pi = threadIdx.x, ci = threadIdx.y;
    const float* src = xbuf + ((size_t)b * PSPAT + p0) * 128 + c0;
    for (int r = 0; r < 32; r += 8)
        tile[ci + r][pi] = src[(size_t)(ci + r) * 128 + pi];
    __syncthreads();
    float* dst = out + ((size_t)b * 128 + c0) * PSPAT + p0;
    for (int r = 0; r < 32; r += 8)
        dst[(size_t)(ci + r) * PSPAT + pi] = tile[pi][ci + r];
}

// ---------------- weight prep: in f32 [K][N] -> out bf16 [N][K] ----------------
__global__ __launch_bounds__(256) void k_prep_w(const float* __restrict__ in,
                                                unsigned short* __restrict__ out,
                                                int K, int N) {
    __shared__ float tile[32][33];
    int n0 = blockIdx.x * 32, k0 = blockIdx.y * 32;
    int x = threadIdx.x, y = threadIdx.y;
    for (int r = 0; r < 32; r += 8)
        tile[y + r][x] = in[(size_t)(k0 + y + r) * N + n0 + x];
    __syncthreads();
    for (int r = 0; r < 32; r += 8)
        out[(size_t)(n0 + y + r) * K + k0 + x] = f2bf(tile[x][y + r]);
}

// ---------------- bias prep: biasbT[layer][head][col(112)][row(112)] ----------------
__global__ void k_prep_bias(const float* __restrict__ rpb, float* __restrict__ biasbT) {
    int row = threadIdx.x;   // 0..111 (q index)
    int col = blockIdx.x;    // 0..111 (k index)
    int head = blockIdx.y;   // 0..3
    int layer = blockIdx.z;
    int tn = min(row, 97), tm = min(col, 97);
    int itn = tn / 49, rn = tn - itn * 49, ihn = rn / 7, iwn = rn - ihn * 7;
    int itm = tm / 49, rm = tm - itm * 49, ihm = rm / 7, iwm = rm - ihm * 7;
    int dt = itn - itm + 1, dh = ihn - ihm + 6, dw = iwn - iwm + 6;
    float v = rpb[((size_t)layer * 507 + dt * 169 + dh * 13 + dw) * 4 + head];
    biasbT[(((size_t)layer * 4 + head) * 112 + col) * 112 + row] = v;
}

// ---------------- fused LN1 + gather + qkv GEMM ----------------
__global__ __launch_bounds__(256) void k_qkv(const float* __restrict__ xbuf,
                                             const float* __restrict__ g,
                                             const float* __restrict__ be,
                                             const unsigned short* __restrict__ wT,  // [384][128]
                                             const float* __restrict__ bias,         // [384]
                                             unsigned short* __restrict__ qkbuf,
                                             unsigned short* __restrict__ vT,
                                             int shifted) {
    __shared__ unsigned short xt[64 * 128];
    int tid = threadIdx.x;
    int row0 = blockIdx.x * 64;
    {
        int r = tid >> 2, q = tid & 3;
        int wt = row0 + r;
        int win = wt / 98, n = wt - win * 98;
        int b_ = win >> 8, wrem = win & 255;
        int tw = wrem >> 6, hw = (wrem >> 3) & 7, ww = wrem & 7;
        int it = n / 49, r2 = n - it * 49, ih = r2 / 7, iw = r2 - ih * 7;
        int t = tw * 2 + it, h = hw * 7 + ih, w = ww * 7 + iw;
        if (shifted) {
            t += 1; if (t >= TT) t -= TT;
            h += 3; if (h >= HH) h -= HH;
            w += 3; if (w >= WW2) w -= WW2;
        }
        const float* src = xbuf + ((size_t)b_ * PSPAT + t * (HH * WW2) + h * WW2 + w) * 128 + q * 32;
        float v[32];
        float s = 0.f, sq = 0.f;
        for (int i = 0; i < 8; i++) {
            f4ld_t f = *(const f4ld_t*)(src + i * 4);
            v[i * 4 + 0] = f.x; v[i * 4 + 1] = f.y; v[i * 4 + 2] = f.z; v[i * 4 + 3] = f.w;
            s += f.x + f.y + f.z + f.w;
            sq += f.x * f.x + f.y * f.y + f.z * f.z + f.w * f.w;
        }
        s += __shfl_xor(s, 1); sq += __shfl_xor(sq, 1);
        s += __shfl_xor(s, 2); sq += __shfl_xor(sq, 2);
        float mu = s * (1.f / 128.f);
        float var = sq * (1.f / 128.f) - mu * mu;
        float rs = rsqrtf(var + 1e-5f);
        for (int c0 = 0; c0 < 32; c0 += 8) {
            float y[8];
            #pragma unroll
            for (int i = 0; i < 8; i++) {
                int c = q * 32 + c0 + i;
                y[i] = (v[c0 + i] - mu) * rs * g[c] + be[c];
            }
            union { unsigned u[4]; sv8_t s8; } pk;
            pk.u[0] = packbf(y[0], y[1]); pk.u[1] = packbf(y[2], y[3]);
            pk.u[2] = packbf(y[4], y[5]); pk.u[3] = packbf(y[6], y[7]);
            lds_st8(xt, r * 256 + SWZB(r, (q * 32 + c0) * 2), pk.s8);
        }
    }
    __syncthreads();
    int wv = tid >> 6, lane = tid & 63, l15 = lane & 15, lhi = lane >> 4;

    if (wv < 2) {
        int nb = wv * 128;
        fv4_t acc[4][8];
        for (int m = 0; m < 4; m++) for (int j = 0; j < 8; j++) acc[m][j] = (fv4_t){0.f, 0.f, 0.f, 0.f};
        for (int kk = 0; kk < 4; kk++) {
            sv8_t a[4];
            #pragma unroll
            for (int m = 0; m < 4; m++) {
                int ar = 16 * m + l15;
                a[m] = lds_ld8(xt, ar * 256 + SWZB(ar, (kk * 32 + 8 * lhi) * 2));
            }
            #pragma unroll
            for (int j = 0; j < 8; j++) {
                sv8_t b = *(const sv8_t*)(wT + (size_t)(nb + 16 * j + l15) * 128 + kk * 32 + 8 * lhi);
                #pragma unroll
                for (int m = 0; m < 4; m++)
                    acc[m][j] = __builtin_amdgcn_mfma_f32_16x16x32_bf16(a[m], b, acc[m][j], 0, 0, 0);
            }
        }
        float sc_ = (wv == 0) ? 0.17677669529663687f : 1.f;
        for (int j = 0; j < 8; j++) {
            int col = nb + 16 * j + l15;
            float bb = bias[col];
            #pragma unroll
            for (int m = 0; m < 4; m++)
                #pragma unroll
                for (int r = 0; r < 4; r++) {
                    int row = row0 + 16 * m + lhi * 4 + r;
                    qkbuf[(size_t)row * 256 + col] = f2bf((acc[m][j][r] + bb) * sc_);
                }
        }
    } else {
        int d16base = (wv - 2) * 4;
        fv4_t acc[4][4];   // [m][f]
        for (int m = 0; m < 4; m++) for (int f = 0; f < 4; f++) acc[m][f] = (fv4_t){0.f, 0.f, 0.f, 0.f};
        for (int kk = 0; kk < 4; kk++) {
            sv8_t x4[4];
            #pragma unroll
            for (int m = 0; m < 4; m++) {
                int ar = 16 * m + l15;
                x4[m] = lds_ld8(xt, ar * 256 + SWZB(ar, (kk * 32 + 8 * lhi) * 2));
            }
            #pragma unroll
            for (int f = 0; f < 4; f++) {
                sv8_t wf = *(const sv8_t*)(wT + (size_t)(256 + (d16base + f) * 16 + l15) * 128 + kk * 32 + 8 * lhi);
                #pragma unroll
                for (int m = 0; m < 4; m++)
                    acc[m][f] = __builtin_amdgcn_mfma_f32_16x16x32_bf16(wf, x4[m], acc[m][f], 0, 0, 0);
            }
        }
        #pragma unroll
        for (int f = 0; f < 4; f++) {
            f4ld_t b4 = *(const f4ld_t*)(bias + 256 + (d16base + f) * 16 + 4 * lhi);
            #pragma unroll
            for (int r = 0; r < 4; r++) {
                int d = (d16base + f) * 16 + 4 * lhi + r;
                #pragma unroll
                for (int m = 0; m < 4; m++) {
                    int row = row0 + 16 * m + l15;
                    int win = row / 98, tok = row - win * 98;
                    vT[(size_t)win * VT_WSTRIDE + d * 112 + tok] = f2bf(acc[m][f][r] + b4[r]);
                }
            }
        }
    }
}

// ---------------- attention core + proj, one block per window ----------------
__global__ __launch_bounds__(256) void k_attn_proj(const unsigned short* __restrict__ qk,
                                                   const unsigned short* __restrict__ vT,
                                                   const float* __restrict__ biasbT, // [4][112 col][112 row]
                                                   const unsigned short* __restrict__ pwT, // [128][128]
                                                   const float* __restrict__ pb,
                                                   float* __restrict__ xbuf,
                                                   int shifted) {
    __shared__ unsigned short pt[4 * 16 * 128];
    __shared__ unsigned short ot[112 * 128];
    __shared__ int lablut[112];
    int win = blockIdx.x;
    int tid = threadIdx.x;
    int wv = tid >> 6, lane = tid & 63;
    int head = wv;
    int l15 = lane & 15, lhi = lane >> 4;
    int wrem = win & 255;
    int tw = wrem >> 6, hw = (wrem >> 3) & 7, ww = wrem & 7;

    for (int m = tid; m < 112; m += 256) {
        int t0 = min(m, 97);
        int it = t0 / 49, r2 = t0 - it * 49, ih = r2 / 7, iw = r2 - ih * 7;
        int lab = 0;
        if (shifted) {
            int t = tw * 2 + it, h = hw * 7 + ih, w = ww * 7 + iw;
            int ct = (t < TT - 2) ? 0 : ((t < TT - 1) ? 1 : 2);
            int ch = (h < HH - 7) ? 0 : ((h < HH - 3) ? 1 : 2);
            int cw = (w < WW2 - 7) ? 0 : ((w < WW2 - 3) ? 1 : 2);
            lab = ct * 9 + ch * 3 + cw;
        }
        lablut[m] = lab;
    }
    {
        unsigned short* myp = pt + wv * 16 * 128;
        for (int idx = lane; idx < 256; idx += 64) {
            int r = idx >> 4, c = 112 + (idx & 15);
            lds_st1(myp, r * 256 + SWZB(r, c * 2), 0);
        }
    }
    __syncthreads();

    size_t rowbase = (size_t)win * 98;
    sv8_t kf[7];
    #pragma unroll
    for (int j = 0; j < 7; j++) {
        int tok = min(16 * j + l15, 97);
        kf[j] = *(const sv8_t*)(qk + (rowbase + tok) * 256 + 128 + head * 32 + 8 * lhi);
    }
    const unsigned short* vbase = vT + (size_t)win * VT_WSTRIDE + (head * 32) * 112;
    sv8_t vf[4][2];
    #pragma unroll
    for (int kk = 0; kk < 4; kk++)
        #pragma unroll
        for (int j = 0; j < 2; j++)
            vf[kk][j] = *(const sv8_t*)(vbase + (16 * j + l15) * 112 + kk * 32 + 8 * lhi);

    unsigned short* myp = pt + wv * 16 * 128;
    const float* bsliceT = biasbT + (size_t)head * 112 * 112;

    // qa 1-deep pipeline: load ms+1's Q fragment during ms body
    sv8_t qa_c = *(const sv8_t*)(qk + (rowbase + l15) * 256 + head * 32 + 8 * lhi);

    for (int ms = 0; ms < 7; ms++) {
        sv8_t qa_n = qa_c;
        if (ms < 6) {
            int qtok = min(16 * (ms + 1) + l15, 97);
            qa_n = *(const sv8_t*)(qk + (rowbase + qtok) * 256 + head * 32 + 8 * lhi);
        }
        f4ld_t bv[7];
        #pragma unroll
        for (int j = 0; j < 7; j++)
            bv[j] = *(const f4ld_t*)(bsliceT + (16 * j + l15) * 112 + 16 * ms + 4 * lhi);
        fv4_t sc[7];
        __builtin_amdgcn_s_setprio(1);
        #pragma unroll
        for (int j = 0; j < 7; j++) {
            fv4_t z = {0.f, 0.f, 0.f, 0.f};
            sc[j] = __builtin_amdgcn_mfma_f32_16x16x32_bf16(qa_c, kf[j], z, 0, 0, 0);
        }
        __builtin_amdgcn_s_setprio(0);
        float mx[4] = {-1e30f, -1e30f, -1e30f, -1e30f};
        int rowt[4];
        #pragma unroll
        for (int r = 0; r < 4; r++) rowt[r] = 16 * ms + lhi * 4 + r;
        #pragma unroll
        for (int j = 0; j < 7; j++) {
            int col = 16 * j + l15;
            int labc = lablut[col];
            bool colpad = (col >= 98);
            #pragma unroll
            for (int r = 0; r < 4; r++) {
                float s = sc[j][r] + bv[j][r];
                if (shifted && labc != lablut[rowt[r]]) s -= 100.f;
                if (colpad) s = -1e30f;
                sc[j][r] = s;
                mx[r] = fmaxf(mx[r], s);
            }
        }
        #pragma unroll
        for (int o = 1; o < 16; o <<= 1)
            #pragma unroll
            for (int r = 0; r < 4; r++) mx[r] = fmaxf(mx[r], __shfl_xor(mx[r], o));
        float sm[4] = {0.f, 0.f, 0.f, 0.f};
        #pragma unroll
        for (int j = 0; j < 7; j++)
            #pragma unroll
            for (int r = 0; r < 4; r++) {
                float p = __expf(sc[j][r] - mx[r]);
                sc[j][r] = p;
                sm[r] += p;
            }
        #pragma unroll
        for (int o = 1; o < 16; o <<= 1)
            #pragma unroll
            for (int r = 0; r < 4; r++) sm[r] += __shfl_xor(sm[r], o);
        #pragma unroll
        for (int j = 0; j < 7; j++)
            #pragma unroll
            for (int r = 0; r < 4; r++) {
                int pr = lhi * 4 + r, pc = 16 * j + l15;
                lds_st1(myp, pr * 256 + SWZB(pr, pc * 2), f2bf(sc[j][r]));
            }
        fv4_t oacc[2] = {{0.f, 0.f, 0.f, 0.f}, {0.f, 0.f, 0.f, 0.f}};
        __builtin_amdgcn_s_setprio(1);
        for (int kk = 0; kk < 4; kk++) {
            sv8_t pa = lds_ld8(myp, l15 * 256 + SWZB(l15, (kk * 32 + 8 * lhi) * 2));
            #pragma unroll
            for (int j = 0; j < 2; j++)
                oacc[j] = __builtin_amdgcn_mfma_f32_16x16x32_bf16(pa, vf[kk][j], oacc[j], 0, 0, 0);
        }
        __builtin_amdgcn_s_setprio(0);
        #pragma unroll
        for (int r = 0; r < 4; r++) {
            int orow = rowt[r];
            float inv = 1.f / sm[r];
            #pragma unroll
            for (int j = 0; j < 2; j++) {
                int ocol = head * 32 + 16 * j + l15;
                float v = (orow < 98) ? oacc[j][r] * inv : 0.f;
                lds_st1(ot, orow * 256 + SWZB(orow, ocol * 2), f2bf(v));
            }
        }
        qa_c = qa_n;
    }
    __syncthreads();

    {
        int nb = wv * 32;
        fv4_t acc[7][2];
        for (int m = 0; m < 7; m++) for (int j = 0; j < 2; j++) acc[m][j] = (fv4_t){0.f, 0.f, 0.f, 0.f};
        for (int kk = 0; kk < 4; kk++) {
            sv8_t b[2];
            #pragma unroll
            for (int j = 0; j < 2; j++)
                b[j] = *(const sv8_t*)(pwT + (size_t)(nb + 16 * j + l15) * 128 + kk * 32 + 8 * lhi);
            __builtin_amdgcn_s_setprio(1);
            #pragma unroll
            for (int m = 0; m < 7; m++) {
                int ar = 16 * m + l15;
                sv8_t a = lds_ld8(ot, ar * 256 + SWZB(ar, (kk * 32 + 8 * lhi) * 2));
                #pragma unroll
                for (int j = 0; j < 2; j++)
                    acc[m][j] = __builtin_amdgcn_mfma_f32_16x16x32_bf16(a, b[j], acc[m][j], 0, 0, 0);
            }
            __builtin_amdgcn_s_setprio(0);
        }
        int b_ = win >> 8;
        for (int m = 0; m < 7; m++)
            #pragma unroll
            for (int r = 0; r < 4; r++) {
                int row = 16 * m + lhi * 4 + r;
                if (row < 98) {
                    int it = row / 49, r2 = row - it * 49, ih = r2 / 7, iw = r2 - ih * 7;
                    int t = tw * 2 + it, h = hw * 7 + ih, w = ww * 7 + iw;
                    if (shifted) {
                        t += 1; if (t >= TT) t -= TT;
                        h += 3; if (h >= HH) h -= HH;
                        w += 3; if (w >= WW2) w -= WW2;
                    }
                    float* xp = xbuf + ((size_t)b_ * PSPAT + t * (HH * WW2) + h * WW2 + w) * 128 + nb;
                    #pragma unroll
                    for (int j = 0; j < 2; j++) {
                        int c = 16 * j + l15;
                        xp[c] += acc[m][j][r] + pb[nb + c];
                    }
                }
            }
    }
}

// ---------------- fused LN2 + fc1 + GELU + fc2 + residual ----------------
// Block-cooperative with software-pipelined weight staging: w1r(q+1) loads are
// issued at the start of fc2(q) (hidden under fc2; drained by next iteration's
// first barrier), w1r(0) is issued before the LN phase.
__global__ __launch_bounds__(256, 2) void k_mlp(const float* __restrict__ xin,
                                                const float* __restrict__ g,
                                                const float* __restrict__ be,
                                                const unsigned short* __restrict__ w1T,  // [512][128]
                                                const float* __restrict__ b1p,
                                                const unsigned short* __restrict__ w2T,  // [128][512]
                                                const float* __restrict__ b2p,
                                                float* __restrict__ xbuf) {
    __shared__ unsigned short A[4][32 * 128];   // 32 KB: per-wave xt then U slice
    __shared__ unsigned short Bst[128 * 128];   // 32 KB: staged weight quarter
    int tid = threadIdx.x;
    int wv = tid >> 6, lane = tid & 63, l15 = lane & 15, lhi = lane >> 4;
    unsigned short* bw = A[wv];
    int tok0 = blockIdx.x * 128 + wv * 32;

    // ---- prefetch w1 quarter 0 (hidden under LN)
    int st_row = tid >> 4, st_colb = (tid & 15) * 16;   // staging coords
    sv8_t w1r[8];
    #pragma unroll
    for (int i = 0; i < 8; i++)
        w1r[i] = *(const sv8_t*)(w1T + (size_t)(i * 16 + st_row) * 128 + (st_colb >> 1));

    // ---- LN (wave-private xt in A[wv])
    #pragma unroll
    for (int tf = 0; tf < 2; tf++) {
        int lrow = 16 * tf + l15;
        const float* src = xin + (size_t)(tok0 + lrow) * 128 + lhi * 32;
        float v[32];
        float s = 0.f, sq = 0.f;
        #pragma unroll
        for (int i = 0; i < 8; i++) {
            f4ld_t f = *(const f4ld_t*)(src + i * 4);
            v[i * 4 + 0] = f.x; v[i * 4 + 1] = f.y; v[i * 4 + 2] = f.z; v[i * 4 + 3] = f.w;
            s += f.x + f.y + f.z + f.w;
            sq += f.x * f.x + f.y * f.y + f.z * f.z + f.w * f.w;
        }
        s += __shfl_xor(s, 16); sq += __shfl_xor(sq, 16);
        s += __shfl_xor(s, 32); sq += __shfl_xor(sq, 32);
        float mu = s * (1.f / 128.f);
        float var = sq * (1.f / 128.f) - mu * mu;
        float rs = rsqrtf(var + 1e-5f);
        #pragma unroll
        for (int j = 0; j < 4; j++) {
            int c0 = lhi * 32 + 8 * j;
            f4ld_t g0 = *(const f4ld_t*)(g + c0);
            f4ld_t g1 = *(const f4ld_t*)(g + c0 + 4);
            f4ld_t b0 = *(const f4ld_t*)(be + c0);
            f4ld_t b1 = *(const f4ld_t*)(be + c0 + 4);
            float y0 = (v[8 * j + 0] - mu) * rs * g0.x + b0.x;
            float y1 = (v[8 * j + 1] - mu) * rs * g0.y + b0.y;
            float y2 = (v[8 * j + 2] - mu) * rs * g0.z + b0.z;
            float y3 = (v[8 * j + 3] - mu) * rs * g0.w + b0.w;
            float y4 = (v[8 * j + 4] - mu) * rs * g1.x + b1.x;
            float y5 = (v[8 * j + 5] - mu) * rs * g1.y + b1.y;
            float y6 = (v[8 * j + 6] - mu) * rs * g1.z + b1.z;
            float y7 = (v[8 * j + 7] - mu) * rs * g1.w + b1.w;
            union { unsigned u[4]; sv8_t s8; } pk;
            pk.u[0] = packbf(y0, y1); pk.u[1] = packbf(y2, y3);
            pk.u[2] = packbf(y4, y5); pk.u[3] = packbf(y6, y7);
            lds_st8(bw, lrow * 256 + SWZB(lrow, 64 * lhi + 16 * j), pk.s8);
        }
    }
    // x fragments to registers (frees A[wv] for U reuse)
    sv8_t xf[2][4];
    #pragma unroll
    for (int tf = 0; tf < 2; tf++)
        #pragma unroll
        for (int kk = 0; kk < 4; kk++) {
            int lrow = 16 * tf + l15;
            xf[tf][kk] = lds_ld8(bw, lrow * 256 + SWZB(lrow, 64 * kk + 16 * lhi));
        }

    fv4_t acc2[8][2];
    #pragma unroll
    for (int cg = 0; cg < 8; cg++)
        #pragma unroll
        for (int tf = 0; tf < 2; tf++) acc2[cg][tf] = (fv4_t){0.f, 0.f, 0.f, 0.f};

    for (int q = 0; q < 4; q++) {
        if (q > 0) __syncthreads();        // prev fc2 done reading Bst (w1r ready)
        #pragma unroll
        for (int i = 0; i < 8; i++)
            lds_st8(Bst, (i * 16 + st_row) * 256 + SWZB(i * 16 + st_row, st_colb), w1r[i]);
        __syncthreads();
        // ---- issue w2 quarter loads NOW; latency hides under fc1 (T14)
        sv8_t w2r[8];
        #pragma unroll
        for (int i = 0; i < 8; i++)
            w2r[i] = *(const sv8_t*)(w2T + (size_t)(i * 16 + st_row) * 512 + q * 128 + (st_colb >> 1));
        // ---- fc1: U^T quarter = mfma(w1 frag from LDS, x frag)
        #pragma unroll
        for (int f = 0; f < 8; f++) {
            sv8_t wf[4];
            #pragma unroll
            for (int kk = 0; kk < 4; kk++) {
                int wrow = 16 * f + l15;
                wf[kk] = lds_ld8(Bst, wrow * 256 + SWZB(wrow, kk * 64 + 16 * lhi));
            }
            fv4_t a1[2] = {{0.f, 0.f, 0.f, 0.f}, {0.f, 0.f, 0.f, 0.f}};
            __builtin_amdgcn_s_setprio(1);
            #pragma unroll
            for (int kk = 0; kk < 4; kk++) {
                a1[0] = __builtin_amdgcn_mfma_f32_16x16x32_bf16(wf[kk], xf[0][kk], a1[0], 0, 0, 0);
                a1[1] = __builtin_amdgcn_mfma_f32_16x16x32_bf16(wf[kk], xf[1][kk], a1[1], 0, 0, 0);
            }
            __builtin_amdgcn_s_setprio(0);
            f4ld_t b4 = *(const f4ld_t*)(b1p + q * 128 + 16 * f + 4 * lhi);
            #pragma unroll
            for (int tf = 0; tf < 2; tf++) {
                float g0 = gelu_f(a1[tf][0] + b4.x);
                float g1 = gelu_f(a1[tf][1] + b4.y);
                float g2 = gelu_f(a1[tf][2] + b4.z);
                float g3 = gelu_f(a1[tf][3] + b4.w);
                union { unsigned u[2]; uint2 u2; } pk;
                pk.u[0] = packbf(g0, g1); pk.u[1] = packbf(g2, g3);
                int lrow = 16 * tf + l15;
                *(uint2*)((char*)bw + lrow * 256 + SWZB(lrow, 32 * f + 8 * lhi)) = pk.u2;
            }
        }
        __syncthreads();                   // all fc1 reads of Bst done
        #pragma unroll
        for (int i = 0; i < 8; i++)
            lds_st8(Bst, (i * 16 + st_row) * 256 + SWZB(i * 16 + st_row, st_colb), w2r[i]);
        __syncthreads();
        // ---- prefetch next w1 quarter; hides under fc2, drained at next barrier
        if (q < 3) {
            #pragma unroll
            for (int i = 0; i < 8; i++)
                w1r[i] = *(const sv8_t*)(w1T + (size_t)((q + 1) * 128 + i * 16 + st_row) * 128 + (st_colb >> 1));
        }
        // ---- fc2 quarter: Out^T += mfma(w2 frag from LDS, U frag)
        #pragma unroll
        for (int kq = 0; kq < 4; kq++) {
            sv8_t uf[2];
            #pragma unroll
            for (int tf = 0; tf < 2; tf++) {
                int lrow = 16 * tf + l15;
                uf[tf] = lds_ld8(bw, lrow * 256 + SWZB(lrow, 64 * kq + 16 * lhi));
            }
            #pragma unroll
            for (int cb = 0; cb < 2; cb++) {
                sv8_t w2f[4];
                #pragma unroll
                for (int c = 0; c < 4; c++) {
                    int wrow = 16 * (4 * cb + c) + l15;
                    w2f[c] = lds_ld8(Bst, wrow * 256 + SWZB(wrow, kq * 64 + 16 * lhi));
                }
                __builtin_amdgcn_s_setprio(1);
                #pragma unroll
                for (int c = 0; c < 4; c++) {
                    int cg = 4 * cb + c;
                    acc2[cg][0] = __builtin_amdgcn_mfma_f32_16x16x32_bf16(w2f[c], uf[0], acc2[cg][0], 0, 0, 0);
                    acc2[cg][1] = __builtin_amdgcn_mfma_f32_16x16x32_bf16(w2f[c], uf[1], acc2[cg][1], 0, 0, 0);
                }
                __builtin_amdgcn_s_setprio(0);
            }
        }
    }
    // ---- epilogue: out[tok][16cg+4lhi+r] += acc2 + b2  (float4 RMW)
    #pragma unroll
    for (int tf = 0; tf < 2; tf++) {
        int row = tok0 + 16 * tf + l15;
        #pragma unroll
        for (int cg = 0; cg < 8; cg++) {
            int c0 = 16 * cg + 4 * lhi;
            f4ld_t b4 = *(const f4ld_t*)(b2p + c0);
            float* xp = xbuf + (size_t)row * 128 + c0;
            f4ld_t o = *(f4ld_t*)xp;
            o.x += acc2[cg][tf][0] + b4.x;
            o.y += acc2[cg][tf][1] + b4.y;
            o.z += acc2[cg][tf][2] + b4.z;
            o.w += acc2[cg][tf][3] + b4.w;
            *(f4ld_t*)xp = o;
        }
    }
}

extern "C" void kernel_launch(void* const* d_in, const int* in_sizes, int n_in,
                              void* d_out, int out_size, void* d_ws, size_t ws_size,
                              hipStream_t stream) {
    const float* x_in   = (const float*)d_in[0];
    const float* ln1_g  = (const float*)d_in[1];
    const float* ln1_b  = (const float*)d_in[2];
    const float* qkv_w  = (const float*)d_in[3];
    const float* qkv_b  = (const float*)d_in[4];
    const float* rpb    = (const float*)d_in[5];
    const float* proj_w = (const float*)d_in[6];
    const float* proj_b = (const float*)d_in[7];
    const float* ln2_g  = (const float*)d_in[8];
    const float* ln2_b  = (const float*)d_in[9];
    const float* fc1_w  = (const float*)d_in[10];
    const float* fc1_b  = (const float*)d_in[11];
    const float* fc2_w  = (const float*)d_in[12];
    const float* fc2_b  = (const float*)d_in[13];
    float* out = (float*)d_out;

    char* ws = (char*)d_ws;
    float* xbuf = (float*)ws;                                        // 102,760,448 B
    unsigned short* qkbuf = (unsigned short*)(ws + 102760448);       // 102,760,448 B
    unsigned short* vTbuf = (unsigned short*)(ws + 205520896);       //  58,720,256 B
    unsigned short* wbase = (unsigned short*)(ws + 264241408);       //     786,432 B
    float* biasbT = (float*)(ws + 264241408 + 786432);               //     401,408 B

    k_transpose_in<<<dim3(PSPAT / 32, 4, BB), dim3(32, 8), 0, stream>>>(x_in, xbuf);

    for (int l = 0; l < 2; l++) {
        unsigned short* wqT = wbase + (size_t)l * 196608;
        unsigned short* wpT = wqT + 49152;
        unsigned short* w1T = wpT + 16384;
        unsigned short* w2T = w1T + 65536;
        k_prep_w<<<dim3(12, 4), dim3(32, 8), 0, stream>>>(qkv_w + (size_t)l * 49152, wqT, 128, 384);
        k_prep_w<<<dim3(4, 4),  dim3(32, 8), 0, stream>>>(proj_w + (size_t)l * 16384, wpT, 128, 128);
        k_prep_w<<<dim3(16, 4), dim3(32, 8), 0, stream>>>(fc1_w + (size_t)l * 65536, w1T, 128, 512);
        k_prep_w<<<dim3(4, 16), dim3(32, 8), 0, stream>>>(fc2_w + (size_t)l * 65536, w2T, 512, 128);
    }
    k_prep_bias<<<dim3(112, 4, 2), 112, 0, stream>>>(rpb, biasbT);

    for (int layer = 0; layer < 2; layer++) {
        unsigned short* wqT = wbase + (size_t)layer * 196608;
        unsigned short* wpT = wqT + 49152;
        unsigned short* w1T = wpT + 16384;
        unsigned short* w2T = w1T + 65536;
        int shifted = layer & 1;

        k_qkv<<<TOK_TOTAL / 64, 256, 0, stream>>>(xbuf, ln1_g + layer * 128, ln1_b + layer * 128,
                                                  wqT, qkv_b + layer * 384, qkbuf, vTbuf, shifted);
        k_attn_proj<<<BNW, 256, 0, stream>>>(qkbuf, vTbuf, biasbT + (size_t)layer * 4 * 112 * 112,
                                             wpT, proj_b + layer * 128, xbuf, shifted);
        k_mlp<<<TOK_TOTAL / 128, 256, 0, stream>>>(xbuf, ln2_g + layer * 128, ln2_b + layer * 128,
                                                   w1T, fc1_b + layer * 512, w2T, fc2_b + layer * 128, xbuf);
    }

    k_transpose_out<<<dim3(PSPAT / 32, 4, BB), dim3(32, 8), 0, stream>>>(xbuf, out);
}

// Round 10
// 941.262 us; speedup vs baseline: 1.5340x; 1.0377x over previous
//
#include <hip/hip_runtime.h>
#include <hip/hip_bf16.h>

typedef __attribute__((ext_vector_type(8))) short sv8_t;   // 8 bf16 (4 VGPR)
typedef __attribute__((ext_vector_type(4))) float fv4_t;   // MFMA accumulator
typedef __attribute__((ext_vector_type(4))) float f4ld_t;  // global float4 load

#define BB 8
#define TT 8
#define HH 56
#define WW2 56
#define NTOK 98
#define BNW 2048
#define PSPAT 25088
#define TOK_TOTAL 200704
#define ACT_ELEMS 25690112
#define VT_WSTRIDE 14336   // 128 * 112

#define SWZB(row, cb) ((cb) ^ ((((unsigned)(row)) & 7u) << 4))

__device__ __forceinline__ unsigned short f2bf(float f) {
    union { float f; unsigned u; } x; x.f = f;
    unsigned r = x.u + 0x7fffu + ((x.u >> 16) & 1u);
    return (unsigned short)(r >> 16);
}
// packed pair via v_cvt_pk_bf16_f32 (RNE, bit-identical to f2bf pair, 1 inst)
__device__ __forceinline__ unsigned packbf(float lo, float hi) {
    __hip_bfloat162 h = __float22bfloat162_rn(make_float2(lo, hi));
    union { __hip_bfloat162 h; unsigned u; } cv; cv.h = h; return cv.u;
}
__device__ __forceinline__ sv8_t lds_ld8(const unsigned short* p, int byteoff) {
    return *(const sv8_t*)((const char*)p + byteoff);
}
__device__ __forceinline__ void lds_st8(unsigned short* p, int byteoff, sv8_t v) {
    *(sv8_t*)((char*)p + byteoff) = v;
}
__device__ __forceinline__ void lds_st1(unsigned short* p, int byteoff, unsigned short v) {
    *(unsigned short*)((char*)p + byteoff) = v;
}
// GELU, tanh form via hardware exp (~10 VALU ops vs erff's ~30)
__device__ __forceinline__ float gelu_f(float v) {
    float u = v * (0.7978845608028654f + 0.035677408136300125f * v * v);
    float e = __expf(2.f * u);
    float th = 1.f - 2.f / (e + 1.f);
    return 0.5f * v * (1.f + th);
}

// ---------------- transpose in: (B,C,P) -> (B,P,C) f32 ----------------
__global__ __launch_bounds__(256) void k_transpose_in(const float* __restrict__ in,
                                                      float* __restrict__ xbuf) {
    __shared__ float tile[32][33];
    int p0 = blockIdx.x * 32, c0 = blockIdx.y * 32, b = blockIdx.z;
    int pi = threadIdx.x, ci = threadIdx.y;
    const float* src = in + ((size_t)b * 128 + c0) * PSPAT + p0;
    for (int r = 0; r < 32; r += 8)
        tile[ci + r][pi] = src[(size_t)(ci + r) * PSPAT + pi];
    __syncthreads();
    float* dst = xbuf + ((size_t)b * PSPAT + p0) * 128 + c0;
    for (int r = 0; r < 32; r += 8)
        dst[(size_t)(ci + r) * 128 + pi] = tile[pi][ci + r];
}

// ---------------- transpose out: (B,P,C) -> (B,C,P) ----------------
__global__ __launch_bounds__(256) void k_transpose_out(const float* __restrict__ xbuf,
                                                       float* __restrict__ out) {
    __shared__ float tile[32][33];
    int p0 = blockIdx.x * 32, c0 = blockIdx.y * 32, b = blockIdx.z;
    int pi = threadIdx.x, ci = threadIdx.y;
    const float* src = xbuf + ((size_t)b * PSPAT + p0) * 128 + c0;
    for (int r = 0; r < 32; r += 8)
        tile[ci + r][pi] = src[(size_t)(ci + r) * 128 + pi];
    __syncthreads();
    float* dst = out + ((size_t)b * 128 + c0) * PSPAT + p0;
    for (int r = 0; r < 32; r += 8)
        dst[(size_t)(ci + r) * PSPAT + pi] = tile[pi][ci + r];
}

// ---------------- weight prep: in f32 [K][N] -> out bf16 [N][K] ----------------
__global__ __launch_bounds__(256) void k_prep_w(const float* __restrict__ in,
                                                unsigned short* __restrict__ out,
                                                int K, int N) {
    __shared__ float tile[32][33];
    int n0 = blockIdx.x * 32, k0 = blockIdx.y * 32;
    int x = threadIdx.x, y = threadIdx.y;
    for (int r = 0; r < 32; r += 8)
        tile[y + r][x] = in[(size_t)(k0 + y + r) * N + n0 + x];
    __syncthreads();
    for (int r = 0; r < 32; r += 8)
        out[(size_t)(n0 + y + r) * K + k0 + x] = f2bf(tile[x][y + r]);
}

// ---------------- bias prep: biasb[layer][head][q row][k col] ----------------
__global__ void k_prep_bias(const float* __restrict__ rpb, float* __restrict__ biasb) {
    int col = threadIdx.x;   // 0..111 (k index)
    int row = blockIdx.x;    // 0..111 (q index)
    int head = blockIdx.y;   // 0..3
    int layer = blockIdx.z;
    int tn = min(row, 97), tm = min(col, 97);
    int itn = tn / 49, rn = tn - itn * 49, ihn = rn / 7, iwn = rn - ihn * 7;
    int itm = tm / 49, rm = tm - itm * 49, ihm = rm / 7, iwm = rm - ihm * 7;
    int dt = itn - itm + 1, dh = ihn - ihm + 6, dw = iwn - iwm + 6;
    float v = rpb[((size_t)layer * 507 + dt * 169 + dh * 13 + dw) * 4 + head];
    biasb[(((size_t)layer * 4 + head) * 112 + row) * 112 + col] = v;
}

// ---------------- fused LN1 + gather + qkv GEMM ----------------
__global__ __launch_bounds__(256) void k_qkv(const float* __restrict__ xbuf,
                                             const float* __restrict__ g,
                                             const float* __restrict__ be,
                                             const unsigned short* __restrict__ wT,  // [384][128]
                                             const float* __restrict__ bias,         // [384]
                                             unsigned short* __restrict__ qkbuf,
                                             unsigned short* __restrict__ vT,
                                             int shifted) {
    __shared__ unsigned short xt[64 * 128];
    int tid = threadIdx.x;
    int row0 = blockIdx.x * 64;
    {
        int r = tid >> 2, q = tid & 3;
        int wt = row0 + r;
        int win = wt / 98, n = wt - win * 98;
        int b_ = win >> 8, wrem = win & 255;
        int tw = wrem >> 6, hw = (wrem >> 3) & 7, ww = wrem & 7;
        int it = n / 49, r2 = n - it * 49, ih = r2 / 7, iw = r2 - ih * 7;
        int t = tw * 2 + it, h = hw * 7 + ih, w = ww * 7 + iw;
        if (shifted) {
            t += 1; if (t >= TT) t -= TT;
            h += 3; if (h >= HH) h -= HH;
            w += 3; if (w >= WW2) w -= WW2;
        }
        const float* src = xbuf + ((size_t)b_ * PSPAT + t * (HH * WW2) + h * WW2 + w) * 128 + q * 32;
        float v[32];
        float s = 0.f, sq = 0.f;
        for (int i = 0; i < 8; i++) {
            f4ld_t f = *(const f4ld_t*)(src + i * 4);
            v[i * 4 + 0] = f.x; v[i * 4 + 1] = f.y; v[i * 4 + 2] = f.z; v[i * 4 + 3] = f.w;
            s += f.x + f.y + f.z + f.w;
            sq += f.x * f.x + f.y * f.y + f.z * f.z + f.w * f.w;
        }
        s += __shfl_xor(s, 1); sq += __shfl_xor(sq, 1);
        s += __shfl_xor(s, 2); sq += __shfl_xor(sq, 2);
        float mu = s * (1.f / 128.f);
        float var = sq * (1.f / 128.f) - mu * mu;
        float rs = rsqrtf(var + 1e-5f);
        for (int c0 = 0; c0 < 32; c0 += 8) {
            float y[8];
            #pragma unroll
            for (int i = 0; i < 8; i++) {
                int c = q * 32 + c0 + i;
                y[i] = (v[c0 + i] - mu) * rs * g[c] + be[c];
            }
            union { unsigned u[4]; sv8_t s8; } pk;
            pk.u[0] = packbf(y[0], y[1]); pk.u[1] = packbf(y[2], y[3]);
            pk.u[2] = packbf(y[4], y[5]); pk.u[3] = packbf(y[6], y[7]);
            lds_st8(xt, r * 256 + SWZB(r, (q * 32 + c0) * 2), pk.s8);
        }
    }
    __syncthreads();
    int wv = tid >> 6, lane = tid & 63, l15 = lane & 15, lhi = lane >> 4;

    if (wv < 2) {
        int nb = wv * 128;
        fv4_t acc[4][8];
        for (int m = 0; m < 4; m++) for (int j = 0; j < 8; j++) acc[m][j] = (fv4_t){0.f, 0.f, 0.f, 0.f};
        for (int kk = 0; kk < 4; kk++) {
            sv8_t a[4];
            #pragma unroll
            for (int m = 0; m < 4; m++) {
                int ar = 16 * m + l15;
                a[m] = lds_ld8(xt, ar * 256 + SWZB(ar, (kk * 32 + 8 * lhi) * 2));
            }
            #pragma unroll
            for (int j = 0; j < 8; j++) {
                sv8_t b = *(const sv8_t*)(wT + (size_t)(nb + 16 * j + l15) * 128 + kk * 32 + 8 * lhi);
                #pragma unroll
                for (int m = 0; m < 4; m++)
                    acc[m][j] = __builtin_amdgcn_mfma_f32_16x16x32_bf16(a[m], b, acc[m][j], 0, 0, 0);
            }
        }
        float sc_ = (wv == 0) ? 0.17677669529663687f : 1.f;
        for (int j = 0; j < 8; j++) {
            int col = nb + 16 * j + l15;
            float bb = bias[col];
            #pragma unroll
            for (int m = 0; m < 4; m++)
                #pragma unroll
                for (int r = 0; r < 4; r++) {
                    int row = row0 + 16 * m + lhi * 4 + r;
                    qkbuf[(size_t)row * 256 + col] = f2bf((acc[m][j][r] + bb) * sc_);
                }
        }
    } else {
        int d16base = (wv - 2) * 4;
        fv4_t acc[4][4];   // [m][f]
        for (int m = 0; m < 4; m++) for (int f = 0; f < 4; f++) acc[m][f] = (fv4_t){0.f, 0.f, 0.f, 0.f};
        for (int kk = 0; kk < 4; kk++) {
            sv8_t x4[4];
            #pragma unroll
            for (int m = 0; m < 4; m++) {
                int ar = 16 * m + l15;
                x4[m] = lds_ld8(xt, ar * 256 + SWZB(ar, (kk * 32 + 8 * lhi) * 2));
            }
            #pragma unroll
            for (int f = 0; f < 4; f++) {
                sv8_t wf = *(const sv8_t*)(wT + (size_t)(256 + (d16base + f) * 16 + l15) * 128 + kk * 32 + 8 * lhi);
                #pragma unroll
                for (int m = 0; m < 4; m++)
                    acc[m][f] = __builtin_amdgcn_mfma_f32_16x16x32_bf16(wf, x4[m], acc[m][f], 0, 0, 0);
            }
        }
        #pragma unroll
        for (int f = 0; f < 4; f++) {
            f4ld_t b4 = *(const f4ld_t*)(bias + 256 + (d16base + f) * 16 + 4 * lhi);
            #pragma unroll
            for (int r = 0; r < 4; r++) {
                int d = (d16base + f) * 16 + 4 * lhi + r;
                #pragma unroll
                for (int m = 0; m < 4; m++) {
                    int row = row0 + 16 * m + l15;
                    int win = row / 98, tok = row - win * 98;
                    vT[(size_t)win * VT_WSTRIDE + d * 112 + tok] = f2bf(acc[m][f][r] + b4[r]);
                }
            }
        }
    }
}

// ---------------- attention core + proj, one block per window ----------------
// Swapped QK^T: sc = mfma(K, Q) -> lane holds 28 scores of ONE q-row (q=l15).
// Softmax fully in-lane (2 shfl_xor), P normalized in-lane, b64 P stores.
__global__ __launch_bounds__(256) void k_attn_proj(const unsigned short* __restrict__ qk,
                                                   const unsigned short* __restrict__ vT,
                                                   const float* __restrict__ biasb,  // [4][q 112][k 112]
                                                   const unsigned short* __restrict__ pwT, // [128][128]
                                                   const float* __restrict__ pb,
                                                   float* __restrict__ xbuf,
                                                   int shifted) {
    __shared__ unsigned short pt[4 * 16 * 128];
    __shared__ unsigned short ot[112 * 128];
    __shared__ int lablut[112];
    int win = blockIdx.x;
    int tid = threadIdx.x;
    int wv = tid >> 6, lane = tid & 63;
    int head = wv;
    int l15 = lane & 15, lhi = lane >> 4;
    int wrem = win & 255;
    int tw = wrem >> 6, hw = (wrem >> 3) & 7, ww = wrem & 7;

    for (int m = tid; m < 112; m += 256) {
        int t0 = min(m, 97);
        int it = t0 / 49, r2 = t0 - it * 49, ih = r2 / 7, iw = r2 - ih * 7;
        int lab = 0;
        if (shifted) {
            int t = tw * 2 + it, h = hw * 7 + ih, w = ww * 7 + iw;
            int ct = (t < TT - 2) ? 0 : ((t < TT - 1) ? 1 : 2);
            int ch = (h < HH - 7) ? 0 : ((h < HH - 3) ? 1 : 2);
            int cw = (w < WW2 - 7) ? 0 : ((w < WW2 - 3) ? 1 : 2);
            lab = ct * 9 + ch * 3 + cw;
        }
        lablut[m] = lab;
    }
    {
        unsigned short* myp = pt + wv * 16 * 128;
        for (int idx = lane; idx < 256; idx += 64) {
            int r = idx >> 4, c = 112 + (idx & 15);
            lds_st1(myp, r * 256 + SWZB(r, c * 2), 0);
        }
    }
    __syncthreads();

    size_t rowbase = (size_t)win * 98;
    sv8_t kf[7];
    #pragma unroll
    for (int j = 0; j < 7; j++) {
        int tok = min(16 * j + l15, 97);
        kf[j] = *(const sv8_t*)(qk + (rowbase + tok) * 256 + 128 + head * 32 + 8 * lhi);
    }
    const unsigned short* vbase = vT + (size_t)win * VT_WSTRIDE + (head * 32) * 112;
    sv8_t vf[4][2];
    #pragma unroll
    for (int kk = 0; kk < 4; kk++)
        #pragma unroll
        for (int j = 0; j < 2; j++)
            vf[kk][j] = *(const sv8_t*)(vbase + (16 * j + l15) * 112 + kk * 32 + 8 * lhi);

    // packed k-labels for this lane's 28 k positions (k = 16j + 4lhi + r)
    int klab[7];
    if (shifted) {
        #pragma unroll
        for (int j = 0; j < 7; j++) {
            int kb = 16 * j + 4 * lhi;
            klab[j] = lablut[kb] | (lablut[kb + 1] << 8) | (lablut[kb + 2] << 16) | (lablut[kb + 3] << 24);
        }
    }

    unsigned short* myp = pt + wv * 16 * 128;

    // qa 1-deep pipeline (B-operand now): lane = q-token l15
    sv8_t qa_c = *(const sv8_t*)(qk + (rowbase + l15) * 256 + head * 32 + 8 * lhi);

    for (int ms = 0; ms < 7; ms++) {
        sv8_t qa_n = qa_c;
        if (ms < 6) {
            int qtok = min(16 * (ms + 1) + l15, 97);
            qa_n = *(const sv8_t*)(qk + (rowbase + qtok) * 256 + head * 32 + 8 * lhi);
        }
        int ql = min(16 * ms + l15, 97);
        int labq = shifted ? lablut[ql] : 0;
        const float* bq = biasb + ((size_t)head * 112 + ql) * 112;
        f4ld_t bv[7];
        #pragma unroll
        for (int j = 0; j < 7; j++)
            bv[j] = *(const f4ld_t*)(bq + 16 * j + 4 * lhi);
        fv4_t sc[7];
        __builtin_amdgcn_s_setprio(1);
        #pragma unroll
        for (int j = 0; j < 7; j++) {
            fv4_t z = {0.f, 0.f, 0.f, 0.f};
            sc[j] = __builtin_amdgcn_mfma_f32_16x16x32_bf16(kf[j], qa_c, z, 0, 0, 0);
        }
        __builtin_amdgcn_s_setprio(0);
        float mx = -1e30f;
        #pragma unroll
        for (int j = 0; j < 7; j++) {
            #pragma unroll
            for (int r = 0; r < 4; r++) {
                float s = sc[j][r] + bv[j][r];
                if (shifted && (((klab[j] >> (8 * r)) & 255) != labq)) s -= 100.f;
                if (16 * j + 4 * lhi + r >= 98) s = -1e30f;
                sc[j][r] = s;
                mx = fmaxf(mx, s);
            }
        }
        mx = fmaxf(mx, __shfl_xor(mx, 16));
        mx = fmaxf(mx, __shfl_xor(mx, 32));
        float sm = 0.f;
        #pragma unroll
        for (int j = 0; j < 7; j++)
            #pragma unroll
            for (int r = 0; r < 4; r++) {
                float p = __expf(sc[j][r] - mx);
                sc[j][r] = p;
                sm += p;
            }
        sm += __shfl_xor(sm, 16);
        sm += __shfl_xor(sm, 32);
        float inv = 1.f / sm;
        #pragma unroll
        for (int j = 0; j < 7; j++) {
            union { unsigned u[2]; uint2 u2; } pk;
            pk.u[0] = packbf(sc[j][0] * inv, sc[j][1] * inv);
            pk.u[1] = packbf(sc[j][2] * inv, sc[j][3] * inv);
            *(uint2*)((char*)myp + l15 * 256 + SWZB(l15, (16 * j + 4 * lhi) * 2)) = pk.u2;
        }
        fv4_t oacc[2] = {{0.f, 0.f, 0.f, 0.f}, {0.f, 0.f, 0.f, 0.f}};
        __builtin_amdgcn_s_setprio(1);
        for (int kk = 0; kk < 4; kk++) {
            sv8_t pa = lds_ld8(myp, l15 * 256 + SWZB(l15, (kk * 32 + 8 * lhi) * 2));
            #pragma unroll
            for (int j = 0; j < 2; j++)
                oacc[j] = __builtin_amdgcn_mfma_f32_16x16x32_bf16(pa, vf[kk][j], oacc[j], 0, 0, 0);
        }
        __builtin_amdgcn_s_setprio(0);
        #pragma unroll
        for (int r = 0; r < 4; r++) {
            int orow = 16 * ms + 4 * lhi + r;
            #pragma unroll
            for (int j = 0; j < 2; j++) {
                int ocol = head * 32 + 16 * j + l15;
                float v = (orow < 98) ? oacc[j][r] : 0.f;
                lds_st1(ot, orow * 256 + SWZB(orow, ocol * 2), f2bf(v));
            }
        }
        qa_c = qa_n;
    }
    __syncthreads();

    {
        int nb = wv * 32;
        fv4_t acc[7][2];
        for (int m = 0; m < 7; m++) for (int j = 0; j < 2; j++) acc[m][j] = (fv4_t){0.f, 0.f, 0.f, 0.f};
        for (int kk = 0; kk < 4; kk++) {
            sv8_t b[2];
            #pragma unroll
            for (int j = 0; j < 2; j++)
                b[j] = *(const sv8_t*)(pwT + (size_t)(nb + 16 * j + l15) * 128 + kk * 32 + 8 * lhi);
            __builtin_amdgcn_s_setprio(1);
            #pragma unroll
            for (int m = 0; m < 7; m++) {
                int ar = 16 * m + l15;
                sv8_t a = lds_ld8(ot, ar * 256 + SWZB(ar, (kk * 32 + 8 * lhi) * 2));
                #pragma unroll
                for (int j = 0; j < 2; j++)
                    acc[m][j] = __builtin_amdgcn_mfma_f32_16x16x32_bf16(a, b[j], acc[m][j], 0, 0, 0);
            }
            __builtin_amdgcn_s_setprio(0);
        }
        int b_ = win >> 8;
        for (int m = 0; m < 7; m++)
            #pragma unroll
            for (int r = 0; r < 4; r++) {
                int row = 16 * m + lhi * 4 + r;
                if (row < 98) {
                    int it = row / 49, r2 = row - it * 49, ih = r2 / 7, iw = r2 - ih * 7;
                    int t = tw * 2 + it, h = hw * 7 + ih, w = ww * 7 + iw;
                    if (shifted) {
                        t += 1; if (t >= TT) t -= TT;
                        h += 3; if (h >= HH) h -= HH;
                        w += 3; if (w >= WW2) w -= WW2;
                    }
                    float* xp = xbuf + ((size_t)b_ * PSPAT + t * (HH * WW2) + h * WW2 + w) * 128 + nb;
                    #pragma unroll
                    for (int j = 0; j < 2; j++) {
                        int c = 16 * j + l15;
                        xp[c] += acc[m][j][r] + pb[nb + c];
                    }
                }
            }
    }
}

// ---------------- fused LN2 + fc1 + GELU + fc2 + residual ----------------
// 48 KB LDS (A 32 KB + 16 KB chunk buffer) -> 3 blocks/CU. Weights staged in
// 16 KB half-chunks (w1 h0/h1 as 64x128, w2 h0/h1 as 128x64), each prefetched
// into registers one phase ahead so its load latency hides under MFMA.
__global__ __launch_bounds__(256, 3) void k_mlp(const float* __restrict__ xin,
                                                const float* __restrict__ g,
                                                const float* __restrict__ be,
                                                const unsigned short* __restrict__ w1T,  // [512][128]
                                                const float* __restrict__ b1p,
                                                const unsigned short* __restrict__ w2T,  // [128][512]
                                                const float* __restrict__ b2p,
                                                float* __restrict__ xbuf) {
    __shared__ unsigned short A[4][32 * 128];   // 32 KB: per-wave xt then U slice
    __shared__ unsigned short Bst[8192];        // 16 KB chunk buffer
    int tid = threadIdx.x;
    int wv = tid >> 6, lane = tid & 63, l15 = lane & 15, lhi = lane >> 4;
    unsigned short* bw = A[wv];
    int tok0 = blockIdx.x * 128 + wv * 32;

    // staging coords: w1 chunk = 64 rows x 128 cols (256B rows), 4 sv8/thread
    int r1 = tid >> 4, c1 = (tid & 15) * 16;          // rows +i*16
    // w2 chunk = 128 rows x 64 cols (128B rows), 4 sv8/thread
    int r2 = tid >> 3, c2 = (tid & 7) * 16;           // rows +i*32

    sv8_t wA[4], wB[4];
    #pragma unroll
    for (int i = 0; i < 4; i++)   // prefetch w1(q0,h0)
        wA[i] = *(const sv8_t*)(w1T + (size_t)(i * 16 + r1) * 128 + (c1 >> 1));

    // ---- LN (wave-private xt in A[wv])
    #pragma unroll
    for (int tf = 0; tf < 2; tf++) {
        int lrow = 16 * tf + l15;
        const float* src = xin + (size_t)(tok0 + lrow) * 128 + lhi * 32;
        float v[32];
        float s = 0.f, sq = 0.f;
        #pragma unroll
        for (int i = 0; i < 8; i++) {
            f4ld_t f = *(const f4ld_t*)(src + i * 4);
            v[i * 4 + 0] = f.x; v[i * 4 + 1] = f.y; v[i * 4 + 2] = f.z; v[i * 4 + 3] = f.w;
            s += f.x + f.y + f.z + f.w;
            sq += f.x * f.x + f.y * f.y + f.z * f.z + f.w * f.w;
        }
        s += __shfl_xor(s, 16); sq += __shfl_xor(sq, 16);
        s += __shfl_xor(s, 32); sq += __shfl_xor(sq, 32);
        float mu = s * (1.f / 128.f);
        float var = sq * (1.f / 128.f) - mu * mu;
        float rs = rsqrtf(var + 1e-5f);
        #pragma unroll
        for (int j = 0; j < 4; j++) {
            int c0 = lhi * 32 + 8 * j;
            f4ld_t g0 = *(const f4ld_t*)(g + c0);
            f4ld_t g1 = *(const f4ld_t*)(g + c0 + 4);
            f4ld_t b0 = *(const f4ld_t*)(be + c0);
            f4ld_t b1 = *(const f4ld_t*)(be + c0 + 4);
            float y0 = (v[8 * j + 0] - mu) * rs * g0.x + b0.x;
            float y1 = (v[8 * j + 1] - mu) * rs * g0.y + b0.y;
            float y2 = (v[8 * j + 2] - mu) * rs * g0.z + b0.z;
            float y3 = (v[8 * j + 3] - mu) * rs * g0.w + b0.w;
            float y4 = (v[8 * j + 4] - mu) * rs * g1.x + b1.x;
            float y5 = (v[8 * j + 5] - mu) * rs * g1.y + b1.y;
            float y6 = (v[8 * j + 6] - mu) * rs * g1.z + b1.z;
            float y7 = (v[8 * j + 7] - mu) * rs * g1.w + b1.w;
            union { unsigned u[4]; sv8_t s8; } pk;
            pk.u[0] = packbf(y0, y1); pk.u[1] = packbf(y2, y3);
            pk.u[2] = packbf(y4, y5); pk.u[3] = packbf(y6, y7);
            lds_st8(bw, lrow * 256 + SWZB(lrow, 64 * lhi + 16 * j), pk.s8);
        }
    }
    sv8_t xf[2][4];
    #pragma unroll
    for (int tf = 0; tf < 2; tf++)
        #pragma unroll
        for (int kk = 0; kk < 4; kk++) {
            int lrow = 16 * tf + l15;
            xf[tf][kk] = lds_ld8(bw, lrow * 256 + SWZB(lrow, 64 * kk + 16 * lhi));
        }

    fv4_t acc2[8][2];
    #pragma unroll
    for (int cg = 0; cg < 8; cg++)
        #pragma unroll
        for (int tf = 0; tf < 2; tf++) acc2[cg][tf] = (fv4_t){0.f, 0.f, 0.f, 0.f};

    #pragma unroll
    for (int q = 0; q < 4; q++) {
        if (q) __syncthreads();            // prev fc2-h1 readers done
        // stage w1 h0
        #pragma unroll
        for (int i = 0; i < 4; i++)
            lds_st8(Bst, (i * 16 + r1) * 256 + SWZB(i * 16 + r1, c1), wA[i]);
        __syncthreads();
        #pragma unroll
        for (int i = 0; i < 4; i++)        // issue w1 h1
            wB[i] = *(const sv8_t*)(w1T + (size_t)(q * 128 + 64 + i * 16 + r1) * 128 + (c1 >> 1));
        // fc1 fg = 0..3
        #pragma unroll
        for (int f = 0; f < 4; f++) {
            int fg = f;
            sv8_t wf[4];
            #pragma unroll
            for (int kk = 0; kk < 4; kk++) {
                int wrow = 16 * f + l15;
                wf[kk] = lds_ld8(Bst, wrow * 256 + SWZB(wrow, kk * 64 + 16 * lhi));
            }
            fv4_t a1[2] = {{0.f, 0.f, 0.f, 0.f}, {0.f, 0.f, 0.f, 0.f}};
            __builtin_amdgcn_s_setprio(1);
            #pragma unroll
            for (int kk = 0; kk < 4; kk++) {
                a1[0] = __builtin_amdgcn_mfma_f32_16x16x32_bf16(wf[kk], xf[0][kk], a1[0], 0, 0, 0);
                a1[1] = __builtin_amdgcn_mfma_f32_16x16x32_bf16(wf[kk], xf[1][kk], a1[1], 0, 0, 0);
            }
            __builtin_amdgcn_s_setprio(0);
            f4ld_t b4 = *(const f4ld_t*)(b1p + q * 128 + 16 * fg + 4 * lhi);
            #pragma unroll
            for (int tf = 0; tf < 2; tf++) {
                float g0 = gelu_f(a1[tf][0] + b4.x);
                float g1 = gelu_f(a1[tf][1] + b4.y);
                float g2 = gelu_f(a1[tf][2] + b4.z);
                float g3 = gelu_f(a1[tf][3] + b4.w);
                union { unsigned u[2]; uint2 u2; } pk;
                pk.u[0] = packbf(g0, g1); pk.u[1] = packbf(g2, g3);
                int lrow = 16 * tf + l15;
                *(uint2*)((char*)bw + lrow * 256 + SWZB(lrow, 32 * fg + 8 * lhi)) = pk.u2;
            }
        }
        __syncthreads();
        // stage w1 h1
        #pragma unroll
        for (int i = 0; i < 4; i++)
            lds_st8(Bst, (i * 16 + r1) * 256 + SWZB(i * 16 + r1, c1), wB[i]);
        __syncthreads();
        #pragma unroll
        for (int i = 0; i < 4; i++)        // issue w2 h0
            wA[i] = *(const sv8_t*)(w2T + (size_t)(i * 32 + r2) * 512 + q * 128 + (c2 >> 1));
        // fc1 fg = 4..7
        #pragma unroll
        for (int f = 0; f < 4; f++) {
            int fg = 4 + f;
            sv8_t wf[4];
            #pragma unroll
            for (int kk = 0; kk < 4; kk++) {
                int wrow = 16 * f + l15;
                wf[kk] = lds_ld8(Bst, wrow * 256 + SWZB(wrow, kk * 64 + 16 * lhi));
            }
            fv4_t a1[2] = {{0.f, 0.f, 0.f, 0.f}, {0.f, 0.f, 0.f, 0.f}};
            __builtin_amdgcn_s_setprio(1);
            #pragma unroll
            for (int kk = 0; kk < 4; kk++) {
                a1[0] = __builtin_amdgcn_mfma_f32_16x16x32_bf16(wf[kk], xf[0][kk], a1[0], 0, 0, 0);
                a1[1] = __builtin_amdgcn_mfma_f32_16x16x32_bf16(wf[kk], xf[1][kk], a1[1], 0, 0, 0);
            }
            __builtin_amdgcn_s_setprio(0);
            f4ld_t b4 = *(const f4ld_t*)(b1p + q * 128 + 16 * fg + 4 * lhi);
            #pragma unroll
            for (int tf = 0; tf < 2; tf++) {
                float g0 = gelu_f(a1[tf][0] + b4.x);
                float g1 = gelu_f(a1[tf][1] + b4.y);
                float g2 = gelu_f(a1[tf][2] + b4.z);
                float g3 = gelu_f(a1[tf][3] + b4.w);
                union { unsigned u[2]; uint2 u2; } pk;
                pk.u[0] = packbf(g0, g1); pk.u[1] = packbf(g2, g3);
                int lrow = 16 * tf + l15;
                *(uint2*)((char*)bw + lrow * 256 + SWZB(lrow, 32 * fg + 8 * lhi)) = pk.u2;
            }
        }
        __syncthreads();
        // stage w2 h0 (128x64 layout)
        #pragma unroll
        for (int i = 0; i < 4; i++)
            lds_st8(Bst, (i * 32 + r2) * 128 + SWZB(i * 32 + r2, c2), wA[i]);
        __syncthreads();
        #pragma unroll
        for (int i = 0; i < 4; i++)        // issue w2 h1
            wB[i] = *(const sv8_t*)(w2T + (size_t)(i * 32 + r2) * 512 + q * 128 + 64 + (c2 >> 1));
        // fc2 kq = 0,1 (k-cols local to h0)
        #pragma unroll
        for (int kq = 0; kq < 2; kq++) {
            sv8_t uf[2];
            #pragma unroll
            for (int tf = 0; tf < 2; tf++) {
                int lrow = 16 * tf + l15;
                uf[tf] = lds_ld8(bw, lrow * 256 + SWZB(lrow, 64 * kq + 16 * lhi));
            }
            #pragma unroll
            for (int cb = 0; cb < 2; cb++) {
                sv8_t w2f[4];
                #pragma unroll
                for (int c = 0; c < 4; c++) {
                    int wrow = 16 * (4 * cb + c) + l15;
                    w2f[c] = lds_ld8(Bst, wrow * 128 + SWZB(wrow, kq * 64 + 16 * lhi));
                }
                __builtin_amdgcn_s_setprio(1);
                #pragma unroll
                for (int c = 0; c < 4; c++) {
                    int cg = 4 * cb + c;
                    acc2[cg][0] = __builtin_amdgcn_mfma_f32_16x16x32_bf16(w2f[c], uf[0], acc2[cg][0], 0, 0, 0);
                    acc2[cg][1] = __builtin_amdgcn_mfma_f32_16x16x32_bf16(w2f[c], uf[1], acc2[cg][1], 0, 0, 0);
                }
                __builtin_amdgcn_s_setprio(0);
            }
        }
        __syncthreads();
        // stage w2 h1
        #pragma unroll
        for (int i = 0; i < 4; i++)
            lds_st8(Bst, (i * 32 + r2) * 128 + SWZB(i * 32 + r2, c2), wB[i]);
        __syncthreads();
        if (q < 3) {
            #pragma unroll
            for (int i = 0; i < 4; i++)    // issue next w1 h0
                wA[i] = *(const sv8_t*)(w1T + (size_t)((q + 1) * 128 + i * 16 + r1) * 128 + (c1 >> 1));
        }
        // fc2 kq = 2,3
        #pragma unroll
        for (int kq = 2; kq < 4; kq++) {
            sv8_t uf[2];
            #pragma unroll
            for (int tf = 0; tf < 2; tf++) {
                int lrow = 16 * tf + l15;
                uf[tf] = lds_ld8(bw, lrow * 256 + SWZB(lrow, 64 * kq + 16 * lhi));
            }
            #pragma unroll
            for (int cb = 0; cb < 2; cb++) {
                sv8_t w2f[4];
                #pragma unroll
                for (int c = 0; c < 4; c++) {
                    int wrow = 16 * (4 * cb + c) + l15;
                    w2f[c] = lds_ld8(Bst, wrow * 128 + SWZB(wrow, (kq - 2) * 64 + 16 * lhi));
                }
                __builtin_amdgcn_s_setprio(1);
                #pragma unroll
                for (int c = 0; c < 4; c++) {
                    int cg = 4 * cb + c;
                    acc2[cg][0] = __builtin_amdgcn_mfma_f32_16x16x32_bf16(w2f[c], uf[0], acc2[cg][0], 0, 0, 0);
                    acc2[cg][1] = __builtin_amdgcn_mfma_f32_16x16x32_bf16(w2f[c], uf[1], acc2[cg][1], 0, 0, 0);
                }
                __builtin_amdgcn_s_setprio(0);
            }
        }
    }
    // ---- epilogue: out[tok][16cg+4lhi+r] += acc2 + b2  (float4 RMW)
    #pragma unroll
    for (int tf = 0; tf < 2; tf++) {
        int row = tok0 + 16 * tf + l15;
        #pragma unroll
        for (int cg = 0; cg < 8; cg++) {
            int c0 = 16 * cg + 4 * lhi;
            f4ld_t b4 = *(const f4ld_t*)(b2p + c0);
            float* xp = xbuf + (size_t)row * 128 + c0;
            f4ld_t o = *(f4ld_t*)xp;
            o.x += acc2[cg][tf][0] + b4.x;
            o.y += acc2[cg][tf][1] + b4.y;
            o.z += acc2[cg][tf][2] + b4.z;
            o.w += acc2[cg][tf][3] + b4.w;
            *(f4ld_t*)xp = o;
        }
    }
}

extern "C" void kernel_launch(void* const* d_in, const int* in_sizes, int n_in,
                              void* d_out, int out_size, void* d_ws, size_t ws_size,
                              hipStream_t stream) {
    const float* x_in   = (const float*)d_in[0];
    const float* ln1_g  = (const float*)d_in[1];
    const float* ln1_b  = (const float*)d_in[2];
    const float* qkv_w  = (const float*)d_in[3];
    const float* qkv_b  = (const float*)d_in[4];
    const float* rpb    = (const float*)d_in[5];
    const float* proj_w = (const float*)d_in[6];
    const float* proj_b = (const float*)d_in[7];
    const float* ln2_g  = (const float*)d_in[8];
    const float* ln2_b  = (const float*)d_in[9];
    const float* fc1_w  = (const float*)d_in[10];
    const float* fc1_b  = (const float*)d_in[11];
    const float* fc2_w  = (const float*)d_in[12];
    const float* fc2_b  = (const float*)d_in[13];
    float* out = (float*)d_out;

    char* ws = (char*)d_ws;
    float* xbuf = (float*)ws;                                        // 102,760,448 B
    unsigned short* qkbuf = (unsigned short*)(ws + 102760448);       // 102,760,448 B
    unsigned short* vTbuf = (unsigned short*)(ws + 205520896);       //  58,720,256 B
    unsigned short* wbase = (unsigned short*)(ws + 264241408);       //     786,432 B
    float* biasb = (float*)(ws + 264241408 + 786432);                //     401,408 B

    k_transpose_in<<<dim3(PSPAT / 32, 4, BB), dim3(32, 8), 0, stream>>>(x_in, xbuf);

    for (int l = 0; l < 2; l++) {
        unsigned short* wqT = wbase + (size_t)l * 196608;
        unsigned short* wpT = wqT + 49152;
        unsigned short* w1T = wpT + 16384;
        unsigned short* w2T = w1T + 65536;
        k_prep_w<<<dim3(12, 4), dim3(32, 8), 0, stream>>>(qkv_w + (size_t)l * 49152, wqT, 128, 384);
        k_prep_w<<<dim3(4, 4),  dim3(32, 8), 0, stream>>>(proj_w + (size_t)l * 16384, wpT, 128, 128);
        k_prep_w<<<dim3(16, 4), dim3(32, 8), 0, stream>>>(fc1_w + (size_t)l * 65536, w1T, 128, 512);
        k_prep_w<<<dim3(4, 16), dim3(32, 8), 0, stream>>>(fc2_w + (size_t)l * 65536, w2T, 512, 128);
    }
    k_prep_bias<<<dim3(112, 4, 2), 112, 0, stream>>>(rpb, biasb);

    for (int layer = 0; layer < 2; layer++) {
        unsigned short* wqT = wbase + (size_t)layer * 196608;
        unsigned short* wpT = wqT + 49152;
        unsigned short* w1T = wpT + 16384;
        unsigned short* w2T = w1T + 65536;
        int shifted = layer & 1;

        k_qkv<<<TOK_TOTAL / 64, 256, 0, stream>>>(xbuf, ln1_g + layer * 128, ln1_b + layer * 128,
                                                  wqT, qkv_b + layer * 384, qkbuf, vTbuf, shifted);
        k_attn_proj<<<BNW, 256, 0, stream>>>(qkbuf, vTbuf, biasb + (size_t)layer * 4 * 112 * 112,
                                             wpT, proj_b + layer * 128, xbuf, shifted);
        k_mlp<<<TOK_TOTAL / 128, 256, 0, stream>>>(xbuf, ln2_g + layer * 128, ln2_b + layer * 128,
                                                   w1T, fc1_b + layer * 512, w2T, fc2_b + layer * 128, xbuf);
    }

    k_transpose_out<<<dim3(PSPAT / 32, 4, BB), dim3(32, 8), 0, stream>>>(xbuf, out);
}

// Round 11
// 889.203 us; speedup vs baseline: 1.6238x; 1.0585x over previous
//
#include <hip/hip_runtime.h>
#include <hip/hip_bf16.h>

typedef __attribute__((ext_vector_type(8))) short sv8_t;   // 8 bf16 (4 VGPR)
typedef __attribute__((ext_vector_type(4))) float fv4_t;   // MFMA accumulator
typedef __attribute__((ext_vector_type(4))) float f4ld_t;  // global float4 load

#define BB 8
#define TT 8
#define HH 56
#define WW2 56
#define NTOK 98
#define BNW 2048
#define PSPAT 25088
#define TOK_TOTAL 200704
#define ACT_ELEMS 25690112
#define VT_WSTRIDE 14336   // 128 * 112

#define SWZB(row, cb) ((cb) ^ ((((unsigned)(row)) & 7u) << 4))

__device__ __forceinline__ unsigned short f2bf(float f) {
    union { float f; unsigned u; } x; x.f = f;
    unsigned r = x.u + 0x7fffu + ((x.u >> 16) & 1u);
    return (unsigned short)(r >> 16);
}
// packed pair via v_cvt_pk_bf16_f32 (RNE, bit-identical to f2bf pair, 1 inst)
__device__ __forceinline__ unsigned packbf(float lo, float hi) {
    __hip_bfloat162 h = __float22bfloat162_rn(make_float2(lo, hi));
    union { __hip_bfloat162 h; unsigned u; } cv; cv.h = h; return cv.u;
}
__device__ __forceinline__ sv8_t lds_ld8(const unsigned short* p, int byteoff) {
    return *(const sv8_t*)((const char*)p + byteoff);
}
__device__ __forceinline__ void lds_st8(unsigned short* p, int byteoff, sv8_t v) {
    *(sv8_t*)((char*)p + byteoff) = v;
}
__device__ __forceinline__ void lds_st1(unsigned short* p, int byteoff, unsigned short v) {
    *(unsigned short*)((char*)p + byteoff) = v;
}
// GELU, tanh form via hardware exp (~10 VALU ops vs erff's ~30)
__device__ __forceinline__ float gelu_f(float v) {
    float u = v * (0.7978845608028654f + 0.035677408136300125f * v * v);
    float e = __expf(2.f * u);
    float th = 1.f - 2.f / (e + 1.f);
    return 0.5f * v * (1.f + th);
}

// ---------------- transpose in: (B,C,P) -> (B,P,C) f32 ----------------
__global__ __launch_bounds__(256) void k_transpose_in(const float* __restrict__ in,
                                                      float* __restrict__ xbuf) {
    __shared__ float tile[32][33];
    int p0 = blockIdx.x * 32, c0 = blockIdx.y * 32, b = blockIdx.z;
    int pi = threadIdx.x, ci = threadIdx.y;
    const float* src = in + ((size_t)b * 128 + c0) * PSPAT + p0;
    for (int r = 0; r < 32; r += 8)
        tile[ci + r][pi] = src[(size_t)(ci + r) * PSPAT + pi];
    __syncthreads();
    float* dst = xbuf + ((size_t)b * PSPAT + p0) * 128 + c0;
    for (int r = 0; r < 32; r += 8)
        dst[(size_t)(ci + r) * 128 + pi] = tile[pi][ci + r];
}

// ---------------- weight prep: in f32 [K][N] -> out bf16 [N][K] ----------------
__global__ __launch_bounds__(256) void k_prep_w(const float* __restrict__ in,
                                                unsigned short* __restrict__ out,
                                                int K, int N) {
    __shared__ float tile[32][33];
    int n0 = blockIdx.x * 32, k0 = blockIdx.y * 32;
    int x = threadIdx.x, y = threadIdx.y;
    for (int r = 0; r < 32; r += 8)
        tile[y + r][x] = in[(size_t)(k0 + y + r) * N + n0 + x];
    __syncthreads();
    for (int r = 0; r < 32; r += 8)
        out[(size_t)(n0 + y + r) * K + k0 + x] = f2bf(tile[x][y + r]);
}

// ---------------- bias prep: biasb[layer][head][q row][k col] ----------------
__global__ void k_prep_bias(const float* __restrict__ rpb, float* __restrict__ biasb) {
    int col = threadIdx.x;   // 0..111 (k index)
    int row = blockIdx.x;    // 0..111 (q index)
    int head = blockIdx.y;   // 0..3
    int layer = blockIdx.z;
    int tn = min(row, 97), tm = min(col, 97);
    int itn = tn / 49, rn = tn - itn * 49, ihn = rn / 7, iwn = rn - ihn * 7;
    int itm = tm / 49, rm = tm - itm * 49, ihm = rm / 7, iwm = rm - ihm * 7;
    int dt = itn - itm + 1, dh = ihn - ihm + 6, dw = iwn - iwm + 6;
    float v = rpb[((size_t)layer * 507 + dt * 169 + dh * 13 + dw) * 4 + head];
    biasb[(((size_t)layer * 4 + head) * 112 + row) * 112 + col] = v;
}

// ---------------- fused LN1 + gather + qkv GEMM ----------------
__global__ __launch_bounds__(256) void k_qkv(const float* __restrict__ xbuf,
                                             const float* __restrict__ g,
                                             const float* __restrict__ be,
                                             const unsigned short* __restrict__ wT,  // [384][128]
                                             const float* __restrict__ bias,         // [384]
                                             unsigned short* __restrict__ qkbuf,
                                             unsigned short* __restrict__ vT,
                                             int shifted) {
    __shared__ unsigned short xt[64 * 128];
    int tid = threadIdx.x;
    int row0 = blockIdx.x * 64;
    {
        int r = tid >> 2, q = tid & 3;
        int wt = row0 + r;
        int win = wt / 98, n = wt - win * 98;
        int b_ = win >> 8, wrem = win & 255;
        int tw = wrem >> 6, hw = (wrem >> 3) & 7, ww = wrem & 7;
        int it = n / 49, r2 = n - it * 49, ih = r2 / 7, iw = r2 - ih * 7;
        int t = tw * 2 + it, h = hw * 7 + ih, w = ww * 7 + iw;
        if (shifted) {
            t += 1; if (t >= TT) t -= TT;
            h += 3; if (h >= HH) h -= HH;
            w += 3; if (w >= WW2) w -= WW2;
        }
        const float* src = xbuf + ((size_t)b_ * PSPAT + t * (HH * WW2) + h * WW2 + w) * 128 + q * 32;
        float v[32];
        float s = 0.f, sq = 0.f;
        for (int i = 0; i < 8; i++) {
            f4ld_t f = *(const f4ld_t*)(src + i * 4);
            v[i * 4 + 0] = f.x; v[i * 4 + 1] = f.y; v[i * 4 + 2] = f.z; v[i * 4 + 3] = f.w;
            s += f.x + f.y + f.z + f.w;
            sq += f.x * f.x + f.y * f.y + f.z * f.z + f.w * f.w;
        }
        s += __shfl_xor(s, 1); sq += __shfl_xor(sq, 1);
        s += __shfl_xor(s, 2); sq += __shfl_xor(sq, 2);
        float mu = s * (1.f / 128.f);
        float var = sq * (1.f / 128.f) - mu * mu;
        float rs = rsqrtf(var + 1e-5f);
        for (int c0 = 0; c0 < 32; c0 += 8) {
            float y[8];
            #pragma unroll
            for (int i = 0; i < 8; i++) {
                int c = q * 32 + c0 + i;
                y[i] = (v[c0 + i] - mu) * rs * g[c] + be[c];
            }
            union { unsigned u[4]; sv8_t s8; } pk;
            pk.u[0] = packbf(y[0], y[1]); pk.u[1] = packbf(y[2], y[3]);
            pk.u[2] = packbf(y[4], y[5]); pk.u[3] = packbf(y[6], y[7]);
            lds_st8(xt, r * 256 + SWZB(r, (q * 32 + c0) * 2), pk.s8);
        }
    }
    __syncthreads();
    int wv = tid >> 6, lane = tid & 63, l15 = lane & 15, lhi = lane >> 4;

    if (wv < 2) {
        int nb = wv * 128;
        fv4_t acc[4][8];
        for (int m = 0; m < 4; m++) for (int j = 0; j < 8; j++) acc[m][j] = (fv4_t){0.f, 0.f, 0.f, 0.f};
        for (int kk = 0; kk < 4; kk++) {
            sv8_t a[4];
            #pragma unroll
            for (int m = 0; m < 4; m++) {
                int ar = 16 * m + l15;
                a[m] = lds_ld8(xt, ar * 256 + SWZB(ar, (kk * 32 + 8 * lhi) * 2));
            }
            #pragma unroll
            for (int j = 0; j < 8; j++) {
                sv8_t b = *(const sv8_t*)(wT + (size_t)(nb + 16 * j + l15) * 128 + kk * 32 + 8 * lhi);
                #pragma unroll
                for (int m = 0; m < 4; m++)
                    acc[m][j] = __builtin_amdgcn_mfma_f32_16x16x32_bf16(a[m], b, acc[m][j], 0, 0, 0);
            }
        }
        float sc_ = (wv == 0) ? 0.17677669529663687f : 1.f;
        for (int j = 0; j < 8; j++) {
            int col = nb + 16 * j + l15;
            float bb = bias[col];
            #pragma unroll
            for (int m = 0; m < 4; m++)
                #pragma unroll
                for (int r = 0; r < 4; r++) {
                    int row = row0 + 16 * m + lhi * 4 + r;
                    qkbuf[(size_t)row * 256 + col] = f2bf((acc[m][j][r] + bb) * sc_);
                }
        }
    } else {
        int d16base = (wv - 2) * 4;
        fv4_t acc[4][4];   // [m][f]
        for (int m = 0; m < 4; m++) for (int f = 0; f < 4; f++) acc[m][f] = (fv4_t){0.f, 0.f, 0.f, 0.f};
        for (int kk = 0; kk < 4; kk++) {
            sv8_t x4[4];
            #pragma unroll
            for (int m = 0; m < 4; m++) {
                int ar = 16 * m + l15;
                x4[m] = lds_ld8(xt, ar * 256 + SWZB(ar, (kk * 32 + 8 * lhi) * 2));
            }
            #pragma unroll
            for (int f = 0; f < 4; f++) {
                sv8_t wf = *(const sv8_t*)(wT + (size_t)(256 + (d16base + f) * 16 + l15) * 128 + kk * 32 + 8 * lhi);
                #pragma unroll
                for (int m = 0; m < 4; m++)
                    acc[m][f] = __builtin_amdgcn_mfma_f32_16x16x32_bf16(wf, x4[m], acc[m][f], 0, 0, 0);
            }
        }
        #pragma unroll
        for (int f = 0; f < 4; f++) {
            f4ld_t b4 = *(const f4ld_t*)(bias + 256 + (d16base + f) * 16 + 4 * lhi);
            #pragma unroll
            for (int r = 0; r < 4; r++) {
                int d = (d16base + f) * 16 + 4 * lhi + r;
                #pragma unroll
                for (int m = 0; m < 4; m++) {
                    int row = row0 + 16 * m + l15;
                    int win = row / 98, tok = row - win * 98;
                    vT[(size_t)win * VT_WSTRIDE + d * 112 + tok] = f2bf(acc[m][f][r] + b4[r]);
                }
            }
        }
    }
}

// ---------------- attention core + proj, one block per window ----------------
__global__ __launch_bounds__(256) void k_attn_proj(const unsigned short* __restrict__ qk,
                                                   const unsigned short* __restrict__ vT,
                                                   const float* __restrict__ biasb,  // [4][q 112][k 112]
                                                   const unsigned short* __restrict__ pwT, // [128][128]
                                                   const float* __restrict__ pb,
                                                   float* __restrict__ xbuf,
                                                   int shifted) {
    __shared__ unsigned short pt[4 * 16 * 128];
    __shared__ unsigned short ot[112 * 128];
    __shared__ int lablut[112];
    int win = blockIdx.x;
    int tid = threadIdx.x;
    int wv = tid >> 6, lane = tid & 63;
    int head = wv;
    int l15 = lane & 15, lhi = lane >> 4;
    int wrem = win & 255;
    int tw = wrem >> 6, hw = (wrem >> 3) & 7, ww = wrem & 7;

    for (int m = tid; m < 112; m += 256) {
        int t0 = min(m, 97);
        int it = t0 / 49, r2 = t0 - it * 49, ih = r2 / 7, iw = r2 - ih * 7;
        int lab = 0;
        if (shifted) {
            int t = tw * 2 + it, h = hw * 7 + ih, w = ww * 7 + iw;
            int ct = (t < TT - 2) ? 0 : ((t < TT - 1) ? 1 : 2);
            int ch = (h < HH - 7) ? 0 : ((h < HH - 3) ? 1 : 2);
            int cw = (w < WW2 - 7) ? 0 : ((w < WW2 - 3) ? 1 : 2);
            lab = ct * 9 + ch * 3 + cw;
        }
        lablut[m] = lab;
    }
    {
        unsigned short* myp = pt + wv * 16 * 128;
        for (int idx = lane; idx < 256; idx += 64) {
            int r = idx >> 4, c = 112 + (idx & 15);
            lds_st1(myp, r * 256 + SWZB(r, c * 2), 0);
        }
    }
    __syncthreads();

    size_t rowbase = (size_t)win * 98;
    sv8_t kf[7];
    #pragma unroll
    for (int j = 0; j < 7; j++) {
        int tok = min(16 * j + l15, 97);
        kf[j] = *(const sv8_t*)(qk + (rowbase + tok) * 256 + 128 + head * 32 + 8 * lhi);
    }
    const unsigned short* vbase = vT + (size_t)win * VT_WSTRIDE + (head * 32) * 112;
    sv8_t vf[4][2];
    #pragma unroll
    for (int kk = 0; kk < 4; kk++)
        #pragma unroll
        for (int j = 0; j < 2; j++)
            vf[kk][j] = *(const sv8_t*)(vbase + (16 * j + l15) * 112 + kk * 32 + 8 * lhi);

    int klab[7];
    if (shifted) {
        #pragma unroll
        for (int j = 0; j < 7; j++) {
            int kb = 16 * j + 4 * lhi;
            klab[j] = lablut[kb] | (lablut[kb + 1] << 8) | (lablut[kb + 2] << 16) | (lablut[kb + 3] << 24);
        }
    }

    unsigned short* myp = pt + wv * 16 * 128;

    sv8_t qa_c = *(const sv8_t*)(qk + (rowbase + l15) * 256 + head * 32 + 8 * lhi);

    for (int ms = 0; ms < 7; ms++) {
        sv8_t qa_n = qa_c;
        if (ms < 6) {
            int qtok = min(16 * (ms + 1) + l15, 97);
            qa_n = *(const sv8_t*)(qk + (rowbase + qtok) * 256 + head * 32 + 8 * lhi);
        }
        int ql = min(16 * ms + l15, 97);
        int labq = shifted ? lablut[ql] : 0;
        const float* bq = biasb + ((size_t)head * 112 + ql) * 112;
        f4ld_t bv[7];
        #pragma unroll
        for (int j = 0; j < 7; j++)
            bv[j] = *(const f4ld_t*)(bq + 16 * j + 4 * lhi);
        fv4_t sc[7];
        __builtin_amdgcn_s_setprio(1);
        #pragma unroll
        for (int j = 0; j < 7; j++) {
            fv4_t z = {0.f, 0.f, 0.f, 0.f};
            sc[j] = __builtin_amdgcn_mfma_f32_16x16x32_bf16(kf[j], qa_c, z, 0, 0, 0);
        }
        __builtin_amdgcn_s_setprio(0);
        float mx = -1e30f;
        #pragma unroll
        for (int j = 0; j < 7; j++) {
            #pragma unroll
            for (int r = 0; r < 4; r++) {
                float s = sc[j][r] + bv[j][r];
                if (shifted && (((klab[j] >> (8 * r)) & 255) != labq)) s -= 100.f;
                if (16 * j + 4 * lhi + r >= 98) s = -1e30f;
                sc[j][r] = s;
                mx = fmaxf(mx, s);
            }
        }
        mx = fmaxf(mx, __shfl_xor(mx, 16));
        mx = fmaxf(mx, __shfl_xor(mx, 32));
        float sm = 0.f;
        #pragma unroll
        for (int j = 0; j < 7; j++)
            #pragma unroll
            for (int r = 0; r < 4; r++) {
                float p = __expf(sc[j][r] - mx);
                sc[j][r] = p;
                sm += p;
            }
        sm += __shfl_xor(sm, 16);
        sm += __shfl_xor(sm, 32);
        float inv = 1.f / sm;
        #pragma unroll
        for (int j = 0; j < 7; j++) {
            union { unsigned u[2]; uint2 u2; } pk;
            pk.u[0] = packbf(sc[j][0] * inv, sc[j][1] * inv);
            pk.u[1] = packbf(sc[j][2] * inv, sc[j][3] * inv);
            *(uint2*)((char*)myp + l15 * 256 + SWZB(l15, (16 * j + 4 * lhi) * 2)) = pk.u2;
        }
        fv4_t oacc[2] = {{0.f, 0.f, 0.f, 0.f}, {0.f, 0.f, 0.f, 0.f}};
        __builtin_amdgcn_s_setprio(1);
        for (int kk = 0; kk < 4; kk++) {
            sv8_t pa = lds_ld8(myp, l15 * 256 + SWZB(l15, (kk * 32 + 8 * lhi) * 2));
            #pragma unroll
            for (int j = 0; j < 2; j++)
                oacc[j] = __builtin_amdgcn_mfma_f32_16x16x32_bf16(pa, vf[kk][j], oacc[j], 0, 0, 0);
        }
        __builtin_amdgcn_s_setprio(0);
        #pragma unroll
        for (int r = 0; r < 4; r++) {
            int orow = 16 * ms + 4 * lhi + r;
            #pragma unroll
            for (int j = 0; j < 2; j++) {
                int ocol = head * 32 + 16 * j + l15;
                float v = (orow < 98) ? oacc[j][r] : 0.f;
                lds_st1(ot, orow * 256 + SWZB(orow, ocol * 2), f2bf(v));
            }
        }
        qa_c = qa_n;
    }
    __syncthreads();

    {
        int nb = wv * 32;
        fv4_t acc[7][2];
        for (int m = 0; m < 7; m++) for (int j = 0; j < 2; j++) acc[m][j] = (fv4_t){0.f, 0.f, 0.f, 0.f};
        for (int kk = 0; kk < 4; kk++) {
            sv8_t b[2];
            #pragma unroll
            for (int j = 0; j < 2; j++)
                b[j] = *(const sv8_t*)(pwT + (size_t)(nb + 16 * j + l15) * 128 + kk * 32 + 8 * lhi);
            __builtin_amdgcn_s_setprio(1);
            #pragma unroll
            for (int m = 0; m < 7; m++) {
                int ar = 16 * m + l15;
                sv8_t a = lds_ld8(ot, ar * 256 + SWZB(ar, (kk * 32 + 8 * lhi) * 2));
                #pragma unroll
                for (int j = 0; j < 2; j++)
                    acc[m][j] = __builtin_amdgcn_mfma_f32_16x16x32_bf16(a, b[j], acc[m][j], 0, 0, 0);
            }
            __builtin_amdgcn_s_setprio(0);
        }
        int b_ = win >> 8;
        for (int m = 0; m < 7; m++)
            #pragma unroll
            for (int r = 0; r < 4; r++) {
                int row = 16 * m + lhi * 4 + r;
                if (row < 98) {
                    int it = row / 49, r2 = row - it * 49, ih = r2 / 7, iw = r2 - ih * 7;
                    int t = tw * 2 + it, h = hw * 7 + ih, w = ww * 7 + iw;
                    if (shifted) {
                        t += 1; if (t >= TT) t -= TT;
                        h += 3; if (h >= HH) h -= HH;
                        w += 3; if (w >= WW2) w -= WW2;
                    }
                    float* xp = xbuf + ((size_t)b_ * PSPAT + t * (HH * WW2) + h * WW2 + w) * 128 + nb;
                    #pragma unroll
                    for (int j = 0; j < 2; j++) {
                        int c = 16 * j + l15;
                        xp[c] += acc[m][j][r] + pb[nb + c];
                    }
                }
            }
    }
}

// ---------------- fused LN2 + fc1 + GELU + fc2 + residual (+final transpose) ----
// Ping-pong chunk pipeline: 16 chunks of 16 KB (w1 q-halves, w2 q-halves).
// Chunk c lives in Bst[c&1]; phase p computes from chunk p while ds_writing
// chunk p+1 (other buffer) and issuing global loads for chunk p+2. One barrier
// per phase. LDS 64 KB -> 2 blocks/CU. Final layer writes out[b][c][p] directly.
#define LOAD_CHUNK(c, R)                                                                   \
    if ((c) < 16) {                                                                        \
        if ((((c) >> 1) & 1) == 0 && (((c)&2) == 0)) {}                                    \
        if (((c) & 2) == 0) {                                                              \
            _Pragma("unroll")                                                              \
            for (int i_ = 0; i_ < 4; i_++)                                                 \
                R[i_] = *(const sv8_t*)(w1T + (size_t)(((c) >> 2) * 128 + ((c)&1) * 64 + i_ * 16 + r1) * 128 + (c1 >> 1)); \
        } else {                                                                           \
            _Pragma("unroll")                                                              \
            for (int i_ = 0; i_ < 4; i_++)                                                 \
                R[i_] = *(const sv8_t*)(w2T + (size_t)(i_ * 32 + r2) * 512 + ((c) >> 2) * 128 + ((c)&1) * 64 + (c2 >> 1)); \
        }                                                                                  \
    }
#define WRITE_CHUNK(c, R)                                                                  \
    if ((c) < 16) {                                                                        \
        unsigned short* bst_ = Bst[(c)&1];                                                 \
        if (((c) & 2) == 0) {                                                              \
            _Pragma("unroll")                                                              \
            for (int i_ = 0; i_ < 4; i_++)                                                 \
                lds_st8(bst_, (i_ * 16 + r1) * 256 + SWZB(i_ * 16 + r1, c1), R[i_]);       \
        } else {                                                                           \
            _Pragma("unroll")                                                              \
            for (int i_ = 0; i_ < 4; i_++)                                                 \
                lds_st8(bst_, (i_ * 32 + r2) * 128 + SWZB(i_ * 32 + r2, c2), R[i_]);       \
        }                                                                                  \
    }

__global__ __launch_bounds__(256, 2) void k_mlp(const float* __restrict__ xin,
                                                const float* __restrict__ g,
                                                const float* __restrict__ be,
                                                const unsigned short* __restrict__ w1T,  // [512][128]
                                                const float* __restrict__ b1p,
                                                const unsigned short* __restrict__ w2T,  // [128][512]
                                                const float* __restrict__ b2p,
                                                float* __restrict__ xbuf,
                                                float* __restrict__ outp,
                                                int final_layer) {
    __shared__ unsigned short A[4][32 * 128];   // 32 KB: per-wave xt then U slice
    __shared__ unsigned short Bst[2][8192];     // 2 x 16 KB ping-pong chunks
    int tid = threadIdx.x;
    int wv = tid >> 6, lane = tid & 63, l15 = lane & 15, lhi = lane >> 4;
    unsigned short* bw = A[wv];
    int tok0 = blockIdx.x * 128 + wv * 32;

    int r1 = tid >> 4, c1 = (tid & 15) * 16;   // w1 chunk coords (64x128)
    int r2 = tid >> 3, c2 = (tid & 7) * 16;    // w2 chunk coords (128x64)

    sv8_t wA[4], wB[4];
    LOAD_CHUNK(0, wA)                          // hidden under LN

    // ---- LN (wave-private xt in A[wv])
    #pragma unroll
    for (int tf = 0; tf < 2; tf++) {
        int lrow = 16 * tf + l15;
        const float* src = xin + (size_t)(tok0 + lrow) * 128 + lhi * 32;
        float v[32];
        float s = 0.f, sq = 0.f;
        #pragma unroll
        for (int i = 0; i < 8; i++) {
            f4ld_t f = *(const f4ld_t*)(src + i * 4);
            v[i * 4 + 0] = f.x; v[i * 4 + 1] = f.y; v[i * 4 + 2] = f.z; v[i * 4 + 3] = f.w;
            s += f.x + f.y + f.z + f.w;
            sq += f.x * f.x + f.y * f.y + f.z * f.z + f.w * f.w;
        }
        s += __shfl_xor(s, 16); sq += __shfl_xor(sq, 16);
        s += __shfl_xor(s, 32); sq += __shfl_xor(sq, 32);
        float mu = s * (1.f / 128.f);
        float var = sq * (1.f / 128.f) - mu * mu;
        float rs = rsqrtf(var + 1e-5f);
        #pragma unroll
        for (int j = 0; j < 4; j++) {
            int c0 = lhi * 32 + 8 * j;
            f4ld_t g0 = *(const f4ld_t*)(g + c0);
            f4ld_t g1 = *(const f4ld_t*)(g + c0 + 4);
            f4ld_t b0 = *(const f4ld_t*)(be + c0);
            f4ld_t b1 = *(const f4ld_t*)(be + c0 + 4);
            float y0 = (v[8 * j + 0] - mu) * rs * g0.x + b0.x;
            float y1 = (v[8 * j + 1] - mu) * rs * g0.y + b0.y;
            float y2 = (v[8 * j + 2] - mu) * rs * g0.z + b0.z;
            float y3 = (v[8 * j + 3] - mu) * rs * g0.w + b0.w;
            float y4 = (v[8 * j + 4] - mu) * rs * g1.x + b1.x;
            float y5 = (v[8 * j + 5] - mu) * rs * g1.y + b1.y;
            float y6 = (v[8 * j + 6] - mu) * rs * g1.z + b1.z;
            float y7 = (v[8 * j + 7] - mu) * rs * g1.w + b1.w;
            union { unsigned u[4]; sv8_t s8; } pk;
            pk.u[0] = packbf(y0, y1); pk.u[1] = packbf(y2, y3);
            pk.u[2] = packbf(y4, y5); pk.u[3] = packbf(y6, y7);
            lds_st8(bw, lrow * 256 + SWZB(lrow, 64 * lhi + 16 * j), pk.s8);
        }
    }
    sv8_t xf[2][4];
    #pragma unroll
    for (int tf = 0; tf < 2; tf++)
        #pragma unroll
        for (int kk = 0; kk < 4; kk++) {
            int lrow = 16 * tf + l15;
            xf[tf][kk] = lds_ld8(bw, lrow * 256 + SWZB(lrow, 64 * kk + 16 * lhi));
        }

    fv4_t acc2[8][2];
    #pragma unroll
    for (int cg = 0; cg < 8; cg++)
        #pragma unroll
        for (int tf = 0; tf < 2; tf++) acc2[cg][tf] = (fv4_t){0.f, 0.f, 0.f, 0.f};

    // prologue: stage chunk0, issue chunk1
    WRITE_CHUNK(0, wA)
    LOAD_CHUNK(1, wB)
    __syncthreads();

    #pragma unroll
    for (int q = 0; q < 4; q++) {
        // ---- phase s=0: fc1 fg 0..3 from Bst[0]
        {
            const int c = 4 * q;
            WRITE_CHUNK(c + 1, wB)
            LOAD_CHUNK(c + 2, wA)
            #pragma unroll
            for (int f = 0; f < 4; f++) {
                int fg = f;
                sv8_t wf[4];
                #pragma unroll
                for (int kk = 0; kk < 4; kk++) {
                    int wrow = 16 * f + l15;
                    wf[kk] = lds_ld8(Bst[0], wrow * 256 + SWZB(wrow, kk * 64 + 16 * lhi));
                }
                fv4_t a1[2] = {{0.f, 0.f, 0.f, 0.f}, {0.f, 0.f, 0.f, 0.f}};
                __builtin_amdgcn_s_setprio(1);
                #pragma unroll
                for (int kk = 0; kk < 4; kk++) {
                    a1[0] = __builtin_amdgcn_mfma_f32_16x16x32_bf16(wf[kk], xf[0][kk], a1[0], 0, 0, 0);
                    a1[1] = __builtin_amdgcn_mfma_f32_16x16x32_bf16(wf[kk], xf[1][kk], a1[1], 0, 0, 0);
                }
                __builtin_amdgcn_s_setprio(0);
                f4ld_t b4 = *(const f4ld_t*)(b1p + q * 128 + 16 * fg + 4 * lhi);
                #pragma unroll
                for (int tf = 0; tf < 2; tf++) {
                    float g0 = gelu_f(a1[tf][0] + b4.x);
                    float g1 = gelu_f(a1[tf][1] + b4.y);
                    float g2 = gelu_f(a1[tf][2] + b4.z);
                    float g3 = gelu_f(a1[tf][3] + b4.w);
                    union { unsigned u[2]; uint2 u2; } pk;
                    pk.u[0] = packbf(g0, g1); pk.u[1] = packbf(g2, g3);
                    int lrow = 16 * tf + l15;
                    *(uint2*)((char*)bw + lrow * 256 + SWZB(lrow, 32 * fg + 8 * lhi)) = pk.u2;
                }
            }
            __syncthreads();
        }
        // ---- phase s=1: fc1 fg 4..7 from Bst[1]
        {
            const int c = 4 * q + 1;
            WRITE_CHUNK(c + 1, wA)
            LOAD_CHUNK(c + 2, wB)
            #pragma unroll
            for (int f = 0; f < 4; f++) {
                int fg = 4 + f;
                sv8_t wf[4];
                #pragma unroll
                for (int kk = 0; kk < 4; kk++) {
                    int wrow = 16 * f + l15;
                    wf[kk] = lds_ld8(Bst[1], wrow * 256 + SWZB(wrow, kk * 64 + 16 * lhi));
                }
                fv4_t a1[2] = {{0.f, 0.f, 0.f, 0.f}, {0.f, 0.f, 0.f, 0.f}};
                __builtin_amdgcn_s_setprio(1);
                #pragma unroll
                for (int kk = 0; kk < 4; kk++) {
                    a1[0] = __builtin_amdgcn_mfma_f32_16x16x32_bf16(wf[kk], xf[0][kk], a1[0], 0, 0, 0);
                    a1[1] = __builtin_amdgcn_mfma_f32_16x16x32_bf16(wf[kk], xf[1][kk], a1[1], 0, 0, 0);
                }
                __builtin_amdgcn_s_setprio(0);
                f4ld_t b4 = *(const f4ld_t*)(b1p + q * 128 + 16 * fg + 4 * lhi);
                #pragma unroll
                for (int tf = 0; tf < 2; tf++) {
                    float g0 = gelu_f(a1[tf][0] + b4.x);
                    float g1 = gelu_f(a1[tf][1] + b4.y);
                    float g2 = gelu_f(a1[tf][2] + b4.z);
                    float g3 = gelu_f(a1[tf][3] + b4.w);
                    union { unsigned u[2]; uint2 u2; } pk;
                    pk.u[0] = packbf(g0, g1); pk.u[1] = packbf(g2, g3);
                    int lrow = 16 * tf + l15;
                    *(uint2*)((char*)bw + lrow * 256 + SWZB(lrow, 32 * fg + 8 * lhi)) = pk.u2;
                }
            }
            __syncthreads();
        }
        // ---- phase s=2: fc2 kq 0,1 from Bst[0]
        {
            const int c = 4 * q + 2;
            WRITE_CHUNK(c + 1, wB)
            LOAD_CHUNK(c + 2, wA)
            #pragma unroll
            for (int kq = 0; kq < 2; kq++) {
                sv8_t uf[2];
                #pragma unroll
                for (int tf = 0; tf < 2; tf++) {
                    int lrow = 16 * tf + l15;
                    uf[tf] = lds_ld8(bw, lrow * 256 + SWZB(lrow, 64 * kq + 16 * lhi));
                }
                #pragma unroll
                for (int cb = 0; cb < 2; cb++) {
                    sv8_t w2f[4];
                    #pragma unroll
                    for (int cc = 0; cc < 4; cc++) {
                        int wrow = 16 * (4 * cb + cc) + l15;
                        w2f[cc] = lds_ld8(Bst[0], wrow * 128 + SWZB(wrow, kq * 64 + 16 * lhi));
                    }
                    __builtin_amdgcn_s_setprio(1);
                    #pragma unroll
                    for (int cc = 0; cc < 4; cc++) {
                        int cg = 4 * cb + cc;
                        acc2[cg][0] = __builtin_amdgcn_mfma_f32_16x16x32_bf16(w2f[cc], uf[0], acc2[cg][0], 0, 0, 0);
                        acc2[cg][1] = __builtin_amdgcn_mfma_f32_16x16x32_bf16(w2f[cc], uf[1], acc2[cg][1], 0, 0, 0);
                    }
                    __builtin_amdgcn_s_setprio(0);
                }
            }
            __syncthreads();
        }
        // ---- phase s=3: fc2 kq 2,3 from Bst[1]
        {
            const int c = 4 * q + 3;
            WRITE_CHUNK(c + 1, wA)
            LOAD_CHUNK(c + 2, wB)
            #pragma unroll
            for (int kq = 2; kq < 4; kq++) {
                sv8_t uf[2];
                #pragma unroll
                for (int tf = 0; tf < 2; tf++) {
                    int lrow = 16 * tf + l15;
                    uf[tf] = lds_ld8(bw, lrow * 256 + SWZB(lrow, 64 * kq + 16 * lhi));
                }
                #pragma unroll
                for (int cb = 0; cb < 2; cb++) {
                    sv8_t w2f[4];
                    #pragma unroll
                    for (int cc = 0; cc < 4; cc++) {
                        int wrow = 16 * (4 * cb + cc) + l15;
                        w2f[cc] = lds_ld8(Bst[1], wrow * 128 + SWZB(wrow, (kq - 2) * 64 + 16 * lhi));
                    }
                    __builtin_amdgcn_s_setprio(1);
                    #pragma unroll
                    for (int cc = 0; cc < 4; cc++) {
                        int cg = 4 * cb + cc;
                        acc2[cg][0] = __builtin_amdgcn_mfma_f32_16x16x32_bf16(w2f[cc], uf[0], acc2[cg][0], 0, 0, 0);
                        acc2[cg][1] = __builtin_amdgcn_mfma_f32_16x16x32_bf16(w2f[cc], uf[1], acc2[cg][1], 0, 0, 0);
                    }
                    __builtin_amdgcn_s_setprio(0);
                }
            }
            __syncthreads();
        }
    }
    // ---- epilogue
    if (!final_layer) {
        #pragma unroll
        for (int tf = 0; tf < 2; tf++) {
            int row = tok0 + 16 * tf + l15;
            #pragma unroll
            for (int cg = 0; cg < 8; cg++) {
                int c0 = 16 * cg + 4 * lhi;
                f4ld_t b4 = *(const f4ld_t*)(b2p + c0);
                float* xp = xbuf + (size_t)row * 128 + c0;
                f4ld_t o = *(f4ld_t*)xp;
                o.x += acc2[cg][tf][0] + b4.x;
                o.y += acc2[cg][tf][1] + b4.y;
                o.z += acc2[cg][tf][2] + b4.z;
                o.w += acc2[cg][tf][3] + b4.w;
                *(f4ld_t*)xp = o;
            }
        }
    } else {
        // final layer: write transposed out[b][c][p] = xbuf + mlp (fuses k_transpose_out)
        #pragma unroll
        for (int tf = 0; tf < 2; tf++) {
            int row = tok0 + 16 * tf + l15;
            int b_ = row / PSPAT, p = row - b_ * PSPAT;
            float* ob = outp + (size_t)b_ * 128 * PSPAT + p;
            #pragma unroll
            for (int cg = 0; cg < 8; cg++) {
                int c0 = 16 * cg + 4 * lhi;
                f4ld_t b4 = *(const f4ld_t*)(b2p + c0);
                const float* xp = xbuf + (size_t)row * 128 + c0;
                f4ld_t o = *(const f4ld_t*)xp;
                o.x += acc2[cg][tf][0] + b4.x;
                o.y += acc2[cg][tf][1] + b4.y;
                o.z += acc2[cg][tf][2] + b4.z;
                o.w += acc2[cg][tf][3] + b4.w;
                ob[(size_t)(c0 + 0) * PSPAT] = o.x;
                ob[(size_t)(c0 + 1) * PSPAT] = o.y;
                ob[(size_t)(c0 + 2) * PSPAT] = o.z;
                ob[(size_t)(c0 + 3) * PSPAT] = o.w;
            }
        }
    }
}

extern "C" void kernel_launch(void* const* d_in, const int* in_sizes, int n_in,
                              void* d_out, int out_size, void* d_ws, size_t ws_size,
                              hipStream_t stream) {
    const float* x_in   = (const float*)d_in[0];
    const float* ln1_g  = (const float*)d_in[1];
    const float* ln1_b  = (const float*)d_in[2];
    const float* qkv_w  = (const float*)d_in[3];
    const float* qkv_b  = (const float*)d_in[4];
    const float* rpb    = (const float*)d_in[5];
    const float* proj_w = (const float*)d_in[6];
    const float* proj_b = (const float*)d_in[7];
    const float* ln2_g  = (const float*)d_in[8];
    const float* ln2_b  = (const float*)d_in[9];
    const float* fc1_w  = (const float*)d_in[10];
    const float* fc1_b  = (const float*)d_in[11];
    const float* fc2_w  = (const float*)d_in[12];
    const float* fc2_b  = (const float*)d_in[13];
    float* out = (float*)d_out;

    char* ws = (char*)d_ws;
    float* xbuf = (float*)ws;                                        // 102,760,448 B
    unsigned short* qkbuf = (unsigned short*)(ws + 102760448);       // 102,760,448 B
    unsigned short* vTbuf = (unsigned short*)(ws + 205520896);       //  58,720,256 B
    unsigned short* wbase = (unsigned short*)(ws + 264241408);       //     786,432 B
    float* biasb = (float*)(ws + 264241408 + 786432);                //     401,408 B

    k_transpose_in<<<dim3(PSPAT / 32, 4, BB), dim3(32, 8), 0, stream>>>(x_in, xbuf);

    for (int l = 0; l < 2; l++) {
        unsigned short* wqT = wbase + (size_t)l * 196608;
        unsigned short* wpT = wqT + 49152;
        unsigned short* w1T = wpT + 16384;
        unsigned short* w2T = w1T + 65536;
        k_prep_w<<<dim3(12, 4), dim3(32, 8), 0, stream>>>(qkv_w + (size_t)l * 49152, wqT, 128, 384);
        k_prep_w<<<dim3(4, 4),  dim3(32, 8), 0, stream>>>(proj_w + (size_t)l * 16384, wpT, 128, 128);
        k_prep_w<<<dim3(16, 4), dim3(32, 8), 0, stream>>>(fc1_w + (size_t)l * 65536, w1T, 128, 512);
        k_prep_w<<<dim3(4, 16), dim3(32, 8), 0, stream>>>(fc2_w + (size_t)l * 65536, w2T, 512, 128);
    }
    k_prep_bias<<<dim3(112, 4, 2), 112, 0, stream>>>(rpb, biasb);

    for (int layer = 0; layer < 2; layer++) {
        unsigned short* wqT = wbase + (size_t)layer * 196608;
        unsigned short* wpT = wqT + 49152;
        unsigned short* w1T = wpT + 16384;
        unsigned short* w2T = w1T + 65536;
        int shifted = layer & 1;

        k_qkv<<<TOK_TOTAL / 64, 256, 0, stream>>>(xbuf, ln1_g + layer * 128, ln1_b + layer * 128,
                                                  wqT, qkv_b + layer * 384, qkbuf, vTbuf, shifted);
        k_attn_proj<<<BNW, 256, 0, stream>>>(qkbuf, vTbuf, biasb + (size_t)layer * 4 * 112 * 112,
                                             wpT, proj_b + layer * 128, xbuf, shifted);
        k_mlp<<<TOK_TOTAL / 128, 256, 0, stream>>>(xbuf, ln2_g + layer * 128, ln2_b + layer * 128,
                                                   w1T, fc1_b + layer * 512, w2T, fc2_b + layer * 128,
                                                   xbuf, out, layer == 1);
    }
}